// Round 1
// baseline (802.695 us; speedup 1.0000x reference)
//
#include <hip/hip_runtime.h>
#include <hip/hip_bf16.h>
#include <math.h>

// Problem constants
constexpr int NN = 100000;   // nodes
constexpr int EE = 1600000;  // edges
constexpr int GG = 512;      // graphs
constexpr int SCAN_N = 100352; // 98 * 1024 (padded scan domain)

// ---------------------------------------------------------------------------
// CSR build: histogram -> scan -> scatter
// ---------------------------------------------------------------------------
__global__ __launch_bounds__(256) void k_hist(const int* __restrict__ dst, int* __restrict__ deg) {
    int i = blockIdx.x * 256 + threadIdx.x;
    if (i < EE) atomicAdd(&deg[dst[i]], 1);
}

// Block-local exclusive scan over 1024-element chunks; block totals to bsum.
__global__ __launch_bounds__(256) void k_scan1(const int* __restrict__ deg,
                                               int* __restrict__ outp,
                                               int* __restrict__ bsum) {
    __shared__ int wsum[4];
    int tid = threadIdx.x, b = blockIdx.x;
    int base = b * 1024 + tid * 4;
    int4 v = *reinterpret_cast<const int4*>(deg + base);
    int t = v.x + v.y + v.z + v.w;
    int lane = tid & 63, w = tid >> 6;
    int sc = t;
    #pragma unroll
    for (int off = 1; off < 64; off <<= 1) {
        int n = __shfl_up(sc, off);
        if (lane >= off) sc += n;
    }
    if (lane == 63) wsum[w] = sc;
    __syncthreads();
    int woff = 0;
    for (int i = 0; i < 4; i++) if (i < w) woff += wsum[i];
    int excl = woff + sc - t;
    outp[base]     = excl;
    outp[base + 1] = excl + v.x;
    outp[base + 2] = excl + v.x + v.y;
    outp[base + 3] = excl + v.x + v.y + v.z;
    if (tid == 255) bsum[b] = woff + sc;
}

// Exclusive scan of the 98 block sums (single block, 128 threads).
__global__ __launch_bounds__(128) void k_scan2(int* __restrict__ bsum) {
    __shared__ int wt[2];
    int tid = threadIdx.x;
    int v = (tid < 98) ? bsum[tid] : 0;
    int lane = tid & 63, w = tid >> 6;
    int sc = v;
    #pragma unroll
    for (int off = 1; off < 64; off <<= 1) {
        int n = __shfl_up(sc, off);
        if (lane >= off) sc += n;
    }
    if (lane == 63) wt[w] = sc;
    __syncthreads();
    int excl = sc - v + (w == 1 ? wt[0] : 0);
    if (tid < 98) bsum[tid] = excl;
}

// Add block offsets in place; also emit cursor copy for the scatter pass.
__global__ __launch_bounds__(256) void k_scan3(const int* __restrict__ bsum,
                                               int* __restrict__ row_ptr,
                                               int* __restrict__ cursor) {
    int b = blockIdx.x, tid = threadIdx.x;
    int i = b * 1024 + tid * 4;
    int add = bsum[b];
    int4 v = *reinterpret_cast<const int4*>(row_ptr + i);
    int4 o; o.x = v.x + add; o.y = v.y + add; o.z = v.z + add; o.w = v.w + add;
    *reinterpret_cast<int4*>(row_ptr + i) = o;
    *reinterpret_cast<int4*>(cursor + i) = o;
}

__global__ __launch_bounds__(256) void k_scatter(const int* __restrict__ src,
                                                 const int* __restrict__ dst,
                                                 int* __restrict__ cursor,
                                                 int* __restrict__ csr_src) {
    int i = blockIdx.x * 256 + threadIdx.x;
    if (i < EE) {
        int pos = atomicAdd(&cursor[dst[i]], 1);
        csr_src[pos] = src[i];
    }
}

// ---------------------------------------------------------------------------
// Fused QKVS GEMM: out[N,256] = X[N,K] @ [Wq|Wk|Wv|Wsk][K,64 each] + biases
// Tile: 32 rows x 256 cols per block (256 threads; thread = 4 rows x 8 cols)
// ---------------------------------------------------------------------------
template<int K>
__global__ __launch_bounds__(256) void gemm_qkvs(
    const float* __restrict__ X,
    const float* __restrict__ Wq, const float* __restrict__ Bq,
    const float* __restrict__ Wk, const float* __restrict__ Bk,
    const float* __restrict__ Wv, const float* __restrict__ Bv,
    const float* __restrict__ Wsk, const float* __restrict__ Bsk,
    float* __restrict__ outp) {
    constexpr int BM = 32;
    constexpr int XP = K + 2;                 // +2 pad: conflict-free row stride
    __shared__ float xs[BM * XP];             // K=128: 16.6 KB
    __shared__ float ws[32 * 256];            // 32 KB per K-chunk
    int tid = threadIdx.x;
    int rowBase = blockIdx.x * BM;
    int tc = tid & 31, tr = tid >> 5;

    // Stage full-K x tile (coalesced float4 loads)
    {
        constexpr int TOT = BM * K / 4;
        const float4* Xv = reinterpret_cast<const float4*>(X + (size_t)rowBase * K);
        #pragma unroll
        for (int i = tid; i < TOT; i += 256) {
            int r = i / (K / 4), kq = i % (K / 4);
            float4 val = Xv[r * (K / 4) + kq];
            float* dp = &xs[r * XP + kq * 4];
            dp[0] = val.x; dp[1] = val.y; dp[2] = val.z; dp[3] = val.w;
        }
    }

    float acc[4][8];
    #pragma unroll
    for (int r = 0; r < 4; r++)
        #pragma unroll
        for (int c = 0; c < 8; c++) acc[r][c] = 0.f;

    for (int k0 = 0; k0 < K; k0 += 32) {
        __syncthreads();   // protect ws (and xs on first iter)
        // Stage W chunk 32x256 into LDS
        #pragma unroll
        for (int a = 0; a < 4; a++) {
            const float* wsrc = (a == 0) ? Wq : (a == 1) ? Wk : (a == 2) ? Wv : Wsk;
            #pragma unroll
            for (int i = 0; i < 2; i++) {
                int f4 = i * 256 + tid;       // [0,512) float4s of 32x64 block
                int kk = f4 >> 4;
                int c  = (f4 & 15) * 4;
                float4 val = *reinterpret_cast<const float4*>(wsrc + (size_t)(k0 + kk) * 64 + c);
                *reinterpret_cast<float4*>(&ws[kk * 256 + a * 64 + c]) = val;
            }
        }
        __syncthreads();
        #pragma unroll
        for (int kk = 0; kk < 32; kk++) {
            float xr[4];
            #pragma unroll
            for (int r = 0; r < 4; r++) xr[r] = xs[(tr * 4 + r) * XP + k0 + kk];
            float4 w0 = *reinterpret_cast<const float4*>(&ws[kk * 256 + tc * 8]);
            float4 w1 = *reinterpret_cast<const float4*>(&ws[kk * 256 + tc * 8 + 4]);
            float wv8[8] = {w0.x, w0.y, w0.z, w0.w, w1.x, w1.y, w1.z, w1.w};
            #pragma unroll
            for (int r = 0; r < 4; r++)
                #pragma unroll
                for (int c = 0; c < 8; c++)
                    acc[r][c] += xr[r] * wv8[c];
        }
    }

    // Epilogue: bias + coalesced store
    int cBase = tc * 8;
    int grp = cBase >> 6;
    const float* bp = (grp == 0) ? Bq : (grp == 1) ? Bk : (grp == 2) ? Bv : Bsk;
    float bias[8];
    #pragma unroll
    for (int c = 0; c < 8; c++) bias[c] = bp[(cBase & 63) + c];
    #pragma unroll
    for (int r = 0; r < 4; r++) {
        int row = rowBase + tr * 4 + r;
        float* op = outp + (size_t)row * 256 + cBase;
        float4 o0, o1;
        o0.x = acc[r][0] + bias[0]; o0.y = acc[r][1] + bias[1];
        o0.z = acc[r][2] + bias[2]; o0.w = acc[r][3] + bias[3];
        o1.x = acc[r][4] + bias[4]; o1.y = acc[r][5] + bias[5];
        o1.z = acc[r][6] + bias[6]; o1.w = acc[r][7] + bias[7];
        *reinterpret_cast<float4*>(op) = o0;
        *reinterpret_cast<float4*>(op + 4) = o1;
    }
}

// ---------------------------------------------------------------------------
// Fused attention: per-node softmax-free aggregation + skip + BN + ReLU.
// One wave per dst node; lane = h*16+d. qkvs row: [q(64)|k(64)|v(64)|s(64)]
// ---------------------------------------------------------------------------
__global__ __launch_bounds__(256) void attn_fused(
    const float* __restrict__ qkvs,
    const int* __restrict__ row_ptr,
    const int* __restrict__ csr_src,
    const float* __restrict__ bng, const float* __restrict__ bnb,
    const float* __restrict__ bnm, const float* __restrict__ bnv,
    float* __restrict__ h_out) {
    int wid = (blockIdx.x * 256 + threadIdx.x) >> 6;
    int lane = threadIdx.x & 63;
    if (wid >= NN) return;
    const float* base = qkvs + (size_t)wid * 256;
    float q = base[lane];
    float skip = base[192 + lane];
    int jb = row_ptr[wid], je = row_ptr[wid + 1];
    float acc = 0.f, denom = 0.f;
    int j = jb;
    for (; j + 1 < je; j += 2) {   // 2-edge ILP
        int s0 = csr_src[j], s1 = csr_src[j + 1];
        const float* b0 = qkvs + (size_t)s0 * 256;
        const float* b1 = qkvs + (size_t)s1 * 256;
        float k0 = b0[64 + lane], v0 = b0[128 + lane];
        float k1 = b1[64 + lane], v1 = b1[128 + lane];
        float p0 = q * k0, p1 = q * k1;
        p0 += __shfl_xor(p0, 1);  p1 += __shfl_xor(p1, 1);
        p0 += __shfl_xor(p0, 2);  p1 += __shfl_xor(p1, 2);
        p0 += __shfl_xor(p0, 4);  p1 += __shfl_xor(p1, 4);
        p0 += __shfl_xor(p0, 8);  p1 += __shfl_xor(p1, 8);
        float e0 = __expf(p0 * 0.25f);
        float e1 = __expf(p1 * 0.25f);
        denom += e0 + e1;
        acc += e0 * v0 + e1 * v1;
    }
    if (j < je) {
        int s0 = csr_src[j];
        const float* b0 = qkvs + (size_t)s0 * 256;
        float k0 = b0[64 + lane], v0 = b0[128 + lane];
        float p0 = q * k0;
        p0 += __shfl_xor(p0, 1);
        p0 += __shfl_xor(p0, 2);
        p0 += __shfl_xor(p0, 4);
        p0 += __shfl_xor(p0, 8);
        float e0 = __expf(p0 * 0.25f);
        denom += e0;
        acc += e0 * v0;
    }
    float o = acc / (denom + 1e-16f) + skip;
    o = (o - bnm[lane]) * rsqrtf(bnv[lane] + 1e-5f) * bng[lane] + bnb[lane];
    h_out[(size_t)wid * 64 + lane] = fmaxf(o, 0.f);
}

// ---------------------------------------------------------------------------
// Global max pool over sorted batch ids (values are post-ReLU, >= 0).
// ---------------------------------------------------------------------------
__global__ __launch_bounds__(256) void k_pool(const float* __restrict__ h,
                                              const int* __restrict__ batch,
                                              float* __restrict__ g0) {
    int f = threadIdx.x & 63;
    int sub = threadIdx.x >> 6;
    int n0 = blockIdx.x * 128;
    int nEnd = n0 + 128; if (nEnd > NN) nEnd = NN;
    int cur_g = -1; float cur_m = 0.f;
    for (int n = n0 + sub; n < nEnd; n += 4) {
        int bg = batch[n];
        float val = h[(size_t)n * 64 + f];
        if (bg != cur_g) {
            if (cur_g >= 0) atomicMax((int*)&g0[cur_g * 64 + f], __float_as_int(cur_m));
            cur_g = bg; cur_m = val;
        } else {
            cur_m = fmaxf(cur_m, val);
        }
    }
    if (cur_g >= 0) atomicMax((int*)&g0[cur_g * 64 + f], __float_as_int(cur_m));
}

// ---------------------------------------------------------------------------
// Fused MLP head: 4 layers + BN + log_softmax. One wave per graph row.
// ---------------------------------------------------------------------------
__global__ __launch_bounds__(256) void k_mlp(
    const float* __restrict__ g0,
    const float* __restrict__ p1w, const float* __restrict__ p1b,
    const float* __restrict__ p2w, const float* __restrict__ p2b,
    const float* __restrict__ cl1w, const float* __restrict__ cl1b,
    const float* __restrict__ bg, const float* __restrict__ bb,
    const float* __restrict__ bm, const float* __restrict__ bv,
    const float* __restrict__ cl2w, const float* __restrict__ cl2b,
    float* __restrict__ outp) {
    __shared__ float w1[64 * 64], w2[64 * 64], w3[64 * 64], w4[64 * 10];
    __shared__ float sb1[64], sb2[64], sb3[64], sbn[4 * 64], sb4[10];
    int tid = threadIdx.x;
    for (int i = tid; i < 64 * 64; i += 256) { w1[i] = p1w[i]; w2[i] = p2w[i]; w3[i] = cl1w[i]; }
    for (int i = tid; i < 64 * 10; i += 256) w4[i] = cl2w[i];
    if (tid < 64) {
        sb1[tid] = p1b[tid]; sb2[tid] = p2b[tid]; sb3[tid] = cl1b[tid];
        sbn[tid] = bg[tid]; sbn[64 + tid] = bb[tid];
        sbn[128 + tid] = bm[tid]; sbn[192 + tid] = bv[tid];
    }
    if (tid < 10) sb4[tid] = cl2b[tid];
    __syncthreads();
    int lane = tid & 63, w = tid >> 6;
    int row = blockIdx.x * 4 + w;
    float x = g0[row * 64 + lane];
    if (!isfinite(x)) x = 0.f;
    float a = sb1[lane];
    for (int k = 0; k < 64; k++) a += __shfl(x, k) * w1[k * 64 + lane];
    x = fmaxf(a, 0.f);
    a = sb2[lane];
    for (int k = 0; k < 64; k++) a += __shfl(x, k) * w2[k * 64 + lane];
    x = a;
    a = sb3[lane];
    for (int k = 0; k < 64; k++) a += __shfl(x, k) * w3[k * 64 + lane];
    a = (a - sbn[128 + lane]) * rsqrtf(sbn[192 + lane] + 1e-5f) * sbn[lane] + sbn[64 + lane];
    x = fmaxf(a, 0.f);
    float lg[10];
    #pragma unroll
    for (int c = 0; c < 10; c++) {
        float p = x * w4[lane * 10 + c];
        p += __shfl_xor(p, 1);  p += __shfl_xor(p, 2);  p += __shfl_xor(p, 4);
        p += __shfl_xor(p, 8);  p += __shfl_xor(p, 16); p += __shfl_xor(p, 32);
        lg[c] = p + sb4[c];
    }
    float mx = lg[0];
    #pragma unroll
    for (int c = 1; c < 10; c++) mx = fmaxf(mx, lg[c]);
    float s = 0.f;
    #pragma unroll
    for (int c = 0; c < 10; c++) s += __expf(lg[c] - mx);
    float lse = mx + logf(s);
    float o = 0.f;
    #pragma unroll
    for (int c = 0; c < 10; c++) if (lane == c) o = lg[c];
    if (lane < 10) outp[row * 10 + lane] = o - lse;
}

// ---------------------------------------------------------------------------
extern "C" void kernel_launch(void* const* d_in, const int* in_sizes, int n_in,
                              void* d_out, int out_size, void* d_ws, size_t ws_size,
                              hipStream_t stream) {
    const float* x     = (const float*)d_in[0];
    const int*   ei    = (const int*)d_in[1];
    const int*   batch = (const int*)d_in[2];
    const float *c1_wq = (const float*)d_in[3],  *c1_bq = (const float*)d_in[4];
    const float *c1_wk = (const float*)d_in[5],  *c1_bk = (const float*)d_in[6];
    const float *c1_wv = (const float*)d_in[7],  *c1_bv = (const float*)d_in[8];
    const float *c1_ws = (const float*)d_in[9],  *c1_bs = (const float*)d_in[10];
    const float *c2_wq = (const float*)d_in[11], *c2_bq = (const float*)d_in[12];
    const float *c2_wk = (const float*)d_in[13], *c2_bk = (const float*)d_in[14];
    const float *c2_wv = (const float*)d_in[15], *c2_bv = (const float*)d_in[16];
    const float *c2_ws = (const float*)d_in[17], *c2_bs = (const float*)d_in[18];
    const float *bn1_g = (const float*)d_in[19], *bn1_b = (const float*)d_in[20];
    const float *bn1_m = (const float*)d_in[21], *bn1_v = (const float*)d_in[22];
    const float *bn2_g = (const float*)d_in[23], *bn2_b = (const float*)d_in[24];
    const float *bn2_m = (const float*)d_in[25], *bn2_v = (const float*)d_in[26];
    const float *clbn_g = (const float*)d_in[27], *clbn_b = (const float*)d_in[28];
    const float *clbn_m = (const float*)d_in[29], *clbn_v = (const float*)d_in[30];
    const float *p1_w = (const float*)d_in[31], *p2_w = (const float*)d_in[32];
    const float *cl1_w = (const float*)d_in[33], *cl2_w = (const float*)d_in[34];
    const float *p1_b = (const float*)d_in[35], *p2_b = (const float*)d_in[36];
    const float *cl1_b = (const float*)d_in[37], *cl2_b = (const float*)d_in[38];

    char* ws = (char*)d_ws;
    float* qkvs = (float*)(ws);                         // 102,400,000 B
    float* h    = (float*)(ws + 102400000);             //  25,600,000 B
    int*   csr  = (int*)  (ws + 128000000);             //   6,400,000 B
    int*   deg  = (int*)  (ws + 134400000);             //     401,408 B
    int*   rowp = (int*)  (ws + 134801408);             //     401,408 B
    int*   curp = (int*)  (ws + 135202816);             //     401,408 B
    int*   bsum = (int*)  (ws + 135604224);             //         512 B
    float* g0   = (float*)(ws + 135604736);             //     131,072 B

    const int* srcIdx = ei;
    const int* dstIdx = ei + EE;

    hipMemsetAsync(deg, 0, SCAN_N * sizeof(int), stream);
    hipMemsetAsync(g0, 0, GG * 64 * sizeof(float), stream);

    // CSR build (shared by both conv layers)
    k_hist<<<(EE + 255) / 256, 256, 0, stream>>>(dstIdx, deg);
    k_scan1<<<98, 256, 0, stream>>>(deg, rowp, bsum);
    k_scan2<<<1, 128, 0, stream>>>(bsum);
    k_scan3<<<98, 256, 0, stream>>>(bsum, rowp, curp);
    k_scatter<<<(EE + 255) / 256, 256, 0, stream>>>(srcIdx, dstIdx, curp, csr);

    // Conv1
    gemm_qkvs<128><<<NN / 32, 256, 0, stream>>>(x, c1_wq, c1_bq, c1_wk, c1_bk,
                                                c1_wv, c1_bv, c1_ws, c1_bs, qkvs);
    attn_fused<<<NN / 4, 256, 0, stream>>>(qkvs, rowp, csr, bn1_g, bn1_b, bn1_m, bn1_v, h);

    // Conv2
    gemm_qkvs<64><<<NN / 32, 256, 0, stream>>>(h, c2_wq, c2_bq, c2_wk, c2_bk,
                                               c2_wv, c2_bv, c2_ws, c2_bs, qkvs);
    attn_fused<<<NN / 4, 256, 0, stream>>>(qkvs, rowp, csr, bn2_g, bn2_b, bn2_m, bn2_v, h);

    // Pool + MLP head
    k_pool<<<(NN + 127) / 128, 256, 0, stream>>>(h, batch, g0);
    k_mlp<<<GG / 4, 256, 0, stream>>>(g0, p1_w, p1_b, p2_w, p2_b, cl1_w, cl1_b,
                                      clbn_g, clbn_b, clbn_m, clbn_v, cl2_w, cl2_b,
                                      (float*)d_out);
}

// Round 2
// 734.074 us; speedup vs baseline: 1.0935x; 1.0935x over previous
//
#include <hip/hip_runtime.h>
#include <hip/hip_bf16.h>
#include <math.h>

// Problem constants
constexpr int NN = 100000;   // nodes
constexpr int EE = 1600000;  // edges
constexpr int GG = 512;      // graphs
constexpr int SCAN_N = 100352; // 98 * 1024 (padded scan domain)

__device__ __forceinline__ unsigned short f2bf_rne(float f) {
    unsigned int u = __float_as_uint(f);
    u += 0x7fff + ((u >> 16) & 1);
    return (unsigned short)(u >> 16);
}

// ---------------------------------------------------------------------------
// CSR build: histogram -> scan -> scatter
// ---------------------------------------------------------------------------
__global__ __launch_bounds__(256) void k_hist(const int* __restrict__ dst, int* __restrict__ deg) {
    int i = blockIdx.x * 256 + threadIdx.x;
    if (i < EE) atomicAdd(&deg[dst[i]], 1);
}

__global__ __launch_bounds__(256) void k_scan1(const int* __restrict__ deg,
                                               int* __restrict__ outp,
                                               int* __restrict__ bsum) {
    __shared__ int wsum[4];
    int tid = threadIdx.x, b = blockIdx.x;
    int base = b * 1024 + tid * 4;
    int4 v = *reinterpret_cast<const int4*>(deg + base);
    int t = v.x + v.y + v.z + v.w;
    int lane = tid & 63, w = tid >> 6;
    int sc = t;
    #pragma unroll
    for (int off = 1; off < 64; off <<= 1) {
        int n = __shfl_up(sc, off);
        if (lane >= off) sc += n;
    }
    if (lane == 63) wsum[w] = sc;
    __syncthreads();
    int woff = 0;
    for (int i = 0; i < 4; i++) if (i < w) woff += wsum[i];
    int excl = woff + sc - t;
    outp[base]     = excl;
    outp[base + 1] = excl + v.x;
    outp[base + 2] = excl + v.x + v.y;
    outp[base + 3] = excl + v.x + v.y + v.z;
    if (tid == 255) bsum[b] = woff + sc;
}

__global__ __launch_bounds__(128) void k_scan2(int* __restrict__ bsum) {
    __shared__ int wt[2];
    int tid = threadIdx.x;
    int v = (tid < 98) ? bsum[tid] : 0;
    int lane = tid & 63, w = tid >> 6;
    int sc = v;
    #pragma unroll
    for (int off = 1; off < 64; off <<= 1) {
        int n = __shfl_up(sc, off);
        if (lane >= off) sc += n;
    }
    if (lane == 63) wt[w] = sc;
    __syncthreads();
    int excl = sc - v + (w == 1 ? wt[0] : 0);
    if (tid < 98) bsum[tid] = excl;
}

__global__ __launch_bounds__(256) void k_scan3(const int* __restrict__ bsum,
                                               int* __restrict__ row_ptr,
                                               int* __restrict__ cursor) {
    int b = blockIdx.x, tid = threadIdx.x;
    int i = b * 1024 + tid * 4;
    int add = bsum[b];
    int4 v = *reinterpret_cast<const int4*>(row_ptr + i);
    int4 o; o.x = v.x + add; o.y = v.y + add; o.z = v.z + add; o.w = v.w + add;
    *reinterpret_cast<int4*>(row_ptr + i) = o;
    *reinterpret_cast<int4*>(cursor + i) = o;
}

__global__ __launch_bounds__(256) void k_scatter(const int* __restrict__ src,
                                                 const int* __restrict__ dst,
                                                 int* __restrict__ cursor,
                                                 int* __restrict__ csr_src) {
    int i = blockIdx.x * 256 + threadIdx.x;
    if (i < EE) {
        int pos = atomicAdd(&cursor[dst[i]], 1);
        csr_src[pos] = src[i];
    }
}

// ---------------------------------------------------------------------------
// Fused QKVS GEMM: [q|k|v|s] = X[N,K] @ W. Writes:
//   qs[N,128]  = [q(64) | s(64)]  fp32
//   kv[N,64]   = interleaved (k,v) bf16 pairs packed in uint32
// Tile: 32 rows x 256 cols per block (256 threads; thread = 4 rows x 8 cols)
// ---------------------------------------------------------------------------
template<int K>
__global__ __launch_bounds__(256) void gemm_qkvs(
    const float* __restrict__ X,
    const float* __restrict__ Wq, const float* __restrict__ Bq,
    const float* __restrict__ Wk, const float* __restrict__ Bk,
    const float* __restrict__ Wv, const float* __restrict__ Bv,
    const float* __restrict__ Wsk, const float* __restrict__ Bsk,
    float* __restrict__ qs, unsigned int* __restrict__ kv) {
    constexpr int BM = 32;
    constexpr int XP = K + 2;
    __shared__ float xs[BM * XP];
    __shared__ float ws[32 * 256];
    int tid = threadIdx.x;
    int rowBase = blockIdx.x * BM;
    int tc = tid & 31, tr = tid >> 5;

    {
        constexpr int TOT = BM * K / 4;
        const float4* Xv = reinterpret_cast<const float4*>(X + (size_t)rowBase * K);
        #pragma unroll
        for (int i = tid; i < TOT; i += 256) {
            int r = i / (K / 4), kq = i % (K / 4);
            float4 val = Xv[r * (K / 4) + kq];
            float* dp = &xs[r * XP + kq * 4];
            dp[0] = val.x; dp[1] = val.y; dp[2] = val.z; dp[3] = val.w;
        }
    }

    float acc[4][8];
    #pragma unroll
    for (int r = 0; r < 4; r++)
        #pragma unroll
        for (int c = 0; c < 8; c++) acc[r][c] = 0.f;

    for (int k0 = 0; k0 < K; k0 += 32) {
        __syncthreads();
        #pragma unroll
        for (int a = 0; a < 4; a++) {
            const float* wsrc = (a == 0) ? Wq : (a == 1) ? Wk : (a == 2) ? Wv : Wsk;
            #pragma unroll
            for (int i = 0; i < 2; i++) {
                int f4 = i * 256 + tid;
                int kk = f4 >> 4;
                int c  = (f4 & 15) * 4;
                float4 val = *reinterpret_cast<const float4*>(wsrc + (size_t)(k0 + kk) * 64 + c);
                *reinterpret_cast<float4*>(&ws[kk * 256 + a * 64 + c]) = val;
            }
        }
        __syncthreads();
        #pragma unroll
        for (int kk = 0; kk < 32; kk++) {
            float xr[4];
            #pragma unroll
            for (int r = 0; r < 4; r++) xr[r] = xs[(tr * 4 + r) * XP + k0 + kk];
            float4 w0 = *reinterpret_cast<const float4*>(&ws[kk * 256 + tc * 8]);
            float4 w1 = *reinterpret_cast<const float4*>(&ws[kk * 256 + tc * 8 + 4]);
            float wv8[8] = {w0.x, w0.y, w0.z, w0.w, w1.x, w1.y, w1.z, w1.w};
            #pragma unroll
            for (int r = 0; r < 4; r++)
                #pragma unroll
                for (int c = 0; c < 8; c++)
                    acc[r][c] += xr[r] * wv8[c];
        }
    }

    // Epilogue
    int cBase = tc * 8;
    int grp = cBase >> 6;
    int f0 = cBase & 63;
    const float* bp = (grp == 0) ? Bq : (grp == 1) ? Bk : (grp == 2) ? Bv : Bsk;
    float bias[8];
    #pragma unroll
    for (int c = 0; c < 8; c++) bias[c] = bp[f0 + c];
    unsigned short* kvu = reinterpret_cast<unsigned short*>(kv);
    #pragma unroll
    for (int r = 0; r < 4; r++) {
        int row = rowBase + tr * 4 + r;
        float o[8];
        #pragma unroll
        for (int c = 0; c < 8; c++) o[c] = acc[r][c] + bias[c];
        if (grp == 0 || grp == 3) {
            float* op = qs + (size_t)row * 128 + (grp == 3 ? 64 : 0) + f0;
            float4 o0 = {o[0], o[1], o[2], o[3]};
            float4 o1 = {o[4], o[5], o[6], o[7]};
            *reinterpret_cast<float4*>(op) = o0;
            *reinterpret_cast<float4*>(op + 4) = o1;
        } else {
            // grp1 = k -> low half, grp2 = v -> high half of uint32 pair
            int half = grp - 1;
            #pragma unroll
            for (int c = 0; c < 8; c++)
                kvu[((size_t)row * 64 + f0 + c) * 2 + half] = f2bf_rne(o[c]);
        }
    }
}

// ---------------------------------------------------------------------------
// Fused attention: one wave per dst node; lane = h*16+d.
// qs[N,128] = [q|skip] fp32; kv[N,64] = (k,v) bf16 pairs.
// ---------------------------------------------------------------------------
__global__ __launch_bounds__(256) void attn_fused(
    const float* __restrict__ qs,
    const unsigned int* __restrict__ kv,
    const int* __restrict__ row_ptr,
    const int* __restrict__ csr_src,
    const float* __restrict__ bng, const float* __restrict__ bnb,
    const float* __restrict__ bnm, const float* __restrict__ bnv,
    float* __restrict__ h_out) {
    int wid = (blockIdx.x * 256 + threadIdx.x) >> 6;
    int lane = threadIdx.x & 63;
    if (wid >= NN) return;
    // fold 1/sqrt(D)=0.25 and log2(e) into q: exp(x*0.25) = exp2(x*0.25*log2e)
    float q = qs[(size_t)wid * 128 + lane] * 0.3606737602222409f;
    float skip = qs[(size_t)wid * 128 + 64 + lane];
    int jb = row_ptr[wid], je = row_ptr[wid + 1];
    float acc = 0.f, denom = 0.f;
    int j = jb;
    for (; j + 3 < je; j += 4) {   // 4-edge ILP
        int s0 = csr_src[j], s1 = csr_src[j + 1];
        int s2 = csr_src[j + 2], s3 = csr_src[j + 3];
        unsigned int c0 = kv[(size_t)s0 * 64 + lane];
        unsigned int c1 = kv[(size_t)s1 * 64 + lane];
        unsigned int c2 = kv[(size_t)s2 * 64 + lane];
        unsigned int c3 = kv[(size_t)s3 * 64 + lane];
        float k0 = __uint_as_float(c0 << 16), v0 = __uint_as_float(c0 & 0xffff0000u);
        float k1 = __uint_as_float(c1 << 16), v1 = __uint_as_float(c1 & 0xffff0000u);
        float k2 = __uint_as_float(c2 << 16), v2 = __uint_as_float(c2 & 0xffff0000u);
        float k3 = __uint_as_float(c3 << 16), v3 = __uint_as_float(c3 & 0xffff0000u);
        float p0 = q * k0, p1 = q * k1, p2 = q * k2, p3 = q * k3;
        p0 += __shfl_xor(p0, 1); p1 += __shfl_xor(p1, 1); p2 += __shfl_xor(p2, 1); p3 += __shfl_xor(p3, 1);
        p0 += __shfl_xor(p0, 2); p1 += __shfl_xor(p1, 2); p2 += __shfl_xor(p2, 2); p3 += __shfl_xor(p3, 2);
        p0 += __shfl_xor(p0, 4); p1 += __shfl_xor(p1, 4); p2 += __shfl_xor(p2, 4); p3 += __shfl_xor(p3, 4);
        p0 += __shfl_xor(p0, 8); p1 += __shfl_xor(p1, 8); p2 += __shfl_xor(p2, 8); p3 += __shfl_xor(p3, 8);
        float e0 = exp2f(p0), e1 = exp2f(p1), e2 = exp2f(p2), e3 = exp2f(p3);
        denom += (e0 + e1) + (e2 + e3);
        acc = fmaf(e0, v0, acc);
        acc = fmaf(e1, v1, acc);
        acc = fmaf(e2, v2, acc);
        acc = fmaf(e3, v3, acc);
    }
    for (; j < je; j++) {
        int s0 = csr_src[j];
        unsigned int c0 = kv[(size_t)s0 * 64 + lane];
        float k0 = __uint_as_float(c0 << 16), v0 = __uint_as_float(c0 & 0xffff0000u);
        float p0 = q * k0;
        p0 += __shfl_xor(p0, 1);
        p0 += __shfl_xor(p0, 2);
        p0 += __shfl_xor(p0, 4);
        p0 += __shfl_xor(p0, 8);
        float e0 = exp2f(p0);
        denom += e0;
        acc = fmaf(e0, v0, acc);
    }
    float o = acc / (denom + 1e-16f) + skip;
    o = (o - bnm[lane]) * rsqrtf(bnv[lane] + 1e-5f) * bng[lane] + bnb[lane];
    h_out[(size_t)wid * 64 + lane] = fmaxf(o, 0.f);
}

// ---------------------------------------------------------------------------
// Global max pool over sorted batch ids (values are post-ReLU, >= 0).
// ---------------------------------------------------------------------------
__global__ __launch_bounds__(256) void k_pool(const float* __restrict__ h,
                                              const int* __restrict__ batch,
                                              float* __restrict__ g0) {
    int f = threadIdx.x & 63;
    int sub = threadIdx.x >> 6;
    int n0 = blockIdx.x * 128;
    int nEnd = n0 + 128; if (nEnd > NN) nEnd = NN;
    int cur_g = -1; float cur_m = 0.f;
    for (int n = n0 + sub; n < nEnd; n += 4) {
        int bg = batch[n];
        float val = h[(size_t)n * 64 + f];
        if (bg != cur_g) {
            if (cur_g >= 0) atomicMax((int*)&g0[cur_g * 64 + f], __float_as_int(cur_m));
            cur_g = bg; cur_m = val;
        } else {
            cur_m = fmaxf(cur_m, val);
        }
    }
    if (cur_g >= 0) atomicMax((int*)&g0[cur_g * 64 + f], __float_as_int(cur_m));
}

// ---------------------------------------------------------------------------
// Fused MLP head: 4 layers + BN + log_softmax. One wave per graph row.
// ---------------------------------------------------------------------------
__global__ __launch_bounds__(256) void k_mlp(
    const float* __restrict__ g0,
    const float* __restrict__ p1w, const float* __restrict__ p1b,
    const float* __restrict__ p2w, const float* __restrict__ p2b,
    const float* __restrict__ cl1w, const float* __restrict__ cl1b,
    const float* __restrict__ bg, const float* __restrict__ bb,
    const float* __restrict__ bm, const float* __restrict__ bv,
    const float* __restrict__ cl2w, const float* __restrict__ cl2b,
    float* __restrict__ outp) {
    __shared__ float w1[64 * 64], w2[64 * 64], w3[64 * 64], w4[64 * 10];
    __shared__ float sb1[64], sb2[64], sb3[64], sbn[4 * 64], sb4[10];
    int tid = threadIdx.x;
    for (int i = tid; i < 64 * 64; i += 256) { w1[i] = p1w[i]; w2[i] = p2w[i]; w3[i] = cl1w[i]; }
    for (int i = tid; i < 64 * 10; i += 256) w4[i] = cl2w[i];
    if (tid < 64) {
        sb1[tid] = p1b[tid]; sb2[tid] = p2b[tid]; sb3[tid] = cl1b[tid];
        sbn[tid] = bg[tid]; sbn[64 + tid] = bb[tid];
        sbn[128 + tid] = bm[tid]; sbn[192 + tid] = bv[tid];
    }
    if (tid < 10) sb4[tid] = cl2b[tid];
    __syncthreads();
    int lane = tid & 63, w = tid >> 6;
    int row = blockIdx.x * 4 + w;
    float x = g0[row * 64 + lane];
    if (!isfinite(x)) x = 0.f;
    float a = sb1[lane];
    for (int k = 0; k < 64; k++) a += __shfl(x, k) * w1[k * 64 + lane];
    x = fmaxf(a, 0.f);
    a = sb2[lane];
    for (int k = 0; k < 64; k++) a += __shfl(x, k) * w2[k * 64 + lane];
    x = a;
    a = sb3[lane];
    for (int k = 0; k < 64; k++) a += __shfl(x, k) * w3[k * 64 + lane];
    a = (a - sbn[128 + lane]) * rsqrtf(sbn[192 + lane] + 1e-5f) * sbn[lane] + sbn[64 + lane];
    x = fmaxf(a, 0.f);
    float lg[10];
    #pragma unroll
    for (int c = 0; c < 10; c++) {
        float p = x * w4[lane * 10 + c];
        p += __shfl_xor(p, 1);  p += __shfl_xor(p, 2);  p += __shfl_xor(p, 4);
        p += __shfl_xor(p, 8);  p += __shfl_xor(p, 16); p += __shfl_xor(p, 32);
        lg[c] = p + sb4[c];
    }
    float mx = lg[0];
    #pragma unroll
    for (int c = 1; c < 10; c++) mx = fmaxf(mx, lg[c]);
    float s = 0.f;
    #pragma unroll
    for (int c = 0; c < 10; c++) s += __expf(lg[c] - mx);
    float lse = mx + logf(s);
    float o = 0.f;
    #pragma unroll
    for (int c = 0; c < 10; c++) if (lane == c) o = lg[c];
    if (lane < 10) outp[row * 10 + lane] = o - lse;
}

// ---------------------------------------------------------------------------
extern "C" void kernel_launch(void* const* d_in, const int* in_sizes, int n_in,
                              void* d_out, int out_size, void* d_ws, size_t ws_size,
                              hipStream_t stream) {
    const float* x     = (const float*)d_in[0];
    const int*   ei    = (const int*)d_in[1];
    const int*   batch = (const int*)d_in[2];
    const float *c1_wq = (const float*)d_in[3],  *c1_bq = (const float*)d_in[4];
    const float *c1_wk = (const float*)d_in[5],  *c1_bk = (const float*)d_in[6];
    const float *c1_wv = (const float*)d_in[7],  *c1_bv = (const float*)d_in[8];
    const float *c1_ws = (const float*)d_in[9],  *c1_bs = (const float*)d_in[10];
    const float *c2_wq = (const float*)d_in[11], *c2_bq = (const float*)d_in[12];
    const float *c2_wk = (const float*)d_in[13], *c2_bk = (const float*)d_in[14];
    const float *c2_wv = (const float*)d_in[15], *c2_bv = (const float*)d_in[16];
    const float *c2_ws = (const float*)d_in[17], *c2_bs = (const float*)d_in[18];
    const float *bn1_g = (const float*)d_in[19], *bn1_b = (const float*)d_in[20];
    const float *bn1_m = (const float*)d_in[21], *bn1_v = (const float*)d_in[22];
    const float *bn2_g = (const float*)d_in[23], *bn2_b = (const float*)d_in[24];
    const float *bn2_m = (const float*)d_in[25], *bn2_v = (const float*)d_in[26];
    const float *clbn_g = (const float*)d_in[27], *clbn_b = (const float*)d_in[28];
    const float *clbn_m = (const float*)d_in[29], *clbn_v = (const float*)d_in[30];
    const float *p1_w = (const float*)d_in[31], *p2_w = (const float*)d_in[32];
    const float *cl1_w = (const float*)d_in[33], *cl2_w = (const float*)d_in[34];
    const float *p1_b = (const float*)d_in[35], *p2_b = (const float*)d_in[36];
    const float *cl1_b = (const float*)d_in[37], *cl2_b = (const float*)d_in[38];

    char* ws = (char*)d_ws;
    float*        qs   = (float*)(ws);                  //  51,200,000 B
    unsigned int* kv   = (unsigned int*)(ws + 51200000);//  25,600,000 B
    float*        h    = (float*)(ws + 76800000);       //  25,600,000 B
    int*          csr  = (int*)  (ws + 102400000);      //   6,400,000 B
    int*          deg  = (int*)  (ws + 108800000);      //     401,408 B
    int*          rowp = (int*)  (ws + 109201408);      //     401,408 B
    int*          curp = (int*)  (ws + 109602816);      //     401,408 B
    int*          bsum = (int*)  (ws + 110004224);      //         512 B
    float*        g0   = (float*)(ws + 110004736);      //     131,072 B

    const int* srcIdx = ei;
    const int* dstIdx = ei + EE;

    hipMemsetAsync(deg, 0, SCAN_N * sizeof(int), stream);
    hipMemsetAsync(g0, 0, GG * 64 * sizeof(float), stream);

    // CSR build (shared by both conv layers)
    k_hist<<<(EE + 255) / 256, 256, 0, stream>>>(dstIdx, deg);
    k_scan1<<<98, 256, 0, stream>>>(deg, rowp, bsum);
    k_scan2<<<1, 128, 0, stream>>>(bsum);
    k_scan3<<<98, 256, 0, stream>>>(bsum, rowp, curp);
    k_scatter<<<(EE + 255) / 256, 256, 0, stream>>>(srcIdx, dstIdx, curp, csr);

    // Conv1
    gemm_qkvs<128><<<NN / 32, 256, 0, stream>>>(x, c1_wq, c1_bq, c1_wk, c1_bk,
                                                c1_wv, c1_bv, c1_ws, c1_bs, qs, kv);
    attn_fused<<<NN / 4, 256, 0, stream>>>(qs, kv, rowp, csr, bn1_g, bn1_b, bn1_m, bn1_v, h);

    // Conv2
    gemm_qkvs<64><<<NN / 32, 256, 0, stream>>>(h, c2_wq, c2_bq, c2_wk, c2_bk,
                                               c2_wv, c2_bv, c2_ws, c2_bs, qs, kv);
    attn_fused<<<NN / 4, 256, 0, stream>>>(qs, kv, rowp, csr, bn2_g, bn2_b, bn2_m, bn2_v, h);

    // Pool + MLP head
    k_pool<<<(NN + 127) / 128, 256, 0, stream>>>(h, batch, g0);
    k_mlp<<<GG / 4, 256, 0, stream>>>(g0, p1_w, p1_b, p2_w, p2_b, cl1_w, cl1_b,
                                      clbn_g, clbn_b, clbn_m, clbn_v, cl2_w, cl2_b,
                                      (float*)d_out);
}

// Round 3
// 627.097 us; speedup vs baseline: 1.2800x; 1.1706x over previous
//
#include <hip/hip_runtime.h>
#include <hip/hip_bf16.h>
#include <math.h>

// Problem constants
constexpr int NN = 100000;   // nodes
constexpr int EE = 1600000;  // edges
constexpr int GG = 512;      // graphs
constexpr int SCAN_N = 100352; // 98 * 1024 (padded scan domain)
constexpr int MPAD = 100096; // 782 * 128 row-padded M

typedef __attribute__((ext_vector_type(8))) short short8;
typedef __attribute__((ext_vector_type(4))) float floatx4;

__device__ __forceinline__ unsigned short f2bf_rne(float f) {
    unsigned int u = __float_as_uint(f);
    u += 0x7fff + ((u >> 16) & 1);
    return (unsigned short)(u >> 16);
}

// ---------------------------------------------------------------------------
// CSR build: histogram -> scan -> scatter
// ---------------------------------------------------------------------------
__global__ __launch_bounds__(256) void k_hist(const int* __restrict__ dst, int* __restrict__ deg) {
    int i = blockIdx.x * 256 + threadIdx.x;
    if (i < EE) atomicAdd(&deg[dst[i]], 1);
}

__global__ __launch_bounds__(256) void k_scan1(const int* __restrict__ deg,
                                               int* __restrict__ outp,
                                               int* __restrict__ bsum) {
    __shared__ int wsum[4];
    int tid = threadIdx.x, b = blockIdx.x;
    int base = b * 1024 + tid * 4;
    int4 v = *reinterpret_cast<const int4*>(deg + base);
    int t = v.x + v.y + v.z + v.w;
    int lane = tid & 63, w = tid >> 6;
    int sc = t;
    #pragma unroll
    for (int off = 1; off < 64; off <<= 1) {
        int n = __shfl_up(sc, off);
        if (lane >= off) sc += n;
    }
    if (lane == 63) wsum[w] = sc;
    __syncthreads();
    int woff = 0;
    for (int i = 0; i < 4; i++) if (i < w) woff += wsum[i];
    int excl = woff + sc - t;
    outp[base]     = excl;
    outp[base + 1] = excl + v.x;
    outp[base + 2] = excl + v.x + v.y;
    outp[base + 3] = excl + v.x + v.y + v.z;
    if (tid == 255) bsum[b] = woff + sc;
}

__global__ __launch_bounds__(128) void k_scan2(int* __restrict__ bsum) {
    __shared__ int wt[2];
    int tid = threadIdx.x;
    int v = (tid < 98) ? bsum[tid] : 0;
    int lane = tid & 63, w = tid >> 6;
    int sc = v;
    #pragma unroll
    for (int off = 1; off < 64; off <<= 1) {
        int n = __shfl_up(sc, off);
        if (lane >= off) sc += n;
    }
    if (lane == 63) wt[w] = sc;
    __syncthreads();
    int excl = sc - v + (w == 1 ? wt[0] : 0);
    if (tid < 98) bsum[tid] = excl;
}

__global__ __launch_bounds__(256) void k_scan3(const int* __restrict__ bsum,
                                               int* __restrict__ row_ptr,
                                               int* __restrict__ cursor) {
    int b = blockIdx.x, tid = threadIdx.x;
    int i = b * 1024 + tid * 4;
    int add = bsum[b];
    int4 v = *reinterpret_cast<const int4*>(row_ptr + i);
    int4 o; o.x = v.x + add; o.y = v.y + add; o.z = v.z + add; o.w = v.w + add;
    *reinterpret_cast<int4*>(row_ptr + i) = o;
    *reinterpret_cast<int4*>(cursor + i) = o;
}

__global__ __launch_bounds__(256) void k_scatter(const int* __restrict__ src,
                                                 const int* __restrict__ dst,
                                                 int* __restrict__ cursor,
                                                 int* __restrict__ csr_src) {
    int i = blockIdx.x * 256 + threadIdx.x;
    if (i < EE) {
        int pos = atomicAdd(&cursor[dst[i]], 1);
        csr_src[pos] = src[i];
    }
}

// ---------------------------------------------------------------------------
// Convert x (fp32) -> bf16 rows
// ---------------------------------------------------------------------------
__global__ __launch_bounds__(256) void k_cvt_x(const float* __restrict__ x,
                                               unsigned short* __restrict__ xb) {
    int i = blockIdx.x * 256 + threadIdx.x;   // one float4 per thread
    float4 v = reinterpret_cast<const float4*>(x)[i];
    ushort4 o;
    o.x = f2bf_rne(v.x); o.y = f2bf_rne(v.y); o.z = f2bf_rne(v.z); o.w = f2bf_rne(v.w);
    reinterpret_cast<ushort4*>(xb)[i] = o;
}

// ---------------------------------------------------------------------------
// Pack weights: Bt[256][K] bf16, columns ordered [k0,v0,k1,v1,...,q(64),s(64)]
// bias[256] fp32 in same column order.
// ---------------------------------------------------------------------------
template<int K>
__global__ __launch_bounds__(256) void k_cvt_w(
    const float* __restrict__ Wq, const float* __restrict__ Bq,
    const float* __restrict__ Wk, const float* __restrict__ Bk,
    const float* __restrict__ Wv, const float* __restrict__ Bv,
    const float* __restrict__ Wsk, const float* __restrict__ Bsk,
    unsigned short* __restrict__ Bt, float* __restrict__ bias) {
    int idx = blockIdx.x * 256 + threadIdx.x;  // [0, 256*K)
    int col = idx / K, k = idx % K;
    float val;
    if (col < 128) {
        int f = col >> 1;
        val = (col & 1) ? Wv[k * 64 + f] : Wk[k * 64 + f];
    } else if (col < 192) {
        val = Wq[k * 64 + (col - 128)];
    } else {
        val = Wsk[k * 64 + (col - 192)];
    }
    Bt[col * K + k] = f2bf_rne(val);
    if (k == 0) {
        float bv;
        if (col < 128) {
            int f = col >> 1;
            bv = (col & 1) ? Bv[f] : Bk[f];
        } else if (col < 192) bv = Bq[col - 128];
        else bv = Bsk[col - 192];
        bias[col] = bv;
    }
}

// ---------------------------------------------------------------------------
// MFMA GEMM: A[MPAD][K] bf16 @ Bt[256][K] bf16 -> col-tile 0: kv bf16 pairs,
// col-tile 1: qs fp32 [q|s]. 128x128 tile, 4 waves (2x2), 64-k LDS chunks.
// ---------------------------------------------------------------------------
template<int K>
__global__ __launch_bounds__(256) void gemm_mfma(
    const unsigned short* __restrict__ A,
    const unsigned short* __restrict__ Bt,
    const float* __restrict__ bias,
    float* __restrict__ qs,
    unsigned short* __restrict__ kvu) {
    constexpr int SP = 72;                    // 64 + 8 pad (bf16 elts)
    __shared__ short As[128 * SP];            // 18432 B
    __shared__ short Bs[128 * SP];            // 18432 B
    int tid = threadIdx.x;
    int wave = tid >> 6, lane = tid & 63;
    int wm = wave >> 1, wn = wave & 1;
    int quad = lane >> 4, l16 = lane & 15;
    int rowBase = blockIdx.x * 128;
    int ct = blockIdx.y;                      // 0: kv cols, 1: q|s cols

    floatx4 acc[4][4];
    #pragma unroll
    for (int i = 0; i < 4; i++)
        #pragma unroll
        for (int j = 0; j < 4; j++) acc[i][j] = (floatx4)0.f;

    for (int kc = 0; kc < K; kc += 64) {
        // Stage A chunk: 128 rows x 64 k (16 B per thread x 4 iters)
        #pragma unroll
        for (int it = 0; it < 4; it++) {
            int flat = it * 256 + tid;        // [0,1024)
            int r = flat >> 3, c8 = (flat & 7) * 8;
            short8 va = *reinterpret_cast<const short8*>(A + (size_t)(rowBase + r) * K + kc + c8);
            *reinterpret_cast<short8*>(&As[r * SP + c8]) = va;
            short8 vb = *reinterpret_cast<const short8*>(Bt + (size_t)(ct * 128 + r) * K + kc + c8);
            *reinterpret_cast<short8*>(&Bs[r * SP + c8]) = vb;
        }
        __syncthreads();
        #pragma unroll
        for (int ks = 0; ks < 2; ks++) {
            short8 af[4], bf[4];
            #pragma unroll
            for (int i = 0; i < 4; i++)
                af[i] = *reinterpret_cast<const short8*>(&As[(wm * 64 + i * 16 + l16) * SP + ks * 32 + quad * 8]);
            #pragma unroll
            for (int j = 0; j < 4; j++)
                bf[j] = *reinterpret_cast<const short8*>(&Bs[(wn * 64 + j * 16 + l16) * SP + ks * 32 + quad * 8]);
            #pragma unroll
            for (int i = 0; i < 4; i++)
                #pragma unroll
                for (int j = 0; j < 4; j++)
                    acc[i][j] = __builtin_amdgcn_mfma_f32_16x16x32_bf16(af[i], bf[j], acc[i][j], 0, 0, 0);
        }
        __syncthreads();
    }

    // Epilogue: bias + store. C layout: col = lane&15 (within n-tile), row = quad*4 + reg.
    float bj[4];
    #pragma unroll
    for (int j = 0; j < 4; j++) bj[j] = bias[ct * 128 + wn * 64 + j * 16 + l16];
    #pragma unroll
    for (int i = 0; i < 4; i++) {
        #pragma unroll
        for (int j = 0; j < 4; j++) {
            int col = wn * 64 + j * 16 + l16;
            #pragma unroll
            for (int r = 0; r < 4; r++) {
                int row = rowBase + wm * 64 + i * 16 + quad * 4 + r;
                if (row < NN) {
                    float val = acc[i][j][r] + bj[j];
                    if (ct == 1) qs[(size_t)row * 128 + col] = val;
                    else kvu[(size_t)row * 128 + col] = f2bf_rne(val);
                }
            }
        }
    }
}

// ---------------------------------------------------------------------------
// Fused attention: one wave per dst node; lane = h*16+d.
// qs[N,128] = [q|skip] fp32; kv[N,64] = (k,v) bf16 pairs. h out bf16.
// ---------------------------------------------------------------------------
__global__ __launch_bounds__(256) void attn_fused(
    const float* __restrict__ qs,
    const unsigned int* __restrict__ kv,
    const int* __restrict__ row_ptr,
    const int* __restrict__ csr_src,
    const float* __restrict__ bng, const float* __restrict__ bnb,
    const float* __restrict__ bnm, const float* __restrict__ bnv,
    unsigned short* __restrict__ h_out) {
    int wid = (blockIdx.x * 256 + threadIdx.x) >> 6;
    int lane = threadIdx.x & 63;
    if (wid >= NN) return;
    // fold 1/sqrt(D)=0.25 and log2(e) into q: exp(x*0.25) = exp2(x*0.25*log2e)
    float q = qs[(size_t)wid * 128 + lane] * 0.3606737602222409f;
    float skip = qs[(size_t)wid * 128 + 64 + lane];
    int jb = row_ptr[wid], je = row_ptr[wid + 1];
    float acc = 0.f, denom = 0.f;
    int j = jb;
    for (; j + 3 < je; j += 4) {   // 4-edge ILP
        int s0 = csr_src[j], s1 = csr_src[j + 1];
        int s2 = csr_src[j + 2], s3 = csr_src[j + 3];
        unsigned int c0 = kv[(size_t)s0 * 64 + lane];
        unsigned int c1 = kv[(size_t)s1 * 64 + lane];
        unsigned int c2 = kv[(size_t)s2 * 64 + lane];
        unsigned int c3 = kv[(size_t)s3 * 64 + lane];
        float k0 = __uint_as_float(c0 << 16), v0 = __uint_as_float(c0 & 0xffff0000u);
        float k1 = __uint_as_float(c1 << 16), v1 = __uint_as_float(c1 & 0xffff0000u);
        float k2 = __uint_as_float(c2 << 16), v2 = __uint_as_float(c2 & 0xffff0000u);
        float k3 = __uint_as_float(c3 << 16), v3 = __uint_as_float(c3 & 0xffff0000u);
        float p0 = q * k0, p1 = q * k1, p2 = q * k2, p3 = q * k3;
        p0 += __shfl_xor(p0, 1); p1 += __shfl_xor(p1, 1); p2 += __shfl_xor(p2, 1); p3 += __shfl_xor(p3, 1);
        p0 += __shfl_xor(p0, 2); p1 += __shfl_xor(p1, 2); p2 += __shfl_xor(p2, 2); p3 += __shfl_xor(p3, 2);
        p0 += __shfl_xor(p0, 4); p1 += __shfl_xor(p1, 4); p2 += __shfl_xor(p2, 4); p3 += __shfl_xor(p3, 4);
        p0 += __shfl_xor(p0, 8); p1 += __shfl_xor(p1, 8); p2 += __shfl_xor(p2, 8); p3 += __shfl_xor(p3, 8);
        float e0 = exp2f(p0), e1 = exp2f(p1), e2 = exp2f(p2), e3 = exp2f(p3);
        denom += (e0 + e1) + (e2 + e3);
        acc = fmaf(e0, v0, acc);
        acc = fmaf(e1, v1, acc);
        acc = fmaf(e2, v2, acc);
        acc = fmaf(e3, v3, acc);
    }
    for (; j < je; j++) {
        int s0 = csr_src[j];
        unsigned int c0 = kv[(size_t)s0 * 64 + lane];
        float k0 = __uint_as_float(c0 << 16), v0 = __uint_as_float(c0 & 0xffff0000u);
        float p0 = q * k0;
        p0 += __shfl_xor(p0, 1);
        p0 += __shfl_xor(p0, 2);
        p0 += __shfl_xor(p0, 4);
        p0 += __shfl_xor(p0, 8);
        float e0 = exp2f(p0);
        denom += e0;
        acc = fmaf(e0, v0, acc);
    }
    float o = acc / (denom + 1e-16f) + skip;
    o = (o - bnm[lane]) * rsqrtf(bnv[lane] + 1e-5f) * bng[lane] + bnb[lane];
    h_out[(size_t)wid * 64 + lane] = f2bf_rne(fmaxf(o, 0.f));
}

// ---------------------------------------------------------------------------
// Global max pool over sorted batch ids (values are post-ReLU, >= 0). h bf16.
// ---------------------------------------------------------------------------
__global__ __launch_bounds__(256) void k_pool(const unsigned short* __restrict__ h,
                                              const int* __restrict__ batch,
                                              float* __restrict__ g0) {
    int f = threadIdx.x & 63;
    int sub = threadIdx.x >> 6;
    int n0 = blockIdx.x * 128;
    int nEnd = n0 + 128; if (nEnd > NN) nEnd = NN;
    int cur_g = -1; float cur_m = 0.f;
    for (int n = n0 + sub; n < nEnd; n += 4) {
        int bg = batch[n];
        float val = __uint_as_float((unsigned int)h[(size_t)n * 64 + f] << 16);
        if (bg != cur_g) {
            if (cur_g >= 0) atomicMax((int*)&g0[cur_g * 64 + f], __float_as_int(cur_m));
            cur_g = bg; cur_m = val;
        } else {
            cur_m = fmaxf(cur_m, val);
        }
    }
    if (cur_g >= 0) atomicMax((int*)&g0[cur_g * 64 + f], __float_as_int(cur_m));
}

// ---------------------------------------------------------------------------
// Fused MLP head: 4 layers + BN + log_softmax. One wave per graph row.
// ---------------------------------------------------------------------------
__global__ __launch_bounds__(256) void k_mlp(
    const float* __restrict__ g0,
    const float* __restrict__ p1w, const float* __restrict__ p1b,
    const float* __restrict__ p2w, const float* __restrict__ p2b,
    const float* __restrict__ cl1w, const float* __restrict__ cl1b,
    const float* __restrict__ bg, const float* __restrict__ bb,
    const float* __restrict__ bm, const float* __restrict__ bv,
    const float* __restrict__ cl2w, const float* __restrict__ cl2b,
    float* __restrict__ outp) {
    __shared__ float w1[64 * 64], w2[64 * 64], w3[64 * 64], w4[64 * 10];
    __shared__ float sb1[64], sb2[64], sb3[64], sbn[4 * 64], sb4[10];
    int tid = threadIdx.x;
    for (int i = tid; i < 64 * 64; i += 256) { w1[i] = p1w[i]; w2[i] = p2w[i]; w3[i] = cl1w[i]; }
    for (int i = tid; i < 64 * 10; i += 256) w4[i] = cl2w[i];
    if (tid < 64) {
        sb1[tid] = p1b[tid]; sb2[tid] = p2b[tid]; sb3[tid] = cl1b[tid];
        sbn[tid] = bg[tid]; sbn[64 + tid] = bb[tid];
        sbn[128 + tid] = bm[tid]; sbn[192 + tid] = bv[tid];
    }
    if (tid < 10) sb4[tid] = cl2b[tid];
    __syncthreads();
    int lane = tid & 63, w = tid >> 6;
    int row = blockIdx.x * 4 + w;
    float x = g0[row * 64 + lane];
    if (!isfinite(x)) x = 0.f;
    float a = sb1[lane];
    for (int k = 0; k < 64; k++) a += __shfl(x, k) * w1[k * 64 + lane];
    x = fmaxf(a, 0.f);
    a = sb2[lane];
    for (int k = 0; k < 64; k++) a += __shfl(x, k) * w2[k * 64 + lane];
    x = a;
    a = sb3[lane];
    for (int k = 0; k < 64; k++) a += __shfl(x, k) * w3[k * 64 + lane];
    a = (a - sbn[128 + lane]) * rsqrtf(sbn[192 + lane] + 1e-5f) * sbn[lane] + sbn[64 + lane];
    x = fmaxf(a, 0.f);
    float lg[10];
    #pragma unroll
    for (int c = 0; c < 10; c++) {
        float p = x * w4[lane * 10 + c];
        p += __shfl_xor(p, 1);  p += __shfl_xor(p, 2);  p += __shfl_xor(p, 4);
        p += __shfl_xor(p, 8);  p += __shfl_xor(p, 16); p += __shfl_xor(p, 32);
        lg[c] = p + sb4[c];
    }
    float mx = lg[0];
    #pragma unroll
    for (int c = 1; c < 10; c++) mx = fmaxf(mx, lg[c]);
    float s = 0.f;
    #pragma unroll
    for (int c = 0; c < 10; c++) s += __expf(lg[c] - mx);
    float lse = mx + logf(s);
    float o = 0.f;
    #pragma unroll
    for (int c = 0; c < 10; c++) if (lane == c) o = lg[c];
    if (lane < 10) outp[row * 10 + lane] = o - lse;
}

// ---------------------------------------------------------------------------
extern "C" void kernel_launch(void* const* d_in, const int* in_sizes, int n_in,
                              void* d_out, int out_size, void* d_ws, size_t ws_size,
                              hipStream_t stream) {
    const float* x     = (const float*)d_in[0];
    const int*   ei    = (const int*)d_in[1];
    const int*   batch = (const int*)d_in[2];
    const float *c1_wq = (const float*)d_in[3],  *c1_bq = (const float*)d_in[4];
    const float *c1_wk = (const float*)d_in[5],  *c1_bk = (const float*)d_in[6];
    const float *c1_wv = (const float*)d_in[7],  *c1_bv = (const float*)d_in[8];
    const float *c1_ws = (const float*)d_in[9],  *c1_bs = (const float*)d_in[10];
    const float *c2_wq = (const float*)d_in[11], *c2_bq = (const float*)d_in[12];
    const float *c2_wk = (const float*)d_in[13], *c2_bk = (const float*)d_in[14];
    const float *c2_wv = (const float*)d_in[15], *c2_bv = (const float*)d_in[16];
    const float *c2_ws = (const float*)d_in[17], *c2_bs = (const float*)d_in[18];
    const float *bn1_g = (const float*)d_in[19], *bn1_b = (const float*)d_in[20];
    const float *bn1_m = (const float*)d_in[21], *bn1_v = (const float*)d_in[22];
    const float *bn2_g = (const float*)d_in[23], *bn2_b = (const float*)d_in[24];
    const float *bn2_m = (const float*)d_in[25], *bn2_v = (const float*)d_in[26];
    const float *clbn_g = (const float*)d_in[27], *clbn_b = (const float*)d_in[28];
    const float *clbn_m = (const float*)d_in[29], *clbn_v = (const float*)d_in[30];
    const float *p1_w = (const float*)d_in[31], *p2_w = (const float*)d_in[32];
    const float *cl1_w = (const float*)d_in[33], *cl2_w = (const float*)d_in[34];
    const float *p1_b = (const float*)d_in[35], *p2_b = (const float*)d_in[36];
    const float *cl1_b = (const float*)d_in[37], *cl2_b = (const float*)d_in[38];

    char* ws = (char*)d_ws;
    float*          qs   = (float*)(ws);                         // 51,200,000
    unsigned int*   kv   = (unsigned int*)(ws + 51200000);       // 25,600,000
    unsigned short* xb   = (unsigned short*)(ws + 76800000);     // 25,624,576 (MPAD x 128)
    unsigned short* hbuf = (unsigned short*)(ws + 76800000);     // aliases xb (xb dead after gemm1)
    int*            csr  = (int*)(ws + 102424576);               //  6,400,000
    int*            deg  = (int*)(ws + 108824576);               //    401,408 (aliased as cursor)
    int*            rowp = (int*)(ws + 109225984);               //    401,408
    int*            bsum = (int*)(ws + 109627392);               //        512
    float*          g0   = (float*)(ws + 109627904);             //    131,072
    unsigned short* Bt1  = (unsigned short*)(ws + 109758976);    //     65,536
    float*          b1   = (float*)(ws + 109824512);             //      1,024
    unsigned short* Bt2  = (unsigned short*)(ws + 109825536);    //     32,768
    float*          b2   = (float*)(ws + 109858304);             //      1,024

    const int* srcIdx = ei;
    const int* dstIdx = ei + EE;

    hipMemsetAsync(deg, 0, SCAN_N * sizeof(int), stream);
    hipMemsetAsync(g0, 0, GG * 64 * sizeof(float), stream);

    // CSR build (deg buffer is reused as the scatter cursor)
    k_hist<<<(EE + 255) / 256, 256, 0, stream>>>(dstIdx, deg);
    k_scan1<<<98, 256, 0, stream>>>(deg, rowp, bsum);
    k_scan2<<<1, 128, 0, stream>>>(bsum);
    k_scan3<<<98, 256, 0, stream>>>(bsum, rowp, deg);
    k_scatter<<<(EE + 255) / 256, 256, 0, stream>>>(srcIdx, dstIdx, deg, csr);

    // Weight packing + x conversion
    k_cvt_w<128><<<128, 256, 0, stream>>>(c1_wq, c1_bq, c1_wk, c1_bk, c1_wv, c1_bv,
                                          c1_ws, c1_bs, Bt1, b1);
    k_cvt_w<64><<<64, 256, 0, stream>>>(c2_wq, c2_bq, c2_wk, c2_bk, c2_wv, c2_bv,
                                        c2_ws, c2_bs, Bt2, b2);
    k_cvt_x<<<12500, 256, 0, stream>>>(x, xb);

    // Conv1
    {
        dim3 grid(MPAD / 128, 2);
        gemm_mfma<128><<<grid, 256, 0, stream>>>(xb, Bt1, b1, qs, (unsigned short*)kv);
    }
    attn_fused<<<NN / 4, 256, 0, stream>>>(qs, kv, rowp, csr, bn1_g, bn1_b, bn1_m, bn1_v, hbuf);

    // Conv2
    {
        dim3 grid(MPAD / 128, 2);
        gemm_mfma<64><<<grid, 256, 0, stream>>>(hbuf, Bt2, b2, qs, (unsigned short*)kv);
    }
    attn_fused<<<NN / 4, 256, 0, stream>>>(qs, kv, rowp, csr, bn2_g, bn2_b, bn2_m, bn2_v, hbuf);

    // Pool + MLP head
    k_pool<<<(NN + 127) / 128, 256, 0, stream>>>(hbuf, batch, g0);
    k_mlp<<<GG / 4, 256, 0, stream>>>(g0, p1_w, p1_b, p2_w, p2_b, cl1_w, cl1_b,
                                      clbn_g, clbn_b, clbn_m, clbn_v, cl2_w, cl2_b,
                                      (float*)d_out);
}

// Round 4
// 484.422 us; speedup vs baseline: 1.6570x; 1.2945x over previous
//
#include <hip/hip_runtime.h>
#include <hip/hip_bf16.h>
#include <math.h>

// Problem constants
constexpr int NN = 100000;   // nodes
constexpr int EE = 1600000;  // edges
constexpr int GG = 512;      // graphs
constexpr int MPAD = 100096; // 782 * 128 row-padded M
constexpr int NBUCK = 782;   // MPAD / 128 coarse buckets (128 nodes each)
constexpr int EPB = 8192;    // edges per partition block

typedef __attribute__((ext_vector_type(8))) short short8;
typedef __attribute__((ext_vector_type(4))) float floatx4;

__device__ __forceinline__ unsigned short f2bf_rne(float f) {
    unsigned int u = __float_as_uint(f);
    u += 0x7fff + ((u >> 16) & 1);
    return (unsigned short)(u >> 16);
}

// ---------------------------------------------------------------------------
// CSR build via two-level counting sort (no random-scatter write amplification)
// ---------------------------------------------------------------------------
__global__ __launch_bounds__(512) void k_bhist(const int* __restrict__ dst,
                                               int* __restrict__ bcnt) {
    __shared__ int cnt[NBUCK];
    int tid = threadIdx.x;
    int e0 = blockIdx.x * EPB;
    for (int j = tid; j < NBUCK; j += 512) cnt[j] = 0;
    __syncthreads();
    #pragma unroll
    for (int t = 0; t < 16; t++) {
        int i = e0 + t * 512 + tid;
        if (i < EE) atomicAdd(&cnt[dst[i] >> 7], 1);
    }
    __syncthreads();
    for (int j = tid; j < NBUCK; j += 512) if (cnt[j]) atomicAdd(&bcnt[j], cnt[j]);
}

__global__ __launch_bounds__(1024) void k_bscan(const int* __restrict__ bcnt,
                                                int* __restrict__ bbase,
                                                int* __restrict__ bcur) {
    __shared__ int sa[1024], sb[1024];
    int t = threadIdx.x;
    sa[t] = (t < NBUCK) ? bcnt[t] : 0;
    __syncthreads();
    int* p = sa; int* q = sb;
    for (int off = 1; off < 1024; off <<= 1) {
        q[t] = (t >= off) ? (p[t] + p[t - off]) : p[t];
        __syncthreads();
        int* tmp = p; p = q; q = tmp;
    }
    int excl = (t == 0) ? 0 : p[t - 1];
    if (t < NBUCK) { bbase[t] = excl; bcur[t] = excl; }
    if (t == NBUCK - 1) bbase[NBUCK] = p[NBUCK - 1];
}

__global__ __launch_bounds__(512) void k_part(const int* __restrict__ src,
                                              const int* __restrict__ dst,
                                              int* __restrict__ bcur,
                                              int2* __restrict__ ppair) {
    __shared__ int cnt[NBUCK];
    __shared__ int base[NBUCK];
    int tid = threadIdx.x;
    int e0 = blockIdx.x * EPB;
    for (int j = tid; j < NBUCK; j += 512) cnt[j] = 0;
    __syncthreads();
    int myd[16], myr[16];
    #pragma unroll
    for (int t = 0; t < 16; t++) {
        int i = e0 + t * 512 + tid;
        if (i < EE) {
            int d = dst[i];
            myd[t] = d;
            myr[t] = atomicAdd(&cnt[d >> 7], 1);
        } else myd[t] = -1;
    }
    __syncthreads();
    for (int j = tid; j < NBUCK; j += 512) base[j] = atomicAdd(&bcur[j], cnt[j]);
    __syncthreads();
    #pragma unroll
    for (int t = 0; t < 16; t++) {
        int i = e0 + t * 512 + tid;
        if (myd[t] >= 0) {
            int2 pr; pr.x = src[i]; pr.y = myd[t];
            ppair[base[myd[t] >> 7] + myr[t]] = pr;
        }
    }
}

// One block per bucket: counting sort by exact dst; writes rowp and csr.
__global__ __launch_bounds__(256) void k_bucket(const int2* __restrict__ ppair,
                                                const int* __restrict__ bbase,
                                                int* __restrict__ rowp,
                                                int* __restrict__ csr) {
    __shared__ int cnt[128];
    __shared__ int sa[128], sb[128];
    __shared__ int cur[128];
    int t = threadIdx.x;
    int b = blockIdx.x;
    int start = bbase[b], end = bbase[b + 1];
    if (t < 128) cnt[t] = 0;
    __syncthreads();
    for (int i = start + t; i < end; i += 256)
        atomicAdd(&cnt[ppair[i].y & 127], 1);
    __syncthreads();
    if (t < 128) sa[t] = cnt[t];
    __syncthreads();
    int* p = sa; int* q = sb;
    for (int off = 1; off < 128; off <<= 1) {
        if (t < 128) q[t] = (t >= off) ? (p[t] + p[t - off]) : p[t];
        __syncthreads();
        int* tmp = p; p = q; q = tmp;
    }
    if (t < 128) {
        int excl = (t == 0) ? 0 : p[t - 1];
        rowp[b * 128 + t] = start + excl;
        cur[t] = start + excl;
    }
    __syncthreads();
    for (int i = start + t; i < end; i += 256) {
        int2 e = ppair[i];
        int pos = atomicAdd(&cur[e.y & 127], 1);
        csr[pos] = e.x;
    }
}

// ---------------------------------------------------------------------------
// Pack weights: Bt[256][K] bf16, columns ordered [k0,v0,k1,v1,...,q(64),s(64)]
// bias[256] fp32 in same column order.
// ---------------------------------------------------------------------------
template<int K>
__global__ __launch_bounds__(256) void k_cvt_w(
    const float* __restrict__ Wq, const float* __restrict__ Bq,
    const float* __restrict__ Wk, const float* __restrict__ Bk,
    const float* __restrict__ Wv, const float* __restrict__ Bv,
    const float* __restrict__ Wsk, const float* __restrict__ Bsk,
    unsigned short* __restrict__ Bt, float* __restrict__ bias) {
    int idx = blockIdx.x * 256 + threadIdx.x;  // [0, 256*K)
    int col = idx / K, k = idx % K;
    float val;
    if (col < 128) {
        int f = col >> 1;
        val = (col & 1) ? Wv[k * 64 + f] : Wk[k * 64 + f];
    } else if (col < 192) {
        val = Wq[k * 64 + (col - 128)];
    } else {
        val = Wsk[k * 64 + (col - 192)];
    }
    Bt[col * K + k] = f2bf_rne(val);
    if (k == 0) {
        float bv;
        if (col < 128) {
            int f = col >> 1;
            bv = (col & 1) ? Bv[f] : Bk[f];
        } else if (col < 192) bv = Bq[col - 128];
        else bv = Bsk[col - 192];
        bias[col] = bv;
    }
}

// ---------------------------------------------------------------------------
// MFMA GEMM: A[M][K] (fp32 or bf16) @ Bt[256][K] bf16 ->
//   col-tile 0: kv bf16 pairs, col-tile 1: qs fp32 [q|s].
// 128x128 tile, 4 waves (2x2), 64-k LDS chunks.
// ---------------------------------------------------------------------------
template<int K, bool AF32>
__global__ __launch_bounds__(256) void gemm_mfma(
    const void* __restrict__ Araw,
    const unsigned short* __restrict__ Bt,
    const float* __restrict__ bias,
    float* __restrict__ qs,
    unsigned short* __restrict__ kvu) {
    constexpr int SP = 72;                    // 64 + 8 pad (bf16 elts)
    __shared__ short As[128 * SP];            // 18432 B
    __shared__ short Bs[128 * SP];            // 18432 B
    int tid = threadIdx.x;
    int wave = tid >> 6, lane = tid & 63;
    int wm = wave >> 1, wn = wave & 1;
    int quad = lane >> 4, l16 = lane & 15;
    int rowBase = blockIdx.x * 128;
    int ct = blockIdx.y;                      // 0: kv cols, 1: q|s cols

    floatx4 acc[4][4];
    #pragma unroll
    for (int i = 0; i < 4; i++)
        #pragma unroll
        for (int j = 0; j < 4; j++) acc[i][j] = (floatx4)0.f;

    for (int kc = 0; kc < K; kc += 64) {
        #pragma unroll
        for (int it = 0; it < 4; it++) {
            int flat = it * 256 + tid;        // [0,1024)
            int r = flat >> 3, c8 = (flat & 7) * 8;
            int ar = rowBase + r; if (ar >= NN) ar = NN - 1;   // clamp: no OOB reads
            short8 va;
            if constexpr (AF32) {
                const float* ap = (const float*)Araw + (size_t)ar * K + kc + c8;
                float4 u0 = *reinterpret_cast<const float4*>(ap);
                float4 u1 = *reinterpret_cast<const float4*>(ap + 4);
                va[0] = (short)f2bf_rne(u0.x); va[1] = (short)f2bf_rne(u0.y);
                va[2] = (short)f2bf_rne(u0.z); va[3] = (short)f2bf_rne(u0.w);
                va[4] = (short)f2bf_rne(u1.x); va[5] = (short)f2bf_rne(u1.y);
                va[6] = (short)f2bf_rne(u1.z); va[7] = (short)f2bf_rne(u1.w);
            } else {
                va = *reinterpret_cast<const short8*>(
                        (const unsigned short*)Araw + (size_t)ar * K + kc + c8);
            }
            *reinterpret_cast<short8*>(&As[r * SP + c8]) = va;
            short8 vb = *reinterpret_cast<const short8*>(Bt + (size_t)(ct * 128 + r) * K + kc + c8);
            *reinterpret_cast<short8*>(&Bs[r * SP + c8]) = vb;
        }
        __syncthreads();
        #pragma unroll
        for (int ks = 0; ks < 2; ks++) {
            short8 af[4], bf[4];
            #pragma unroll
            for (int i = 0; i < 4; i++)
                af[i] = *reinterpret_cast<const short8*>(&As[(wm * 64 + i * 16 + l16) * SP + ks * 32 + quad * 8]);
            #pragma unroll
            for (int j = 0; j < 4; j++)
                bf[j] = *reinterpret_cast<const short8*>(&Bs[(wn * 64 + j * 16 + l16) * SP + ks * 32 + quad * 8]);
            #pragma unroll
            for (int i = 0; i < 4; i++)
                #pragma unroll
                for (int j = 0; j < 4; j++)
                    acc[i][j] = __builtin_amdgcn_mfma_f32_16x16x32_bf16(af[i], bf[j], acc[i][j], 0, 0, 0);
        }
        __syncthreads();
    }

    // Epilogue: bias + store. C layout: col = lane&15 (within n-tile), row = quad*4 + reg.
    float bj[4];
    #pragma unroll
    for (int j = 0; j < 4; j++) bj[j] = bias[ct * 128 + wn * 64 + j * 16 + l16];
    #pragma unroll
    for (int i = 0; i < 4; i++) {
        #pragma unroll
        for (int j = 0; j < 4; j++) {
            int col = wn * 64 + j * 16 + l16;
            #pragma unroll
            for (int r = 0; r < 4; r++) {
                int row = rowBase + wm * 64 + i * 16 + quad * 4 + r;
                if (row < NN) {
                    float val = acc[i][j][r] + bj[j];
                    if (ct == 1) qs[(size_t)row * 128 + col] = val;
                    else kvu[(size_t)row * 128 + col] = f2bf_rne(val);
                }
            }
        }
    }
}

// ---------------------------------------------------------------------------
// Fused attention: one wave per dst node; lane = h*16+d.
// qs[N,128] = [q|skip] fp32; kv[N,64] = (k,v) bf16 pairs. h out bf16.
// ---------------------------------------------------------------------------
__global__ __launch_bounds__(256) void attn_fused(
    const float* __restrict__ qs,
    const unsigned int* __restrict__ kv,
    const int* __restrict__ row_ptr,
    const int* __restrict__ csr_src,
    const float* __restrict__ bng, const float* __restrict__ bnb,
    const float* __restrict__ bnm, const float* __restrict__ bnv,
    unsigned short* __restrict__ h_out) {
    int wid = (blockIdx.x * 256 + threadIdx.x) >> 6;
    int lane = threadIdx.x & 63;
    if (wid >= NN) return;
    // fold 1/sqrt(D)=0.25 and log2(e) into q: exp(x*0.25) = exp2(x*0.25*log2e)
    float q = qs[(size_t)wid * 128 + lane] * 0.3606737602222409f;
    float skip = qs[(size_t)wid * 128 + 64 + lane];
    int jb = row_ptr[wid], je = row_ptr[wid + 1];
    float acc = 0.f, denom = 0.f;
    int j = jb;
    for (; j + 3 < je; j += 4) {   // 4-edge ILP
        int s0 = csr_src[j], s1 = csr_src[j + 1];
        int s2 = csr_src[j + 2], s3 = csr_src[j + 3];
        unsigned int c0 = kv[(size_t)s0 * 64 + lane];
        unsigned int c1 = kv[(size_t)s1 * 64 + lane];
        unsigned int c2 = kv[(size_t)s2 * 64 + lane];
        unsigned int c3 = kv[(size_t)s3 * 64 + lane];
        float k0 = __uint_as_float(c0 << 16), v0 = __uint_as_float(c0 & 0xffff0000u);
        float k1 = __uint_as_float(c1 << 16), v1 = __uint_as_float(c1 & 0xffff0000u);
        float k2 = __uint_as_float(c2 << 16), v2 = __uint_as_float(c2 & 0xffff0000u);
        float k3 = __uint_as_float(c3 << 16), v3 = __uint_as_float(c3 & 0xffff0000u);
        float p0 = q * k0, p1 = q * k1, p2 = q * k2, p3 = q * k3;
        p0 += __shfl_xor(p0, 1); p1 += __shfl_xor(p1, 1); p2 += __shfl_xor(p2, 1); p3 += __shfl_xor(p3, 1);
        p0 += __shfl_xor(p0, 2); p1 += __shfl_xor(p1, 2); p2 += __shfl_xor(p2, 2); p3 += __shfl_xor(p3, 2);
        p0 += __shfl_xor(p0, 4); p1 += __shfl_xor(p1, 4); p2 += __shfl_xor(p2, 4); p3 += __shfl_xor(p3, 4);
        p0 += __shfl_xor(p0, 8); p1 += __shfl_xor(p1, 8); p2 += __shfl_xor(p2, 8); p3 += __shfl_xor(p3, 8);
        float e0 = exp2f(p0), e1 = exp2f(p1), e2 = exp2f(p2), e3 = exp2f(p3);
        denom += (e0 + e1) + (e2 + e3);
        acc = fmaf(e0, v0, acc);
        acc = fmaf(e1, v1, acc);
        acc = fmaf(e2, v2, acc);
        acc = fmaf(e3, v3, acc);
    }
    for (; j < je; j++) {
        int s0 = csr_src[j];
        unsigned int c0 = kv[(size_t)s0 * 64 + lane];
        float k0 = __uint_as_float(c0 << 16), v0 = __uint_as_float(c0 & 0xffff0000u);
        float p0 = q * k0;
        p0 += __shfl_xor(p0, 1);
        p0 += __shfl_xor(p0, 2);
        p0 += __shfl_xor(p0, 4);
        p0 += __shfl_xor(p0, 8);
        float e0 = exp2f(p0);
        denom += e0;
        acc = fmaf(e0, v0, acc);
    }
    float o = acc / (denom + 1e-16f) + skip;
    o = (o - bnm[lane]) * rsqrtf(bnv[lane] + 1e-5f) * bng[lane] + bnb[lane];
    h_out[(size_t)wid * 64 + lane] = f2bf_rne(fmaxf(o, 0.f));
}

// ---------------------------------------------------------------------------
// Global max pool over sorted batch ids (values are post-ReLU, >= 0). h bf16.
// ---------------------------------------------------------------------------
__global__ __launch_bounds__(256) void k_pool(const unsigned short* __restrict__ h,
                                              const int* __restrict__ batch,
                                              float* __restrict__ g0) {
    int f = threadIdx.x & 63;
    int sub = threadIdx.x >> 6;
    int n0 = blockIdx.x * 128;
    int nEnd = n0 + 128; if (nEnd > NN) nEnd = NN;
    int cur_g = -1; float cur_m = 0.f;
    for (int n = n0 + sub; n < nEnd; n += 4) {
        int bg = batch[n];
        float val = __uint_as_float((unsigned int)h[(size_t)n * 64 + f] << 16);
        if (bg != cur_g) {
            if (cur_g >= 0) atomicMax((int*)&g0[cur_g * 64 + f], __float_as_int(cur_m));
            cur_g = bg; cur_m = val;
        } else {
            cur_m = fmaxf(cur_m, val);
        }
    }
    if (cur_g >= 0) atomicMax((int*)&g0[cur_g * 64 + f], __float_as_int(cur_m));
}

// ---------------------------------------------------------------------------
// Fused MLP head: 4 layers + BN + log_softmax. One wave per graph row.
// ---------------------------------------------------------------------------
__global__ __launch_bounds__(256) void k_mlp(
    const float* __restrict__ g0,
    const float* __restrict__ p1w, const float* __restrict__ p1b,
    const float* __restrict__ p2w, const float* __restrict__ p2b,
    const float* __restrict__ cl1w, const float* __restrict__ cl1b,
    const float* __restrict__ bg, const float* __restrict__ bb,
    const float* __restrict__ bm, const float* __restrict__ bv,
    const float* __restrict__ cl2w, const float* __restrict__ cl2b,
    float* __restrict__ outp) {
    __shared__ float w1[64 * 64], w2[64 * 64], w3[64 * 64], w4[64 * 10];
    __shared__ float sb1[64], sb2[64], sb3[64], sbn[4 * 64], sb4[10];
    int tid = threadIdx.x;
    for (int i = tid; i < 64 * 64; i += 256) { w1[i] = p1w[i]; w2[i] = p2w[i]; w3[i] = cl1w[i]; }
    for (int i = tid; i < 64 * 10; i += 256) w4[i] = cl2w[i];
    if (tid < 64) {
        sb1[tid] = p1b[tid]; sb2[tid] = p2b[tid]; sb3[tid] = cl1b[tid];
        sbn[tid] = bg[tid]; sbn[64 + tid] = bb[tid];
        sbn[128 + tid] = bm[tid]; sbn[192 + tid] = bv[tid];
    }
    if (tid < 10) sb4[tid] = cl2b[tid];
    __syncthreads();
    int lane = tid & 63, w = tid >> 6;
    int row = blockIdx.x * 4 + w;
    float x = g0[row * 64 + lane];
    if (!isfinite(x)) x = 0.f;
    float a = sb1[lane];
    for (int k = 0; k < 64; k++) a += __shfl(x, k) * w1[k * 64 + lane];
    x = fmaxf(a, 0.f);
    a = sb2[lane];
    for (int k = 0; k < 64; k++) a += __shfl(x, k) * w2[k * 64 + lane];
    x = a;
    a = sb3[lane];
    for (int k = 0; k < 64; k++) a += __shfl(x, k) * w3[k * 64 + lane];
    a = (a - sbn[128 + lane]) * rsqrtf(sbn[192 + lane] + 1e-5f) * sbn[lane] + sbn[64 + lane];
    x = fmaxf(a, 0.f);
    float lg[10];
    #pragma unroll
    for (int c = 0; c < 10; c++) {
        float p = x * w4[lane * 10 + c];
        p += __shfl_xor(p, 1);  p += __shfl_xor(p, 2);  p += __shfl_xor(p, 4);
        p += __shfl_xor(p, 8);  p += __shfl_xor(p, 16); p += __shfl_xor(p, 32);
        lg[c] = p + sb4[c];
    }
    float mx = lg[0];
    #pragma unroll
    for (int c = 1; c < 10; c++) mx = fmaxf(mx, lg[c]);
    float s = 0.f;
    #pragma unroll
    for (int c = 0; c < 10; c++) s += __expf(lg[c] - mx);
    float lse = mx + logf(s);
    float o = 0.f;
    #pragma unroll
    for (int c = 0; c < 10; c++) if (lane == c) o = lg[c];
    if (lane < 10) outp[row * 10 + lane] = o - lse;
}

// ---------------------------------------------------------------------------
extern "C" void kernel_launch(void* const* d_in, const int* in_sizes, int n_in,
                              void* d_out, int out_size, void* d_ws, size_t ws_size,
                              hipStream_t stream) {
    const float* x     = (const float*)d_in[0];
    const int*   ei    = (const int*)d_in[1];
    const int*   batch = (const int*)d_in[2];
    const float *c1_wq = (const float*)d_in[3],  *c1_bq = (const float*)d_in[4];
    const float *c1_wk = (const float*)d_in[5],  *c1_bk = (const float*)d_in[6];
    const float *c1_wv = (const float*)d_in[7],  *c1_bv = (const float*)d_in[8];
    const float *c1_ws = (const float*)d_in[9],  *c1_bs = (const float*)d_in[10];
    const float *c2_wq = (const float*)d_in[11], *c2_bq = (const float*)d_in[12];
    const float *c2_wk = (const float*)d_in[13], *c2_bk = (const float*)d_in[14];
    const float *c2_wv = (const float*)d_in[15], *c2_bv = (const float*)d_in[16];
    const float *c2_ws = (const float*)d_in[17], *c2_bs = (const float*)d_in[18];
    const float *bn1_g = (const float*)d_in[19], *bn1_b = (const float*)d_in[20];
    const float *bn1_m = (const float*)d_in[21], *bn1_v = (const float*)d_in[22];
    const float *bn2_g = (const float*)d_in[23], *bn2_b = (const float*)d_in[24];
    const float *bn2_m = (const float*)d_in[25], *bn2_v = (const float*)d_in[26];
    const float *clbn_g = (const float*)d_in[27], *clbn_b = (const float*)d_in[28];
    const float *clbn_m = (const float*)d_in[29], *clbn_v = (const float*)d_in[30];
    const float *p1_w = (const float*)d_in[31], *p2_w = (const float*)d_in[32];
    const float *cl1_w = (const float*)d_in[33], *cl2_w = (const float*)d_in[34];
    const float *p1_b = (const float*)d_in[35], *p2_b = (const float*)d_in[36];
    const float *cl1_b = (const float*)d_in[37], *cl2_b = (const float*)d_in[38];

    char* ws = (char*)d_ws;
    float*          qs    = (float*)(ws);                        // 51,200,000
    unsigned int*   kv    = (unsigned int*)(ws + 51200000);      // 25,600,000
    unsigned short* hbuf  = (unsigned short*)(ws + 76800000);    // 12,812,288 (MPAD x 64)
    int2*           ppair = (int2*)(ws + 89612288);              // 12,800,000
    int*            csr   = (int*)(ws + 102412288);              //  6,400,000
    int*            rowp  = (int*)(ws + 108812288);              //    400,400
    int*            bcnt  = (int*)(ws + 109212688);              //      3,136
    int*            bbase = (int*)(ws + 109215824);              //      3,136
    int*            bcur  = (int*)(ws + 109218960);              //      3,136
    float*          g0    = (float*)(ws + 109222096);            //    131,072
    unsigned short* Bt1   = (unsigned short*)(ws + 109353168);   //     65,536
    float*          b1    = (float*)(ws + 109418704);            //      1,024
    unsigned short* Bt2   = (unsigned short*)(ws + 109419728);   //     32,768
    float*          b2    = (float*)(ws + 109452496);            //      1,024

    const int* srcIdx = ei;
    const int* dstIdx = ei + EE;

    hipMemsetAsync(bcnt, 0, NBUCK * sizeof(int), stream);
    hipMemsetAsync(g0, 0, GG * 64 * sizeof(float), stream);

    // CSR build: two-level counting sort
    constexpr int PBLK = (EE + EPB - 1) / EPB;   // 196
    k_bhist<<<PBLK, 512, 0, stream>>>(dstIdx, bcnt);
    k_bscan<<<1, 1024, 0, stream>>>(bcnt, bbase, bcur);
    k_part<<<PBLK, 512, 0, stream>>>(srcIdx, dstIdx, bcur, ppair);
    k_bucket<<<NBUCK, 256, 0, stream>>>(ppair, bbase, rowp, csr);

    // Weight packing
    k_cvt_w<128><<<128, 256, 0, stream>>>(c1_wq, c1_bq, c1_wk, c1_bk, c1_wv, c1_bv,
                                          c1_ws, c1_bs, Bt1, b1);
    k_cvt_w<64><<<64, 256, 0, stream>>>(c2_wq, c2_bq, c2_wk, c2_bk, c2_wv, c2_bv,
                                        c2_ws, c2_bs, Bt2, b2);

    // Conv1 (A = x fp32, converted in staging)
    {
        dim3 grid(MPAD / 128, 2);
        gemm_mfma<128, true><<<grid, 256, 0, stream>>>(x, Bt1, b1, qs, (unsigned short*)kv);
    }
    attn_fused<<<NN / 4, 256, 0, stream>>>(qs, kv, rowp, csr, bn1_g, bn1_b, bn1_m, bn1_v, hbuf);

    // Conv2 (A = hbuf bf16)
    {
        dim3 grid(MPAD / 128, 2);
        gemm_mfma<64, false><<<grid, 256, 0, stream>>>(hbuf, Bt2, b2, qs, (unsigned short*)kv);
    }
    attn_fused<<<NN / 4, 256, 0, stream>>>(qs, kv, rowp, csr, bn2_g, bn2_b, bn2_m, bn2_v, hbuf);

    // Pool + MLP head
    k_pool<<<(NN + 127) / 128, 256, 0, stream>>>(hbuf, batch, g0);
    k_mlp<<<GG / 4, 256, 0, stream>>>(g0, p1_w, p1_b, p2_w, p2_b, cl1_w, cl1_b,
                                      clbn_g, clbn_b, clbn_m, clbn_v, cl2_w, cl2_b,
                                      (float*)d_out);
}

// Round 5
// 452.845 us; speedup vs baseline: 1.7726x; 1.0697x over previous
//
#include <hip/hip_runtime.h>
#include <hip/hip_bf16.h>
#include <math.h>

// Problem constants
constexpr int NN = 100000;   // nodes
constexpr int EE = 1600000;  // edges
constexpr int GG = 512;      // graphs
constexpr int MPAD = 100096; // 782 * 128 row-padded M
constexpr int NBUCK = 782;   // MPAD / 128 coarse buckets (128 nodes each)
constexpr int EPB = 8192;    // edges per partition block

typedef __attribute__((ext_vector_type(8))) short short8;
typedef __attribute__((ext_vector_type(4))) float floatx4;

__device__ __forceinline__ unsigned short f2bf_rne(float f) {
    unsigned int u = __float_as_uint(f);
    u += 0x7fff + ((u >> 16) & 1);
    return (unsigned short)(u >> 16);
}

// DPP-based add of lane (per 16-lane row): single v_add_f32 with DPP ctrl.
template<int C>
__device__ __forceinline__ float dppadd(float x) {
    int t = __builtin_amdgcn_update_dpp(0, __float_as_int(x), C, 0xf, 0xf, true);
    return x + __int_as_float(t);
}
// Full 16-lane-row reduction: xor1, xor2 (quad_perm), then rotate 4, rotate 8.
__device__ __forceinline__ float hred16(float p) {
    p = dppadd<0xB1>(p);   // quad_perm [1,0,3,2]  (xor 1)
    p = dppadd<0x4E>(p);   // quad_perm [2,3,0,1]  (xor 2)
    p = dppadd<0x124>(p);  // row_ror:4
    p = dppadd<0x128>(p);  // row_ror:8
    return p;
}

// ---------------------------------------------------------------------------
// CSR build via two-level counting sort (no random-scatter write amplification)
// ---------------------------------------------------------------------------
__global__ __launch_bounds__(512) void k_bhist(const int* __restrict__ dst,
                                               int* __restrict__ bcnt) {
    __shared__ int cnt[NBUCK];
    int tid = threadIdx.x;
    int e0 = blockIdx.x * EPB;
    for (int j = tid; j < NBUCK; j += 512) cnt[j] = 0;
    __syncthreads();
    #pragma unroll
    for (int t = 0; t < 16; t++) {
        int i = e0 + t * 512 + tid;
        if (i < EE) atomicAdd(&cnt[dst[i] >> 7], 1);
    }
    __syncthreads();
    for (int j = tid; j < NBUCK; j += 512) if (cnt[j]) atomicAdd(&bcnt[j], cnt[j]);
}

__global__ __launch_bounds__(1024) void k_bscan(const int* __restrict__ bcnt,
                                                int* __restrict__ bbase,
                                                int* __restrict__ bcur) {
    __shared__ int sa[1024], sb[1024];
    int t = threadIdx.x;
    sa[t] = (t < NBUCK) ? bcnt[t] : 0;
    __syncthreads();
    int* p = sa; int* q = sb;
    for (int off = 1; off < 1024; off <<= 1) {
        q[t] = (t >= off) ? (p[t] + p[t - off]) : p[t];
        __syncthreads();
        int* tmp = p; p = q; q = tmp;
    }
    int excl = (t == 0) ? 0 : p[t - 1];
    if (t < NBUCK) { bbase[t] = excl; bcur[t] = excl; }
    if (t == NBUCK - 1) bbase[NBUCK] = p[NBUCK - 1];
}

__global__ __launch_bounds__(512) void k_part(const int* __restrict__ src,
                                              const int* __restrict__ dst,
                                              int* __restrict__ bcur,
                                              int2* __restrict__ ppair) {
    __shared__ int cnt[NBUCK];
    __shared__ int base[NBUCK];
    int tid = threadIdx.x;
    int e0 = blockIdx.x * EPB;
    for (int j = tid; j < NBUCK; j += 512) cnt[j] = 0;
    __syncthreads();
    int myd[16], myr[16];
    #pragma unroll
    for (int t = 0; t < 16; t++) {
        int i = e0 + t * 512 + tid;
        if (i < EE) {
            int d = dst[i];
            myd[t] = d;
            myr[t] = atomicAdd(&cnt[d >> 7], 1);
        } else myd[t] = -1;
    }
    __syncthreads();
    for (int j = tid; j < NBUCK; j += 512) base[j] = atomicAdd(&bcur[j], cnt[j]);
    __syncthreads();
    #pragma unroll
    for (int t = 0; t < 16; t++) {
        int i = e0 + t * 512 + tid;
        if (myd[t] >= 0) {
            int2 pr; pr.x = src[i]; pr.y = myd[t];
            ppair[base[myd[t] >> 7] + myr[t]] = pr;
        }
    }
}

// One block per bucket: counting sort by exact dst; writes rowp and csr.
__global__ __launch_bounds__(256) void k_bucket(const int2* __restrict__ ppair,
                                                const int* __restrict__ bbase,
                                                int* __restrict__ rowp,
                                                int* __restrict__ csr) {
    __shared__ int cnt[128];
    __shared__ int sa[128], sb[128];
    __shared__ int cur[128];
    int t = threadIdx.x;
    int b = blockIdx.x;
    int start = bbase[b], end = bbase[b + 1];
    if (t < 128) cnt[t] = 0;
    __syncthreads();
    for (int i = start + t; i < end; i += 256)
        atomicAdd(&cnt[ppair[i].y & 127], 1);
    __syncthreads();
    if (t < 128) sa[t] = cnt[t];
    __syncthreads();
    int* p = sa; int* q = sb;
    for (int off = 1; off < 128; off <<= 1) {
        if (t < 128) q[t] = (t >= off) ? (p[t] + p[t - off]) : p[t];
        __syncthreads();
        int* tmp = p; p = q; q = tmp;
    }
    if (t < 128) {
        int excl = (t == 0) ? 0 : p[t - 1];
        rowp[b * 128 + t] = start + excl;
        cur[t] = start + excl;
    }
    __syncthreads();
    for (int i = start + t; i < end; i += 256) {
        int2 e = ppair[i];
        int pos = atomicAdd(&cur[e.y & 127], 1);
        csr[pos] = e.x;
    }
}

// ---------------------------------------------------------------------------
// Pack weights: Bt[256][K] bf16, columns ordered [k0,v0,k1,v1,...,q(64),s(64)]
// bias[256] fp32 in same column order.
// ---------------------------------------------------------------------------
template<int K>
__global__ __launch_bounds__(256) void k_cvt_w(
    const float* __restrict__ Wq, const float* __restrict__ Bq,
    const float* __restrict__ Wk, const float* __restrict__ Bk,
    const float* __restrict__ Wv, const float* __restrict__ Bv,
    const float* __restrict__ Wsk, const float* __restrict__ Bsk,
    unsigned short* __restrict__ Bt, float* __restrict__ bias) {
    int idx = blockIdx.x * 256 + threadIdx.x;  // [0, 256*K)
    int col = idx / K, k = idx % K;
    float val;
    if (col < 128) {
        int f = col >> 1;
        val = (col & 1) ? Wv[k * 64 + f] : Wk[k * 64 + f];
    } else if (col < 192) {
        val = Wq[k * 64 + (col - 128)];
    } else {
        val = Wsk[k * 64 + (col - 192)];
    }
    Bt[col * K + k] = f2bf_rne(val);
    if (k == 0) {
        float bv;
        if (col < 128) {
            int f = col >> 1;
            bv = (col & 1) ? Bv[f] : Bk[f];
        } else if (col < 192) bv = Bq[col - 128];
        else bv = Bsk[col - 192];
        bias[col] = bv;
    }
}

// ---------------------------------------------------------------------------
// MFMA GEMM: A[M][K] (fp32 or bf16) @ Bt[256][K] bf16 ->
//   col-tile 0: kv bf16 pairs, col-tile 1: qs fp32 [q|s].
// 128x128 tile, 4 waves (2x2), 64-k LDS chunks.
// ---------------------------------------------------------------------------
template<int K, bool AF32>
__global__ __launch_bounds__(256) void gemm_mfma(
    const void* __restrict__ Araw,
    const unsigned short* __restrict__ Bt,
    const float* __restrict__ bias,
    float* __restrict__ qs,
    unsigned short* __restrict__ kvu) {
    constexpr int SP = 72;                    // 64 + 8 pad (bf16 elts)
    __shared__ short As[128 * SP];            // 18432 B
    __shared__ short Bs[128 * SP];            // 18432 B
    int tid = threadIdx.x;
    int wave = tid >> 6, lane = tid & 63;
    int wm = wave >> 1, wn = wave & 1;
    int quad = lane >> 4, l16 = lane & 15;
    int rowBase = blockIdx.x * 128;
    int ct = blockIdx.y;                      // 0: kv cols, 1: q|s cols

    floatx4 acc[4][4];
    #pragma unroll
    for (int i = 0; i < 4; i++)
        #pragma unroll
        for (int j = 0; j < 4; j++) acc[i][j] = (floatx4)0.f;

    for (int kc = 0; kc < K; kc += 64) {
        #pragma unroll
        for (int it = 0; it < 4; it++) {
            int flat = it * 256 + tid;        // [0,1024)
            int r = flat >> 3, c8 = (flat & 7) * 8;
            int ar = rowBase + r; if (ar >= NN) ar = NN - 1;   // clamp: no OOB reads
            short8 va;
            if constexpr (AF32) {
                const float* ap = (const float*)Araw + (size_t)ar * K + kc + c8;
                float4 u0 = *reinterpret_cast<const float4*>(ap);
                float4 u1 = *reinterpret_cast<const float4*>(ap + 4);
                va[0] = (short)f2bf_rne(u0.x); va[1] = (short)f2bf_rne(u0.y);
                va[2] = (short)f2bf_rne(u0.z); va[3] = (short)f2bf_rne(u0.w);
                va[4] = (short)f2bf_rne(u1.x); va[5] = (short)f2bf_rne(u1.y);
                va[6] = (short)f2bf_rne(u1.z); va[7] = (short)f2bf_rne(u1.w);
            } else {
                va = *reinterpret_cast<const short8*>(
                        (const unsigned short*)Araw + (size_t)ar * K + kc + c8);
            }
            *reinterpret_cast<short8*>(&As[r * SP + c8]) = va;
            short8 vb = *reinterpret_cast<const short8*>(Bt + (size_t)(ct * 128 + r) * K + kc + c8);
            *reinterpret_cast<short8*>(&Bs[r * SP + c8]) = vb;
        }
        __syncthreads();
        #pragma unroll
        for (int ks = 0; ks < 2; ks++) {
            short8 af[4], bf[4];
            #pragma unroll
            for (int i = 0; i < 4; i++)
                af[i] = *reinterpret_cast<const short8*>(&As[(wm * 64 + i * 16 + l16) * SP + ks * 32 + quad * 8]);
            #pragma unroll
            for (int j = 0; j < 4; j++)
                bf[j] = *reinterpret_cast<const short8*>(&Bs[(wn * 64 + j * 16 + l16) * SP + ks * 32 + quad * 8]);
            #pragma unroll
            for (int i = 0; i < 4; i++)
                #pragma unroll
                for (int j = 0; j < 4; j++)
                    acc[i][j] = __builtin_amdgcn_mfma_f32_16x16x32_bf16(af[i], bf[j], acc[i][j], 0, 0, 0);
        }
        __syncthreads();
    }

    // Epilogue: bias + store. C layout: col = lane&15 (within n-tile), row = quad*4 + reg.
    float bj[4];
    #pragma unroll
    for (int j = 0; j < 4; j++) bj[j] = bias[ct * 128 + wn * 64 + j * 16 + l16];
    #pragma unroll
    for (int i = 0; i < 4; i++) {
        #pragma unroll
        for (int j = 0; j < 4; j++) {
            int col = wn * 64 + j * 16 + l16;
            #pragma unroll
            for (int r = 0; r < 4; r++) {
                int row = rowBase + wm * 64 + i * 16 + quad * 4 + r;
                if (row < NN) {
                    float val = acc[i][j][r] + bj[j];
                    if (ct == 1) qs[(size_t)row * 128 + col] = val;
                    else kvu[(size_t)row * 128 + col] = f2bf_rne(val);
                }
            }
        }
    }
}

// ---------------------------------------------------------------------------
// Fused attention: one wave per dst node; lane = h*16+d.
// qs[N,128] = [q|skip] fp32; kv[N,64] = (k,v) bf16 pairs. h out bf16.
// Reductions via DPP (quad_perm / row_ror) - no LDS-pipe shuffles.
// ---------------------------------------------------------------------------
__global__ __launch_bounds__(256) void attn_fused(
    const float* __restrict__ qs,
    const unsigned int* __restrict__ kv,
    const int* __restrict__ row_ptr,
    const int* __restrict__ csr_src,
    const float* __restrict__ bng, const float* __restrict__ bnb,
    const float* __restrict__ bnm, const float* __restrict__ bnv,
    unsigned short* __restrict__ h_out) {
    int wid = (blockIdx.x * 256 + threadIdx.x) >> 6;
    int lane = threadIdx.x & 63;
    if (wid >= NN) return;
    // fold 1/sqrt(D)=0.25 and log2(e) into q: exp(x*0.25) = exp2(x*0.25*log2e)
    float q = qs[(size_t)wid * 128 + lane] * 0.3606737602222409f;
    float skip = qs[(size_t)wid * 128 + 64 + lane];
    int jb = row_ptr[wid], je = row_ptr[wid + 1];
    float acc = 0.f, denom = 0.f;
    int j = jb;
    for (; j + 3 < je; j += 4) {   // 4-edge ILP
        int s0 = csr_src[j], s1 = csr_src[j + 1];
        int s2 = csr_src[j + 2], s3 = csr_src[j + 3];
        unsigned int c0 = kv[(size_t)s0 * 64 + lane];
        unsigned int c1 = kv[(size_t)s1 * 64 + lane];
        unsigned int c2 = kv[(size_t)s2 * 64 + lane];
        unsigned int c3 = kv[(size_t)s3 * 64 + lane];
        float k0 = __uint_as_float(c0 << 16), v0 = __uint_as_float(c0 & 0xffff0000u);
        float k1 = __uint_as_float(c1 << 16), v1 = __uint_as_float(c1 & 0xffff0000u);
        float k2 = __uint_as_float(c2 << 16), v2 = __uint_as_float(c2 & 0xffff0000u);
        float k3 = __uint_as_float(c3 << 16), v3 = __uint_as_float(c3 & 0xffff0000u);
        float p0 = hred16(q * k0);
        float p1 = hred16(q * k1);
        float p2 = hred16(q * k2);
        float p3 = hred16(q * k3);
        float e0 = exp2f(p0), e1 = exp2f(p1), e2 = exp2f(p2), e3 = exp2f(p3);
        denom += (e0 + e1) + (e2 + e3);
        acc = fmaf(e0, v0, acc);
        acc = fmaf(e1, v1, acc);
        acc = fmaf(e2, v2, acc);
        acc = fmaf(e3, v3, acc);
    }
    for (; j < je; j++) {
        int s0 = csr_src[j];
        unsigned int c0 = kv[(size_t)s0 * 64 + lane];
        float k0 = __uint_as_float(c0 << 16), v0 = __uint_as_float(c0 & 0xffff0000u);
        float e0 = exp2f(hred16(q * k0));
        denom += e0;
        acc = fmaf(e0, v0, acc);
    }
    float o = acc / (denom + 1e-16f) + skip;
    o = (o - bnm[lane]) * rsqrtf(bnv[lane] + 1e-5f) * bng[lane] + bnb[lane];
    h_out[(size_t)wid * 64 + lane] = f2bf_rne(fmaxf(o, 0.f));
}

// ---------------------------------------------------------------------------
// Global max pool over sorted batch ids (values are post-ReLU, >= 0). h bf16.
// ---------------------------------------------------------------------------
__global__ __launch_bounds__(256) void k_pool(const unsigned short* __restrict__ h,
                                              const int* __restrict__ batch,
                                              float* __restrict__ g0) {
    int f = threadIdx.x & 63;
    int sub = threadIdx.x >> 6;
    int n0 = blockIdx.x * 128;
    int nEnd = n0 + 128; if (nEnd > NN) nEnd = NN;
    int cur_g = -1; float cur_m = 0.f;
    for (int n = n0 + sub; n < nEnd; n += 4) {
        int bg = batch[n];
        float val = __uint_as_float((unsigned int)h[(size_t)n * 64 + f] << 16);
        if (bg != cur_g) {
            if (cur_g >= 0) atomicMax((int*)&g0[cur_g * 64 + f], __float_as_int(cur_m));
            cur_g = bg; cur_m = val;
        } else {
            cur_m = fmaxf(cur_m, val);
        }
    }
    if (cur_g >= 0) atomicMax((int*)&g0[cur_g * 64 + f], __float_as_int(cur_m));
}

// ---------------------------------------------------------------------------
// Fused MLP head: 4 layers + BN + log_softmax. One wave per graph row.
// ---------------------------------------------------------------------------
__global__ __launch_bounds__(256) void k_mlp(
    const float* __restrict__ g0,
    const float* __restrict__ p1w, const float* __restrict__ p1b,
    const float* __restrict__ p2w, const float* __restrict__ p2b,
    const float* __restrict__ cl1w, const float* __restrict__ cl1b,
    const float* __restrict__ bg, const float* __restrict__ bb,
    const float* __restrict__ bm, const float* __restrict__ bv,
    const float* __restrict__ cl2w, const float* __restrict__ cl2b,
    float* __restrict__ outp) {
    __shared__ float w1[64 * 64], w2[64 * 64], w3[64 * 64], w4[64 * 10];
    __shared__ float sb1[64], sb2[64], sb3[64], sbn[4 * 64], sb4[10];
    int tid = threadIdx.x;
    for (int i = tid; i < 64 * 64; i += 256) { w1[i] = p1w[i]; w2[i] = p2w[i]; w3[i] = cl1w[i]; }
    for (int i = tid; i < 64 * 10; i += 256) w4[i] = cl2w[i];
    if (tid < 64) {
        sb1[tid] = p1b[tid]; sb2[tid] = p2b[tid]; sb3[tid] = cl1b[tid];
        sbn[tid] = bg[tid]; sbn[64 + tid] = bb[tid];
        sbn[128 + tid] = bm[tid]; sbn[192 + tid] = bv[tid];
    }
    if (tid < 10) sb4[tid] = cl2b[tid];
    __syncthreads();
    int lane = tid & 63, w = tid >> 6;
    int row = blockIdx.x * 4 + w;
    float x = g0[row * 64 + lane];
    if (!isfinite(x)) x = 0.f;
    float a = sb1[lane];
    for (int k = 0; k < 64; k++) a += __shfl(x, k) * w1[k * 64 + lane];
    x = fmaxf(a, 0.f);
    a = sb2[lane];
    for (int k = 0; k < 64; k++) a += __shfl(x, k) * w2[k * 64 + lane];
    x = a;
    a = sb3[lane];
    for (int k = 0; k < 64; k++) a += __shfl(x, k) * w3[k * 64 + lane];
    a = (a - sbn[128 + lane]) * rsqrtf(sbn[192 + lane] + 1e-5f) * sbn[lane] + sbn[64 + lane];
    x = fmaxf(a, 0.f);
    float lg[10];
    #pragma unroll
    for (int c = 0; c < 10; c++) {
        float p = x * w4[lane * 10 + c];
        p += __shfl_xor(p, 1);  p += __shfl_xor(p, 2);  p += __shfl_xor(p, 4);
        p += __shfl_xor(p, 8);  p += __shfl_xor(p, 16); p += __shfl_xor(p, 32);
        lg[c] = p + sb4[c];
    }
    float mx = lg[0];
    #pragma unroll
    for (int c = 1; c < 10; c++) mx = fmaxf(mx, lg[c]);
    float s = 0.f;
    #pragma unroll
    for (int c = 0; c < 10; c++) s += __expf(lg[c] - mx);
    float lse = mx + logf(s);
    float o = 0.f;
    #pragma unroll
    for (int c = 0; c < 10; c++) if (lane == c) o = lg[c];
    if (lane < 10) outp[row * 10 + lane] = o - lse;
}

// ---------------------------------------------------------------------------
extern "C" void kernel_launch(void* const* d_in, const int* in_sizes, int n_in,
                              void* d_out, int out_size, void* d_ws, size_t ws_size,
                              hipStream_t stream) {
    const float* x     = (const float*)d_in[0];
    const int*   ei    = (const int*)d_in[1];
    const int*   batch = (const int*)d_in[2];
    const float *c1_wq = (const float*)d_in[3],  *c1_bq = (const float*)d_in[4];
    const float *c1_wk = (const float*)d_in[5],  *c1_bk = (const float*)d_in[6];
    const float *c1_wv = (const float*)d_in[7],  *c1_bv = (const float*)d_in[8];
    const float *c1_ws = (const float*)d_in[9],  *c1_bs = (const float*)d_in[10];
    const float *c2_wq = (const float*)d_in[11], *c2_bq = (const float*)d_in[12];
    const float *c2_wk = (const float*)d_in[13], *c2_bk = (const float*)d_in[14];
    const float *c2_wv = (const float*)d_in[15], *c2_bv = (const float*)d_in[16];
    const float *c2_ws = (const float*)d_in[17], *c2_bs = (const float*)d_in[18];
    const float *bn1_g = (const float*)d_in[19], *bn1_b = (const float*)d_in[20];
    const float *bn1_m = (const float*)d_in[21], *bn1_v = (const float*)d_in[22];
    const float *bn2_g = (const float*)d_in[23], *bn2_b = (const float*)d_in[24];
    const float *bn2_m = (const float*)d_in[25], *bn2_v = (const float*)d_in[26];
    const float *clbn_g = (const float*)d_in[27], *clbn_b = (const float*)d_in[28];
    const float *clbn_m = (const float*)d_in[29], *clbn_v = (const float*)d_in[30];
    const float *p1_w = (const float*)d_in[31], *p2_w = (const float*)d_in[32];
    const float *cl1_w = (const float*)d_in[33], *cl2_w = (const float*)d_in[34];
    const float *p1_b = (const float*)d_in[35], *p2_b = (const float*)d_in[36];
    const float *cl1_b = (const float*)d_in[37], *cl2_b = (const float*)d_in[38];

    char* ws = (char*)d_ws;
    float*          qs    = (float*)(ws);                        // 51,200,000
    unsigned int*   kv    = (unsigned int*)(ws + 51200000);      // 25,600,000
    unsigned short* hbuf  = (unsigned short*)(ws + 76800000);    // 12,812,288 (MPAD x 64)
    int2*           ppair = (int2*)(ws + 89612288);              // 12,800,000
    int*            csr   = (int*)(ws + 102412288);              //  6,400,000
    int*            rowp  = (int*)(ws + 108812288);              //    400,400
    int*            bcnt  = (int*)(ws + 109212688);              //      3,136
    int*            bbase = (int*)(ws + 109215824);              //      3,136
    int*            bcur  = (int*)(ws + 109218960);              //      3,136
    float*          g0    = (float*)(ws + 109222096);            //    131,072
    unsigned short* Bt1   = (unsigned short*)(ws + 109353168);   //     65,536
    float*          b1    = (float*)(ws + 109418704);            //      1,024
    unsigned short* Bt2   = (unsigned short*)(ws + 109419728);   //     32,768
    float*          b2    = (float*)(ws + 109452496);            //      1,024

    const int* srcIdx = ei;
    const int* dstIdx = ei + EE;

    hipMemsetAsync(bcnt, 0, NBUCK * sizeof(int), stream);
    hipMemsetAsync(g0, 0, GG * 64 * sizeof(float), stream);

    // CSR build: two-level counting sort
    constexpr int PBLK = (EE + EPB - 1) / EPB;   // 196
    k_bhist<<<PBLK, 512, 0, stream>>>(dstIdx, bcnt);
    k_bscan<<<1, 1024, 0, stream>>>(bcnt, bbase, bcur);
    k_part<<<PBLK, 512, 0, stream>>>(srcIdx, dstIdx, bcur, ppair);
    k_bucket<<<NBUCK, 256, 0, stream>>>(ppair, bbase, rowp, csr);

    // Weight packing
    k_cvt_w<128><<<128, 256, 0, stream>>>(c1_wq, c1_bq, c1_wk, c1_bk, c1_wv, c1_bv,
                                          c1_ws, c1_bs, Bt1, b1);
    k_cvt_w<64><<<64, 256, 0, stream>>>(c2_wq, c2_bq, c2_wk, c2_bk, c2_wv, c2_bv,
                                        c2_ws, c2_bs, Bt2, b2);

    // Conv1 (A = x fp32, converted in staging)
    {
        dim3 grid(MPAD / 128, 2);
        gemm_mfma<128, true><<<grid, 256, 0, stream>>>(x, Bt1, b1, qs, (unsigned short*)kv);
    }
    attn_fused<<<NN / 4, 256, 0, stream>>>(qs, kv, rowp, csr, bn1_g, bn1_b, bn1_m, bn1_v, hbuf);

    // Conv2 (A = hbuf bf16)
    {
        dim3 grid(MPAD / 128, 2);
        gemm_mfma<64, false><<<grid, 256, 0, stream>>>(hbuf, Bt2, b2, qs, (unsigned short*)kv);
    }
    attn_fused<<<NN / 4, 256, 0, stream>>>(qs, kv, rowp, csr, bn2_g, bn2_b, bn2_m, bn2_v, hbuf);

    // Pool + MLP head
    k_pool<<<(NN + 127) / 128, 256, 0, stream>>>(hbuf, batch, g0);
    k_mlp<<<GG / 4, 256, 0, stream>>>(g0, p1_w, p1_b, p2_w, p2_b, cl1_w, cl1_b,
                                      clbn_g, clbn_b, clbn_m, clbn_v, cl2_w, cl2_b,
                                      (float*)d_out);
}

// Round 6
// 451.734 us; speedup vs baseline: 1.7769x; 1.0025x over previous
//
#include <hip/hip_runtime.h>
#include <hip/hip_bf16.h>
#include <math.h>

// Problem constants
constexpr int NN = 100000;   // nodes
constexpr int EE = 1600000;  // edges
constexpr int GG = 512;      // graphs
constexpr int MPAD = 100096; // 782 * 128 row-padded M
constexpr int NBUCK = 782;   // MPAD / 128 coarse buckets (128 nodes each)
constexpr int EPB = 8192;    // edges per partition block

typedef __attribute__((ext_vector_type(8))) short short8;
typedef __attribute__((ext_vector_type(4))) float floatx4;

__device__ __forceinline__ unsigned short f2bf_rne(float f) {
    unsigned int u = __float_as_uint(f);
    u += 0x7fff + ((u >> 16) & 1);
    return (unsigned short)(u >> 16);
}

// DPP-based add: single v_add_f32 with DPP ctrl on src.
template<int C>
__device__ __forceinline__ float dppadd(float x) {
    int t = __builtin_amdgcn_update_dpp(0, __float_as_int(x), C, 0xf, 0xf, true);
    return x + __int_as_float(t);
}
// Reduction over 8-lane head group: xor1, xor2 (quad_perm), then half-row mirror.
__device__ __forceinline__ float hred8(float p) {
    p = dppadd<0xB1>(p);   // quad_perm [1,0,3,2]  (xor 1)
    p = dppadd<0x4E>(p);   // quad_perm [2,3,0,1]  (xor 2)
    p = dppadd<0x141>(p);  // row_half_mirror (lane l <-> 7-l within 8)
    return p;
}

// ---------------------------------------------------------------------------
// CSR build via two-level counting sort (no random-scatter write amplification)
// ---------------------------------------------------------------------------
__global__ __launch_bounds__(512) void k_bhist(const int* __restrict__ dst,
                                               int* __restrict__ bcnt) {
    __shared__ int cnt[NBUCK];
    int tid = threadIdx.x;
    int e0 = blockIdx.x * EPB;
    for (int j = tid; j < NBUCK; j += 512) cnt[j] = 0;
    __syncthreads();
    #pragma unroll
    for (int t = 0; t < 16; t++) {
        int i = e0 + t * 512 + tid;
        if (i < EE) atomicAdd(&cnt[dst[i] >> 7], 1);
    }
    __syncthreads();
    for (int j = tid; j < NBUCK; j += 512) if (cnt[j]) atomicAdd(&bcnt[j], cnt[j]);
}

__global__ __launch_bounds__(1024) void k_bscan(const int* __restrict__ bcnt,
                                                int* __restrict__ bbase,
                                                int* __restrict__ bcur) {
    __shared__ int sa[1024], sb[1024];
    int t = threadIdx.x;
    sa[t] = (t < NBUCK) ? bcnt[t] : 0;
    __syncthreads();
    int* p = sa; int* q = sb;
    for (int off = 1; off < 1024; off <<= 1) {
        q[t] = (t >= off) ? (p[t] + p[t - off]) : p[t];
        __syncthreads();
        int* tmp = p; p = q; q = tmp;
    }
    int excl = (t == 0) ? 0 : p[t - 1];
    if (t < NBUCK) { bbase[t] = excl; bcur[t] = excl; }
    if (t == NBUCK - 1) bbase[NBUCK] = p[NBUCK - 1];
}

__global__ __launch_bounds__(512) void k_part(const int* __restrict__ src,
                                              const int* __restrict__ dst,
                                              int* __restrict__ bcur,
                                              int2* __restrict__ ppair) {
    __shared__ int cnt[NBUCK];
    __shared__ int base[NBUCK];
    int tid = threadIdx.x;
    int e0 = blockIdx.x * EPB;
    for (int j = tid; j < NBUCK; j += 512) cnt[j] = 0;
    __syncthreads();
    int myd[16], myr[16];
    #pragma unroll
    for (int t = 0; t < 16; t++) {
        int i = e0 + t * 512 + tid;
        if (i < EE) {
            int d = dst[i];
            myd[t] = d;
            myr[t] = atomicAdd(&cnt[d >> 7], 1);
        } else myd[t] = -1;
    }
    __syncthreads();
    for (int j = tid; j < NBUCK; j += 512) base[j] = atomicAdd(&bcur[j], cnt[j]);
    __syncthreads();
    #pragma unroll
    for (int t = 0; t < 16; t++) {
        int i = e0 + t * 512 + tid;
        if (myd[t] >= 0) {
            int2 pr; pr.x = src[i]; pr.y = myd[t];
            ppair[base[myd[t] >> 7] + myr[t]] = pr;
        }
    }
}

// One block per bucket: counting sort by exact dst; writes rowp and csr.
__global__ __launch_bounds__(256) void k_bucket(const int2* __restrict__ ppair,
                                                const int* __restrict__ bbase,
                                                int* __restrict__ rowp,
                                                int* __restrict__ csr) {
    __shared__ int cnt[128];
    __shared__ int sa[128], sb[128];
    __shared__ int cur[128];
    int t = threadIdx.x;
    int b = blockIdx.x;
    int start = bbase[b], end = bbase[b + 1];
    if (t < 128) cnt[t] = 0;
    __syncthreads();
    for (int i = start + t; i < end; i += 256)
        atomicAdd(&cnt[ppair[i].y & 127], 1);
    __syncthreads();
    if (t < 128) sa[t] = cnt[t];
    __syncthreads();
    int* p = sa; int* q = sb;
    for (int off = 1; off < 128; off <<= 1) {
        if (t < 128) q[t] = (t >= off) ? (p[t] + p[t - off]) : p[t];
        __syncthreads();
        int* tmp = p; p = q; q = tmp;
    }
    if (t < 128) {
        int excl = (t == 0) ? 0 : p[t - 1];
        rowp[b * 128 + t] = start + excl;
        cur[t] = start + excl;
    }
    __syncthreads();
    for (int i = start + t; i < end; i += 256) {
        int2 e = ppair[i];
        int pos = atomicAdd(&cur[e.y & 127], 1);
        csr[pos] = e.x;
    }
}

// ---------------------------------------------------------------------------
// Pack weights: Bt[256][K] bf16.
// Col-tile 0 columns: [k(64) | v(64)]; col-tile 1 columns: [q(64) | s(64)].
// bias[256] fp32 in same column order.
// ---------------------------------------------------------------------------
template<int K>
__global__ __launch_bounds__(256) void k_cvt_w(
    const float* __restrict__ Wq, const float* __restrict__ Bq,
    const float* __restrict__ Wk, const float* __restrict__ Bk,
    const float* __restrict__ Wv, const float* __restrict__ Bv,
    const float* __restrict__ Wsk, const float* __restrict__ Bsk,
    unsigned short* __restrict__ Bt, float* __restrict__ bias) {
    int idx = blockIdx.x * 256 + threadIdx.x;  // [0, 256*K)
    int col = idx / K, k = idx % K;
    float val;
    if (col < 64)        val = Wk[k * 64 + col];
    else if (col < 128)  val = Wv[k * 64 + (col - 64)];
    else if (col < 192)  val = Wq[k * 64 + (col - 128)];
    else                 val = Wsk[k * 64 + (col - 192)];
    Bt[col * K + k] = f2bf_rne(val);
    if (k == 0) {
        float bv;
        if (col < 64)        bv = Bk[col];
        else if (col < 128)  bv = Bv[col - 64];
        else if (col < 192)  bv = Bq[col - 128];
        else                 bv = Bsk[col - 192];
        bias[col] = bv;
    }
}

// ---------------------------------------------------------------------------
// MFMA GEMM: A[M][K] (fp32 or bf16) @ Bt[256][K] bf16 ->
//   col-tile 0: kv rows [k(64)|v(64)] bf16, col-tile 1: qs fp32 [q|s].
// 128x128 tile, 4 waves (2x2), 64-k LDS chunks.
// ---------------------------------------------------------------------------
template<int K, bool AF32>
__global__ __launch_bounds__(256) void gemm_mfma(
    const void* __restrict__ Araw,
    const unsigned short* __restrict__ Bt,
    const float* __restrict__ bias,
    float* __restrict__ qs,
    unsigned short* __restrict__ kvu) {
    constexpr int SP = 72;                    // 64 + 8 pad (bf16 elts)
    __shared__ short As[128 * SP];            // 18432 B
    __shared__ short Bs[128 * SP];            // 18432 B
    int tid = threadIdx.x;
    int wave = tid >> 6, lane = tid & 63;
    int wm = wave >> 1, wn = wave & 1;
    int quad = lane >> 4, l16 = lane & 15;
    int rowBase = blockIdx.x * 128;
    int ct = blockIdx.y;                      // 0: kv cols, 1: q|s cols

    floatx4 acc[4][4];
    #pragma unroll
    for (int i = 0; i < 4; i++)
        #pragma unroll
        for (int j = 0; j < 4; j++) acc[i][j] = (floatx4)0.f;

    for (int kc = 0; kc < K; kc += 64) {
        #pragma unroll
        for (int it = 0; it < 4; it++) {
            int flat = it * 256 + tid;        // [0,1024)
            int r = flat >> 3, c8 = (flat & 7) * 8;
            int ar = rowBase + r; if (ar >= NN) ar = NN - 1;   // clamp: no OOB reads
            short8 va;
            if constexpr (AF32) {
                const float* ap = (const float*)Araw + (size_t)ar * K + kc + c8;
                float4 u0 = *reinterpret_cast<const float4*>(ap);
                float4 u1 = *reinterpret_cast<const float4*>(ap + 4);
                va[0] = (short)f2bf_rne(u0.x); va[1] = (short)f2bf_rne(u0.y);
                va[2] = (short)f2bf_rne(u0.z); va[3] = (short)f2bf_rne(u0.w);
                va[4] = (short)f2bf_rne(u1.x); va[5] = (short)f2bf_rne(u1.y);
                va[6] = (short)f2bf_rne(u1.z); va[7] = (short)f2bf_rne(u1.w);
            } else {
                va = *reinterpret_cast<const short8*>(
                        (const unsigned short*)Araw + (size_t)ar * K + kc + c8);
            }
            *reinterpret_cast<short8*>(&As[r * SP + c8]) = va;
            short8 vb = *reinterpret_cast<const short8*>(Bt + (size_t)(ct * 128 + r) * K + kc + c8);
            *reinterpret_cast<short8*>(&Bs[r * SP + c8]) = vb;
        }
        __syncthreads();
        #pragma unroll
        for (int ks = 0; ks < 2; ks++) {
            short8 af[4], bf[4];
            #pragma unroll
            for (int i = 0; i < 4; i++)
                af[i] = *reinterpret_cast<const short8*>(&As[(wm * 64 + i * 16 + l16) * SP + ks * 32 + quad * 8]);
            #pragma unroll
            for (int j = 0; j < 4; j++)
                bf[j] = *reinterpret_cast<const short8*>(&Bs[(wn * 64 + j * 16 + l16) * SP + ks * 32 + quad * 8]);
            #pragma unroll
            for (int i = 0; i < 4; i++)
                #pragma unroll
                for (int j = 0; j < 4; j++)
                    acc[i][j] = __builtin_amdgcn_mfma_f32_16x16x32_bf16(af[i], bf[j], acc[i][j], 0, 0, 0);
        }
        __syncthreads();
    }

    // Epilogue: bias + store. C layout: col = lane&15 (within n-tile), row = quad*4 + reg.
    float bj[4];
    #pragma unroll
    for (int j = 0; j < 4; j++) bj[j] = bias[ct * 128 + wn * 64 + j * 16 + l16];
    #pragma unroll
    for (int i = 0; i < 4; i++) {
        #pragma unroll
        for (int j = 0; j < 4; j++) {
            int col = wn * 64 + j * 16 + l16;
            #pragma unroll
            for (int r = 0; r < 4; r++) {
                int row = rowBase + wm * 64 + i * 16 + quad * 4 + r;
                if (row < NN) {
                    float val = acc[i][j][r] + bj[j];
                    if (ct == 1) qs[(size_t)row * 128 + col] = val;
                    else kvu[(size_t)row * 128 + col] = f2bf_rne(val);
                }
            }
        }
    }
}

// ---------------------------------------------------------------------------
// Fused attention, half-wave edge pairs. One wave per dst node.
// lane = half*32 + sl; lane covers output features (2sl, 2sl+1).
// kvp row (dwords): [0,32) = k feature pairs, [32,64) = v feature pairs.
// qs[N,128] = [q|skip] fp32. h out bf16 (dword = 2 features).
// ---------------------------------------------------------------------------
__global__ __launch_bounds__(256) void attn_fused(
    const float* __restrict__ qs,
    const unsigned int* __restrict__ kvp,
    const int* __restrict__ row_ptr,
    const int* __restrict__ csr_src,
    const float* __restrict__ bng, const float* __restrict__ bnb,
    const float* __restrict__ bnm, const float* __restrict__ bnv,
    unsigned int* __restrict__ h_out) {
    int wid = (blockIdx.x * 256 + threadIdx.x) >> 6;
    int lane = threadIdx.x & 63;
    if (wid >= NN) return;
    int half = lane >> 5, sl = lane & 31;
    const float* qrow = qs + (size_t)wid * 128;
    // fold 1/sqrt(D)=0.25 and log2(e): exp(x*0.25) = exp2(x*0.25*log2e)
    float2 q2 = reinterpret_cast<const float2*>(qrow)[sl];
    float q0 = q2.x * 0.3606737602222409f;
    float q1 = q2.y * 0.3606737602222409f;
    int jb = row_ptr[wid], je = row_ptr[wid + 1];
    float acc0 = 0.f, acc1 = 0.f, denom = 0.f;
    int j = jb;
    for (; j + 3 < je; j += 4) {    // 2 pair-slots = 4 edges in flight
        int sA = csr_src[j + half];
        int sB = csr_src[j + 2 + half];
        const unsigned int* rA = kvp + (size_t)sA * 64;
        const unsigned int* rB = kvp + (size_t)sB * 64;
        unsigned int kdA = rA[sl], vdA = rA[32 + sl];
        unsigned int kdB = rB[sl], vdB = rB[32 + sl];
        float kA0 = __uint_as_float(kdA << 16), kA1 = __uint_as_float(kdA & 0xffff0000u);
        float kB0 = __uint_as_float(kdB << 16), kB1 = __uint_as_float(kdB & 0xffff0000u);
        float pA = fmaf(kA0, q0, kA1 * q1);
        float pB = fmaf(kB0, q0, kB1 * q1);
        pA = hred8(pA); pB = hred8(pB);
        float eA = exp2f(pA), eB = exp2f(pB);
        float vA0 = __uint_as_float(vdA << 16), vA1 = __uint_as_float(vdA & 0xffff0000u);
        float vB0 = __uint_as_float(vdB << 16), vB1 = __uint_as_float(vdB & 0xffff0000u);
        denom += eA + eB;
        acc0 = fmaf(eA, vA0, acc0); acc1 = fmaf(eA, vA1, acc1);
        acc0 = fmaf(eB, vB0, acc0); acc1 = fmaf(eB, vB1, acc1);
    }
    for (; j + 1 < je; j += 2) {    // single pair
        int s = csr_src[j + half];
        const unsigned int* r = kvp + (size_t)s * 64;
        unsigned int kd = r[sl], vd = r[32 + sl];
        float k0 = __uint_as_float(kd << 16), k1 = __uint_as_float(kd & 0xffff0000u);
        float p = hred8(fmaf(k0, q0, k1 * q1));
        float e = exp2f(p);
        float v0 = __uint_as_float(vd << 16), v1 = __uint_as_float(vd & 0xffff0000u);
        denom += e;
        acc0 = fmaf(e, v0, acc0); acc1 = fmaf(e, v1, acc1);
    }
    if (j < je) {                    // tail edge: both halves load it, half 1 zeroed
        int s = csr_src[j];
        const unsigned int* r = kvp + (size_t)s * 64;
        unsigned int kd = r[sl], vd = r[32 + sl];
        float k0 = __uint_as_float(kd << 16), k1 = __uint_as_float(kd & 0xffff0000u);
        float p = hred8(fmaf(k0, q0, k1 * q1));
        float e = (half == 0) ? exp2f(p) : 0.f;
        float v0 = __uint_as_float(vd << 16), v1 = __uint_as_float(vd & 0xffff0000u);
        denom += e;
        acc0 = fmaf(e, v0, acc0); acc1 = fmaf(e, v1, acc1);
    }
    // combine the two halves
    acc0 += __shfl_xor(acc0, 32);
    acc1 += __shfl_xor(acc1, 32);
    denom += __shfl_xor(denom, 32);
    float inv = 1.f / (denom + 1e-16f);
    float2 s2 = reinterpret_cast<const float2*>(qrow + 64)[sl];
    float2 m2 = reinterpret_cast<const float2*>(bnm)[sl];
    float2 v2 = reinterpret_cast<const float2*>(bnv)[sl];
    float2 g2 = reinterpret_cast<const float2*>(bng)[sl];
    float2 b2 = reinterpret_cast<const float2*>(bnb)[sl];
    float o0 = acc0 * inv + s2.x;
    float o1 = acc1 * inv + s2.y;
    o0 = (o0 - m2.x) * rsqrtf(v2.x + 1e-5f) * g2.x + b2.x;
    o1 = (o1 - m2.y) * rsqrtf(v2.y + 1e-5f) * g2.y + b2.y;
    o0 = fmaxf(o0, 0.f); o1 = fmaxf(o1, 0.f);
    if (half == 0) {
        unsigned int hw = (unsigned int)f2bf_rne(o0) | ((unsigned int)f2bf_rne(o1) << 16);
        h_out[(size_t)wid * 32 + sl] = hw;
    }
}

// ---------------------------------------------------------------------------
// Global max pool over sorted batch ids (values are post-ReLU, >= 0). h bf16.
// ---------------------------------------------------------------------------
__global__ __launch_bounds__(256) void k_pool(const unsigned short* __restrict__ h,
                                              const int* __restrict__ batch,
                                              float* __restrict__ g0) {
    int f = threadIdx.x & 63;
    int sub = threadIdx.x >> 6;
    int n0 = blockIdx.x * 128;
    int nEnd = n0 + 128; if (nEnd > NN) nEnd = NN;
    int cur_g = -1; float cur_m = 0.f;
    for (int n = n0 + sub; n < nEnd; n += 4) {
        int bg = batch[n];
        float val = __uint_as_float((unsigned int)h[(size_t)n * 64 + f] << 16);
        if (bg != cur_g) {
            if (cur_g >= 0) atomicMax((int*)&g0[cur_g * 64 + f], __float_as_int(cur_m));
            cur_g = bg; cur_m = val;
        } else {
            cur_m = fmaxf(cur_m, val);
        }
    }
    if (cur_g >= 0) atomicMax((int*)&g0[cur_g * 64 + f], __float_as_int(cur_m));
}

// ---------------------------------------------------------------------------
// Fused MLP head: 4 layers + BN + log_softmax. One wave per graph row.
// ---------------------------------------------------------------------------
__global__ __launch_bounds__(256) void k_mlp(
    const float* __restrict__ g0,
    const float* __restrict__ p1w, const float* __restrict__ p1b,
    const float* __restrict__ p2w, const float* __restrict__ p2b,
    const float* __restrict__ cl1w, const float* __restrict__ cl1b,
    const float* __restrict__ bg, const float* __restrict__ bb,
    const float* __restrict__ bm, const float* __restrict__ bv,
    const float* __restrict__ cl2w, const float* __restrict__ cl2b,
    float* __restrict__ outp) {
    __shared__ float w1[64 * 64], w2[64 * 64], w3[64 * 64], w4[64 * 10];
    __shared__ float sb1[64], sb2[64], sb3[64], sbn[4 * 64], sb4[10];
    int tid = threadIdx.x;
    for (int i = tid; i < 64 * 64; i += 256) { w1[i] = p1w[i]; w2[i] = p2w[i]; w3[i] = cl1w[i]; }
    for (int i = tid; i < 64 * 10; i += 256) w4[i] = cl2w[i];
    if (tid < 64) {
        sb1[tid] = p1b[tid]; sb2[tid] = p2b[tid]; sb3[tid] = cl1b[tid];
        sbn[tid] = bg[tid]; sbn[64 + tid] = bb[tid];
        sbn[128 + tid] = bm[tid]; sbn[192 + tid] = bv[tid];
    }
    if (tid < 10) sb4[tid] = cl2b[tid];
    __syncthreads();
    int lane = tid & 63, w = tid >> 6;
    int row = blockIdx.x * 4 + w;
    float x = g0[row * 64 + lane];
    if (!isfinite(x)) x = 0.f;
    float a = sb1[lane];
    for (int k = 0; k < 64; k++) a += __shfl(x, k) * w1[k * 64 + lane];
    x = fmaxf(a, 0.f);
    a = sb2[lane];
    for (int k = 0; k < 64; k++) a += __shfl(x, k) * w2[k * 64 + lane];
    x = a;
    a = sb3[lane];
    for (int k = 0; k < 64; k++) a += __shfl(x, k) * w3[k * 64 + lane];
    a = (a - sbn[128 + lane]) * rsqrtf(sbn[192 + lane] + 1e-5f) * sbn[lane] + sbn[64 + lane];
    x = fmaxf(a, 0.f);
    float lg[10];
    #pragma unroll
    for (int c = 0; c < 10; c++) {
        float p = x * w4[lane * 10 + c];
        p += __shfl_xor(p, 1);  p += __shfl_xor(p, 2);  p += __shfl_xor(p, 4);
        p += __shfl_xor(p, 8);  p += __shfl_xor(p, 16); p += __shfl_xor(p, 32);
        lg[c] = p + sb4[c];
    }
    float mx = lg[0];
    #pragma unroll
    for (int c = 1; c < 10; c++) mx = fmaxf(mx, lg[c]);
    float s = 0.f;
    #pragma unroll
    for (int c = 0; c < 10; c++) s += __expf(lg[c] - mx);
    float lse = mx + logf(s);
    float o = 0.f;
    #pragma unroll
    for (int c = 0; c < 10; c++) if (lane == c) o = lg[c];
    if (lane < 10) outp[row * 10 + lane] = o - lse;
}

// ---------------------------------------------------------------------------
extern "C" void kernel_launch(void* const* d_in, const int* in_sizes, int n_in,
                              void* d_out, int out_size, void* d_ws, size_t ws_size,
                              hipStream_t stream) {
    const float* x     = (const float*)d_in[0];
    const int*   ei    = (const int*)d_in[1];
    const int*   batch = (const int*)d_in[2];
    const float *c1_wq = (const float*)d_in[3],  *c1_bq = (const float*)d_in[4];
    const float *c1_wk = (const float*)d_in[5],  *c1_bk = (const float*)d_in[6];
    const float *c1_wv = (const float*)d_in[7],  *c1_bv = (const float*)d_in[8];
    const float *c1_ws = (const float*)d_in[9],  *c1_bs = (const float*)d_in[10];
    const float *c2_wq = (const float*)d_in[11], *c2_bq = (const float*)d_in[12];
    const float *c2_wk = (const float*)d_in[13], *c2_bk = (const float*)d_in[14];
    const float *c2_wv = (const float*)d_in[15], *c2_bv = (const float*)d_in[16];
    const float *c2_ws = (const float*)d_in[17], *c2_bs = (const float*)d_in[18];
    const float *bn1_g = (const float*)d_in[19], *bn1_b = (const float*)d_in[20];
    const float *bn1_m = (const float*)d_in[21], *bn1_v = (const float*)d_in[22];
    const float *bn2_g = (const float*)d_in[23], *bn2_b = (const float*)d_in[24];
    const float *bn2_m = (const float*)d_in[25], *bn2_v = (const float*)d_in[26];
    const float *clbn_g = (const float*)d_in[27], *clbn_b = (const float*)d_in[28];
    const float *clbn_m = (const float*)d_in[29], *clbn_v = (const float*)d_in[30];
    const float *p1_w = (const float*)d_in[31], *p2_w = (const float*)d_in[32];
    const float *cl1_w = (const float*)d_in[33], *cl2_w = (const float*)d_in[34];
    const float *p1_b = (const float*)d_in[35], *p2_b = (const float*)d_in[36];
    const float *cl1_b = (const float*)d_in[37], *cl2_b = (const float*)d_in[38];

    char* ws = (char*)d_ws;
    float*          qs    = (float*)(ws);                        // 51,200,000
    unsigned int*   kv    = (unsigned int*)(ws + 51200000);      // 25,600,000
    unsigned short* hbuf  = (unsigned short*)(ws + 76800000);    // 12,812,288 (MPAD x 64)
    int2*           ppair = (int2*)(ws + 89612288);              // 12,800,000
    int*            csr   = (int*)(ws + 102412288);              //  6,400,000
    int*            rowp  = (int*)(ws + 108812288);              //    400,400
    int*            bcnt  = (int*)(ws + 109212688);              //      3,136
    int*            bbase = (int*)(ws + 109215824);              //      3,136
    int*            bcur  = (int*)(ws + 109218960);              //      3,136
    float*          g0    = (float*)(ws + 109222096);            //    131,072
    unsigned short* Bt1   = (unsigned short*)(ws + 109353168);   //     65,536
    float*          b1    = (float*)(ws + 109418704);            //      1,024
    unsigned short* Bt2   = (unsigned short*)(ws + 109419728);   //     32,768
    float*          b2    = (float*)(ws + 109452496);            //      1,024

    const int* srcIdx = ei;
    const int* dstIdx = ei + EE;

    hipMemsetAsync(bcnt, 0, NBUCK * sizeof(int), stream);
    hipMemsetAsync(g0, 0, GG * 64 * sizeof(float), stream);

    // CSR build: two-level counting sort
    constexpr int PBLK = (EE + EPB - 1) / EPB;   // 196
    k_bhist<<<PBLK, 512, 0, stream>>>(dstIdx, bcnt);
    k_bscan<<<1, 1024, 0, stream>>>(bcnt, bbase, bcur);
    k_part<<<PBLK, 512, 0, stream>>>(srcIdx, dstIdx, bcur, ppair);
    k_bucket<<<NBUCK, 256, 0, stream>>>(ppair, bbase, rowp, csr);

    // Weight packing
    k_cvt_w<128><<<128, 256, 0, stream>>>(c1_wq, c1_bq, c1_wk, c1_bk, c1_wv, c1_bv,
                                          c1_ws, c1_bs, Bt1, b1);
    k_cvt_w<64><<<64, 256, 0, stream>>>(c2_wq, c2_bq, c2_wk, c2_bk, c2_wv, c2_bv,
                                        c2_ws, c2_bs, Bt2, b2);

    // Conv1 (A = x fp32, converted in staging)
    {
        dim3 grid(MPAD / 128, 2);
        gemm_mfma<128, true><<<grid, 256, 0, stream>>>(x, Bt1, b1, qs, (unsigned short*)kv);
    }
    attn_fused<<<NN / 4, 256, 0, stream>>>(qs, kv, rowp, csr, bn1_g, bn1_b, bn1_m, bn1_v,
                                           (unsigned int*)hbuf);

    // Conv2 (A = hbuf bf16)
    {
        dim3 grid(MPAD / 128, 2);
        gemm_mfma<64, false><<<grid, 256, 0, stream>>>(hbuf, Bt2, b2, qs, (unsigned short*)kv);
    }
    attn_fused<<<NN / 4, 256, 0, stream>>>(qs, kv, rowp, csr, bn2_g, bn2_b, bn2_m, bn2_v,
                                           (unsigned int*)hbuf);

    // Pool + MLP head
    k_pool<<<(NN + 127) / 128, 256, 0, stream>>>(hbuf, batch, g0);
    k_mlp<<<GG / 4, 256, 0, stream>>>(g0, p1_w, p1_b, p2_w, p2_b, cl1_w, cl1_b,
                                      clbn_g, clbn_b, clbn_m, clbn_v, cl2_w, cl2_b,
                                      (float*)d_out);
}

// Round 7
// 422.588 us; speedup vs baseline: 1.8995x; 1.0690x over previous
//
#include <hip/hip_runtime.h>
#include <hip/hip_bf16.h>
#include <math.h>

// Problem constants
constexpr int NN = 100000;   // nodes
constexpr int EE = 1600000;  // edges
constexpr int GG = 512;      // graphs
constexpr int MPAD = 100096; // 782 * 128 row-padded M
constexpr int NBUCK = 782;   // MPAD / 128 coarse buckets (128 nodes each)
constexpr int EPB = 8192;    // edges per partition block
constexpr int CAP = 4096;    // per-bucket fixed capacity (mean 2048, sigma~45)

typedef __attribute__((ext_vector_type(8))) short short8;
typedef __attribute__((ext_vector_type(4))) float floatx4;

__device__ __forceinline__ unsigned short f2bf_rne(float f) {
    unsigned int u = __float_as_uint(f);
    u += 0x7fff + ((u >> 16) & 1);
    return (unsigned short)(u >> 16);
}

// DPP-based add: single v_add_f32 with DPP ctrl on src.
template<int C>
__device__ __forceinline__ float dppadd(float x) {
    int t = __builtin_amdgcn_update_dpp(0, __float_as_int(x), C, 0xf, 0xf, true);
    return x + __int_as_float(t);
}
// Reduction over 4-lane group (one head = 16 features = 4 lanes x 4 feats).
__device__ __forceinline__ float qred4(float p) {
    p = dppadd<0xB1>(p);   // quad_perm [1,0,3,2]  (xor 1)
    p = dppadd<0x4E>(p);   // quad_perm [2,3,0,1]  (xor 2)
    return p;
}

__device__ __forceinline__ float dot4(uint2 kd, float q0, float q1, float q2, float q3) {
    float k0 = __uint_as_float(kd.x << 16);
    float k1 = __uint_as_float(kd.x & 0xffff0000u);
    float k2 = __uint_as_float(kd.y << 16);
    float k3 = __uint_as_float(kd.y & 0xffff0000u);
    return fmaf(k0, q0, fmaf(k1, q1, fmaf(k2, q2, k3 * q3)));
}

// ---------------------------------------------------------------------------
// CSR build: fixed-stride bucket partition (no histogram, no global scan)
// ---------------------------------------------------------------------------
__global__ __launch_bounds__(512) void k_part(const int* __restrict__ src,
                                              const int* __restrict__ dst,
                                              int* __restrict__ bcur,
                                              unsigned int* __restrict__ ppair) {
    __shared__ int cnt[NBUCK];
    __shared__ int base[NBUCK];
    int tid = threadIdx.x;
    int e0 = blockIdx.x * EPB;
    for (int j = tid; j < NBUCK; j += 512) cnt[j] = 0;
    __syncthreads();
    int myd[16], myr[16];
    #pragma unroll
    for (int t = 0; t < 16; t++) {
        int i = e0 + t * 512 + tid;
        if (i < EE) {
            int d = dst[i];
            myd[t] = d;
            myr[t] = atomicAdd(&cnt[d >> 7], 1);
        } else myd[t] = -1;
    }
    __syncthreads();
    for (int j = tid; j < NBUCK; j += 512) base[j] = atomicAdd(&bcur[j], cnt[j]);
    __syncthreads();
    #pragma unroll
    for (int t = 0; t < 16; t++) {
        int i = e0 + t * 512 + tid;
        if (myd[t] >= 0) {
            int b = myd[t] >> 7;
            int pos = base[b] + myr[t];
            if (pos < CAP)
                ppair[(size_t)b * CAP + pos] =
                    ((unsigned int)src[i] << 7) | (unsigned int)(myd[t] & 127);
        }
    }
}

// One block per bucket: counting sort by exact dst; emits rowbeg/rowend + csr.
__global__ __launch_bounds__(256) void k_bucket(const unsigned int* __restrict__ ppair,
                                                const int* __restrict__ bcur,
                                                int* __restrict__ rowbeg,
                                                int* __restrict__ rowend,
                                                int* __restrict__ csr) {
    __shared__ int cnt[128];
    __shared__ int sa[128], sb[128];
    __shared__ int cur[128];
    int t = threadIdx.x;
    int b = blockIdx.x;
    int n = bcur[b]; if (n > CAP) n = CAP;
    int start = b * CAP;
    if (t < 128) cnt[t] = 0;
    __syncthreads();
    for (int i = t; i < n; i += 256)
        atomicAdd(&cnt[ppair[start + i] & 127], 1);
    __syncthreads();
    if (t < 128) sa[t] = cnt[t];
    __syncthreads();
    int* p = sa; int* q = sb;
    for (int off = 1; off < 128; off <<= 1) {
        if (t < 128) q[t] = (t >= off) ? (p[t] + p[t - off]) : p[t];
        __syncthreads();
        int* tmp = p; p = q; q = tmp;
    }
    if (t < 128) {
        int excl = (t == 0) ? 0 : p[t - 1];
        rowbeg[b * 128 + t] = start + excl;
        rowend[b * 128 + t] = start + p[t];
        cur[t] = start + excl;
    }
    __syncthreads();
    for (int i = t; i < n; i += 256) {
        unsigned int e = ppair[start + i];
        int pos = atomicAdd(&cur[e & 127], 1);
        csr[pos] = (int)(e >> 7);
    }
}

// ---------------------------------------------------------------------------
// Pack weights: Bt[256][K] bf16.
// Col-tile 0 columns: [k(64) | v(64)]; col-tile 1 columns: [q(64) | s(64)].
// bias[256] fp32 in same column order.
// ---------------------------------------------------------------------------
template<int K>
__global__ __launch_bounds__(256) void k_cvt_w(
    const float* __restrict__ Wq, const float* __restrict__ Bq,
    const float* __restrict__ Wk, const float* __restrict__ Bk,
    const float* __restrict__ Wv, const float* __restrict__ Bv,
    const float* __restrict__ Wsk, const float* __restrict__ Bsk,
    unsigned short* __restrict__ Bt, float* __restrict__ bias) {
    int idx = blockIdx.x * 256 + threadIdx.x;  // [0, 256*K)
    int col = idx / K, k = idx % K;
    float val;
    if (col < 64)        val = Wk[k * 64 + col];
    else if (col < 128)  val = Wv[k * 64 + (col - 64)];
    else if (col < 192)  val = Wq[k * 64 + (col - 128)];
    else                 val = Wsk[k * 64 + (col - 192)];
    Bt[col * K + k] = f2bf_rne(val);
    if (k == 0) {
        float bv;
        if (col < 64)        bv = Bk[col];
        else if (col < 128)  bv = Bv[col - 64];
        else if (col < 192)  bv = Bq[col - 128];
        else                 bv = Bsk[col - 192];
        bias[col] = bv;
    }
}

// ---------------------------------------------------------------------------
// MFMA GEMM: A[M][K] (fp32 or bf16) @ Bt[256][K] bf16 ->
//   col-tile 0: kv rows [k(64)|v(64)] bf16, col-tile 1: qs fp32 [q|s].
// 128x128 tile, 4 waves (2x2), 64-k LDS chunks.
// ---------------------------------------------------------------------------
template<int K, bool AF32>
__global__ __launch_bounds__(256) void gemm_mfma(
    const void* __restrict__ Araw,
    const unsigned short* __restrict__ Bt,
    const float* __restrict__ bias,
    float* __restrict__ qs,
    unsigned short* __restrict__ kvu) {
    constexpr int SP = 72;                    // 64 + 8 pad (bf16 elts)
    __shared__ short As[128 * SP];            // 18432 B
    __shared__ short Bs[128 * SP];            // 18432 B
    int tid = threadIdx.x;
    int wave = tid >> 6, lane = tid & 63;
    int wm = wave >> 1, wn = wave & 1;
    int quad = lane >> 4, l16 = lane & 15;
    int rowBase = blockIdx.x * 128;
    int ct = blockIdx.y;                      // 0: kv cols, 1: q|s cols

    floatx4 acc[4][4];
    #pragma unroll
    for (int i = 0; i < 4; i++)
        #pragma unroll
        for (int j = 0; j < 4; j++) acc[i][j] = (floatx4)0.f;

    for (int kc = 0; kc < K; kc += 64) {
        #pragma unroll
        for (int it = 0; it < 4; it++) {
            int flat = it * 256 + tid;        // [0,1024)
            int r = flat >> 3, c8 = (flat & 7) * 8;
            int ar = rowBase + r; if (ar >= NN) ar = NN - 1;   // clamp: no OOB reads
            short8 va;
            if constexpr (AF32) {
                const float* ap = (const float*)Araw + (size_t)ar * K + kc + c8;
                float4 u0 = *reinterpret_cast<const float4*>(ap);
                float4 u1 = *reinterpret_cast<const float4*>(ap + 4);
                va[0] = (short)f2bf_rne(u0.x); va[1] = (short)f2bf_rne(u0.y);
                va[2] = (short)f2bf_rne(u0.z); va[3] = (short)f2bf_rne(u0.w);
                va[4] = (short)f2bf_rne(u1.x); va[5] = (short)f2bf_rne(u1.y);
                va[6] = (short)f2bf_rne(u1.z); va[7] = (short)f2bf_rne(u1.w);
            } else {
                va = *reinterpret_cast<const short8*>(
                        (const unsigned short*)Araw + (size_t)ar * K + kc + c8);
            }
            *reinterpret_cast<short8*>(&As[r * SP + c8]) = va;
            short8 vb = *reinterpret_cast<const short8*>(Bt + (size_t)(ct * 128 + r) * K + kc + c8);
            *reinterpret_cast<short8*>(&Bs[r * SP + c8]) = vb;
        }
        __syncthreads();
        #pragma unroll
        for (int ks = 0; ks < 2; ks++) {
            short8 af[4], bf[4];
            #pragma unroll
            for (int i = 0; i < 4; i++)
                af[i] = *reinterpret_cast<const short8*>(&As[(wm * 64 + i * 16 + l16) * SP + ks * 32 + quad * 8]);
            #pragma unroll
            for (int j = 0; j < 4; j++)
                bf[j] = *reinterpret_cast<const short8*>(&Bs[(wn * 64 + j * 16 + l16) * SP + ks * 32 + quad * 8]);
            #pragma unroll
            for (int i = 0; i < 4; i++)
                #pragma unroll
                for (int j = 0; j < 4; j++)
                    acc[i][j] = __builtin_amdgcn_mfma_f32_16x16x32_bf16(af[i], bf[j], acc[i][j], 0, 0, 0);
        }
        __syncthreads();
    }

    // Epilogue: bias + store. C layout: col = lane&15 (within n-tile), row = quad*4 + reg.
    float bj[4];
    #pragma unroll
    for (int j = 0; j < 4; j++) bj[j] = bias[ct * 128 + wn * 64 + j * 16 + l16];
    #pragma unroll
    for (int i = 0; i < 4; i++) {
        #pragma unroll
        for (int j = 0; j < 4; j++) {
            int col = wn * 64 + j * 16 + l16;
            #pragma unroll
            for (int r = 0; r < 4; r++) {
                int row = rowBase + wm * 64 + i * 16 + quad * 4 + r;
                if (row < NN) {
                    float val = acc[i][j][r] + bj[j];
                    if (ct == 1) qs[(size_t)row * 128 + col] = val;
                    else kvu[(size_t)row * 128 + col] = f2bf_rne(val);
                }
            }
        }
    }
}

// ---------------------------------------------------------------------------
// Fused attention, quarter-wave edges. One wave per dst node, 4 edges/iter.
// lane = g*16 + ql; lane covers features [4ql, 4ql+4) of group g's edge.
// kv row (bytes): [k 128B bf16 | v 128B bf16]; lane loads dwordx2.
// Head = 16 features = 4 lanes -> 2-DPP reduction. h out bf16.
// ---------------------------------------------------------------------------
__global__ __launch_bounds__(256) void attn_fused(
    const float* __restrict__ qs,
    const uint2* __restrict__ kvp,          // 32 uint2 per node row
    const int* __restrict__ rowbeg,
    const int* __restrict__ rowend,
    const int* __restrict__ csr,
    const float* __restrict__ bng, const float* __restrict__ bnb,
    const float* __restrict__ bnm, const float* __restrict__ bnv,
    uint2* __restrict__ h_out) {
    int wid = (blockIdx.x * 256 + threadIdx.x) >> 6;
    int lane = threadIdx.x & 63;
    if (wid >= NN) return;
    int g = lane >> 4, ql = lane & 15;
    const float* qrow = qs + (size_t)wid * 128;
    const float SC = 0.3606737602222409f;   // 0.25 * log2(e)
    float4 q4 = reinterpret_cast<const float4*>(qrow)[ql];
    float q0 = q4.x * SC, q1 = q4.y * SC, q2 = q4.z * SC, q3 = q4.w * SC;
    int jb = rowbeg[wid], je = rowend[wid];
    float a0 = 0.f, a1 = 0.f, a2 = 0.f, a3 = 0.f, denom = 0.f;
    int j = jb;
    for (; j + 7 < je; j += 8) {            // 2 slots x 4 groups = 8 edges in flight
        int sA = csr[j + g];
        int sB = csr[j + 4 + g];
        const uint2* rA = kvp + (size_t)sA * 32;
        const uint2* rB = kvp + (size_t)sB * 32;
        uint2 kA = rA[ql], vA = rA[16 + ql];
        uint2 kB = rB[ql], vB = rB[16 + ql];
        float pA = qred4(dot4(kA, q0, q1, q2, q3));
        float pB = qred4(dot4(kB, q0, q1, q2, q3));
        float eA = exp2f(pA), eB = exp2f(pB);
        denom += eA + eB;
        a0 = fmaf(eA, __uint_as_float(vA.x << 16), a0);
        a1 = fmaf(eA, __uint_as_float(vA.x & 0xffff0000u), a1);
        a2 = fmaf(eA, __uint_as_float(vA.y << 16), a2);
        a3 = fmaf(eA, __uint_as_float(vA.y & 0xffff0000u), a3);
        a0 = fmaf(eB, __uint_as_float(vB.x << 16), a0);
        a1 = fmaf(eB, __uint_as_float(vB.x & 0xffff0000u), a1);
        a2 = fmaf(eB, __uint_as_float(vB.y << 16), a2);
        a3 = fmaf(eB, __uint_as_float(vB.y & 0xffff0000u), a3);
    }
    for (; j < je; j += 4) {                // masked tail, 4 at a time
        int jj = j + g;
        bool valid = jj < je;
        int s = csr[valid ? jj : je - 1];
        const uint2* r = kvp + (size_t)s * 32;
        uint2 kd = r[ql], vd = r[16 + ql];
        float p = qred4(dot4(kd, q0, q1, q2, q3));
        float e = valid ? exp2f(p) : 0.f;
        denom += e;
        a0 = fmaf(e, __uint_as_float(vd.x << 16), a0);
        a1 = fmaf(e, __uint_as_float(vd.x & 0xffff0000u), a1);
        a2 = fmaf(e, __uint_as_float(vd.y << 16), a2);
        a3 = fmaf(e, __uint_as_float(vd.y & 0xffff0000u), a3);
    }
    // combine 4 groups
    a0 += __shfl_xor(a0, 16);  a0 += __shfl_xor(a0, 32);
    a1 += __shfl_xor(a1, 16);  a1 += __shfl_xor(a1, 32);
    a2 += __shfl_xor(a2, 16);  a2 += __shfl_xor(a2, 32);
    a3 += __shfl_xor(a3, 16);  a3 += __shfl_xor(a3, 32);
    denom += __shfl_xor(denom, 16);  denom += __shfl_xor(denom, 32);
    float inv = 1.f / (denom + 1e-16f);
    float4 s4 = reinterpret_cast<const float4*>(qrow + 64)[ql];
    float4 m4 = reinterpret_cast<const float4*>(bnm)[ql];
    float4 v4 = reinterpret_cast<const float4*>(bnv)[ql];
    float4 g4 = reinterpret_cast<const float4*>(bng)[ql];
    float4 b4 = reinterpret_cast<const float4*>(bnb)[ql];
    float o0 = a0 * inv + s4.x, o1 = a1 * inv + s4.y;
    float o2 = a2 * inv + s4.z, o3 = a3 * inv + s4.w;
    o0 = fmaxf((o0 - m4.x) * rsqrtf(v4.x + 1e-5f) * g4.x + b4.x, 0.f);
    o1 = fmaxf((o1 - m4.y) * rsqrtf(v4.y + 1e-5f) * g4.y + b4.y, 0.f);
    o2 = fmaxf((o2 - m4.z) * rsqrtf(v4.z + 1e-5f) * g4.z + b4.z, 0.f);
    o3 = fmaxf((o3 - m4.w) * rsqrtf(v4.w + 1e-5f) * g4.w + b4.w, 0.f);
    if (g == 0) {
        uint2 hw;
        hw.x = (unsigned int)f2bf_rne(o0) | ((unsigned int)f2bf_rne(o1) << 16);
        hw.y = (unsigned int)f2bf_rne(o2) | ((unsigned int)f2bf_rne(o3) << 16);
        h_out[(size_t)wid * 16 + ql] = hw;
    }
}

// ---------------------------------------------------------------------------
// Global max pool over sorted batch ids (values are post-ReLU, >= 0). h bf16.
// ---------------------------------------------------------------------------
__global__ __launch_bounds__(256) void k_pool(const unsigned short* __restrict__ h,
                                              const int* __restrict__ batch,
                                              float* __restrict__ g0) {
    int f = threadIdx.x & 63;
    int sub = threadIdx.x >> 6;
    int n0 = blockIdx.x * 128;
    int nEnd = n0 + 128; if (nEnd > NN) nEnd = NN;
    int cur_g = -1; float cur_m = 0.f;
    for (int n = n0 + sub; n < nEnd; n += 4) {
        int bg = batch[n];
        float val = __uint_as_float((unsigned int)h[(size_t)n * 64 + f] << 16);
        if (bg != cur_g) {
            if (cur_g >= 0) atomicMax((int*)&g0[cur_g * 64 + f], __float_as_int(cur_m));
            cur_g = bg; cur_m = val;
        } else {
            cur_m = fmaxf(cur_m, val);
        }
    }
    if (cur_g >= 0) atomicMax((int*)&g0[cur_g * 64 + f], __float_as_int(cur_m));
}

// ---------------------------------------------------------------------------
// Fused MLP head: 4 layers + BN + log_softmax. One wave per graph row.
// ---------------------------------------------------------------------------
__global__ __launch_bounds__(256) void k_mlp(
    const float* __restrict__ g0,
    const float* __restrict__ p1w, const float* __restrict__ p1b,
    const float* __restrict__ p2w, const float* __restrict__ p2b,
    const float* __restrict__ cl1w, const float* __restrict__ cl1b,
    const float* __restrict__ bg, const float* __restrict__ bb,
    const float* __restrict__ bm, const float* __restrict__ bv,
    const float* __restrict__ cl2w, const float* __restrict__ cl2b,
    float* __restrict__ outp) {
    __shared__ float w1[64 * 64], w2[64 * 64], w3[64 * 64], w4[64 * 10];
    __shared__ float sb1[64], sb2[64], sb3[64], sbn[4 * 64], sb4[10];
    int tid = threadIdx.x;
    for (int i = tid; i < 64 * 64; i += 256) { w1[i] = p1w[i]; w2[i] = p2w[i]; w3[i] = cl1w[i]; }
    for (int i = tid; i < 64 * 10; i += 256) w4[i] = cl2w[i];
    if (tid < 64) {
        sb1[tid] = p1b[tid]; sb2[tid] = p2b[tid]; sb3[tid] = cl1b[tid];
        sbn[tid] = bg[tid]; sbn[64 + tid] = bb[tid];
        sbn[128 + tid] = bm[tid]; sbn[192 + tid] = bv[tid];
    }
    if (tid < 10) sb4[tid] = cl2b[tid];
    __syncthreads();
    int lane = tid & 63, w = tid >> 6;
    int row = blockIdx.x * 4 + w;
    float x = g0[row * 64 + lane];
    if (!isfinite(x)) x = 0.f;
    float a = sb1[lane];
    for (int k = 0; k < 64; k++) a += __shfl(x, k) * w1[k * 64 + lane];
    x = fmaxf(a, 0.f);
    a = sb2[lane];
    for (int k = 0; k < 64; k++) a += __shfl(x, k) * w2[k * 64 + lane];
    x = a;
    a = sb3[lane];
    for (int k = 0; k < 64; k++) a += __shfl(x, k) * w3[k * 64 + lane];
    a = (a - sbn[128 + lane]) * rsqrtf(sbn[192 + lane] + 1e-5f) * sbn[lane] + sbn[64 + lane];
    x = fmaxf(a, 0.f);
    float lg[10];
    #pragma unroll
    for (int c = 0; c < 10; c++) {
        float p = x * w4[lane * 10 + c];
        p += __shfl_xor(p, 1);  p += __shfl_xor(p, 2);  p += __shfl_xor(p, 4);
        p += __shfl_xor(p, 8);  p += __shfl_xor(p, 16); p += __shfl_xor(p, 32);
        lg[c] = p + sb4[c];
    }
    float mx = lg[0];
    #pragma unroll
    for (int c = 1; c < 10; c++) mx = fmaxf(mx, lg[c]);
    float s = 0.f;
    #pragma unroll
    for (int c = 0; c < 10; c++) s += __expf(lg[c] - mx);
    float lse = mx + logf(s);
    float o = 0.f;
    #pragma unroll
    for (int c = 0; c < 10; c++) if (lane == c) o = lg[c];
    if (lane < 10) outp[row * 10 + lane] = o - lse;
}

// ---------------------------------------------------------------------------
extern "C" void kernel_launch(void* const* d_in, const int* in_sizes, int n_in,
                              void* d_out, int out_size, void* d_ws, size_t ws_size,
                              hipStream_t stream) {
    const float* x     = (const float*)d_in[0];
    const int*   ei    = (const int*)d_in[1];
    const int*   batch = (const int*)d_in[2];
    const float *c1_wq = (const float*)d_in[3],  *c1_bq = (const float*)d_in[4];
    const float *c1_wk = (const float*)d_in[5],  *c1_bk = (const float*)d_in[6];
    const float *c1_wv = (const float*)d_in[7],  *c1_bv = (const float*)d_in[8];
    const float *c1_ws = (const float*)d_in[9],  *c1_bs = (const float*)d_in[10];
    const float *c2_wq = (const float*)d_in[11], *c2_bq = (const float*)d_in[12];
    const float *c2_wk = (const float*)d_in[13], *c2_bk = (const float*)d_in[14];
    const float *c2_wv = (const float*)d_in[15], *c2_bv = (const float*)d_in[16];
    const float *c2_ws = (const float*)d_in[17], *c2_bs = (const float*)d_in[18];
    const float *bn1_g = (const float*)d_in[19], *bn1_b = (const float*)d_in[20];
    const float *bn1_m = (const float*)d_in[21], *bn1_v = (const float*)d_in[22];
    const float *bn2_g = (const float*)d_in[23], *bn2_b = (const float*)d_in[24];
    const float *bn2_m = (const float*)d_in[25], *bn2_v = (const float*)d_in[26];
    const float *clbn_g = (const float*)d_in[27], *clbn_b = (const float*)d_in[28];
    const float *clbn_m = (const float*)d_in[29], *clbn_v = (const float*)d_in[30];
    const float *p1_w = (const float*)d_in[31], *p2_w = (const float*)d_in[32];
    const float *cl1_w = (const float*)d_in[33], *cl2_w = (const float*)d_in[34];
    const float *p1_b = (const float*)d_in[35], *p2_b = (const float*)d_in[36];
    const float *cl1_b = (const float*)d_in[37], *cl2_b = (const float*)d_in[38];

    char* ws = (char*)d_ws;
    float*          qs     = (float*)(ws);                        //  51,200,000
    unsigned int*   kv     = (unsigned int*)(ws + 51200000);      //  25,600,000
    unsigned short* hbuf   = (unsigned short*)(ws + 76800000);    //  12,812,288
    unsigned int*   ppair  = (unsigned int*)(ws + 89612288);      //  12,812,288 (782*4096*4)
    int*            csr    = (int*)(ws + 102424576);              //  12,812,288
    int*            rowbeg = (int*)(ws + 115236864);              //     400,384
    int*            rowend = (int*)(ws + 115637248);              //     400,384
    int*            bcur   = (int*)(ws + 116037632);              //       3,136
    float*          g0     = (float*)(ws + 116040768);            //     131,072
    unsigned short* Bt1    = (unsigned short*)(ws + 116171840);   //      65,536
    float*          b1     = (float*)(ws + 116237376);            //       1,024
    unsigned short* Bt2    = (unsigned short*)(ws + 116238400);   //      32,768
    float*          b2     = (float*)(ws + 116271168);            //       1,024

    const int* srcIdx = ei;
    const int* dstIdx = ei + EE;

    hipMemsetAsync(bcur, 0, NBUCK * sizeof(int), stream);
    hipMemsetAsync(g0, 0, GG * 64 * sizeof(float), stream);

    // CSR build: fixed-stride bucket partition + per-bucket counting sort
    constexpr int PBLK = (EE + EPB - 1) / EPB;   // 196
    k_part<<<PBLK, 512, 0, stream>>>(srcIdx, dstIdx, bcur, ppair);
    k_bucket<<<NBUCK, 256, 0, stream>>>(ppair, bcur, rowbeg, rowend, csr);

    // Weight packing
    k_cvt_w<128><<<128, 256, 0, stream>>>(c1_wq, c1_bq, c1_wk, c1_bk, c1_wv, c1_bv,
                                          c1_ws, c1_bs, Bt1, b1);
    k_cvt_w<64><<<64, 256, 0, stream>>>(c2_wq, c2_bq, c2_wk, c2_bk, c2_wv, c2_bv,
                                        c2_ws, c2_bs, Bt2, b2);

    // Conv1 (A = x fp32, converted in staging)
    {
        dim3 grid(MPAD / 128, 2);
        gemm_mfma<128, true><<<grid, 256, 0, stream>>>(x, Bt1, b1, qs, (unsigned short*)kv);
    }
    attn_fused<<<NN / 4, 256, 0, stream>>>(qs, (const uint2*)kv, rowbeg, rowend, csr,
                                           bn1_g, bn1_b, bn1_m, bn1_v, (uint2*)hbuf);

    // Conv2 (A = hbuf bf16)
    {
        dim3 grid(MPAD / 128, 2);
        gemm_mfma<64, false><<<grid, 256, 0, stream>>>(hbuf, Bt2, b2, qs, (unsigned short*)kv);
    }
    attn_fused<<<NN / 4, 256, 0, stream>>>(qs, (const uint2*)kv, rowbeg, rowend, csr,
                                           bn2_g, bn2_b, bn2_m, bn2_v, (uint2*)hbuf);

    // Pool + MLP head
    k_pool<<<(NN + 127) / 128, 256, 0, stream>>>(hbuf, batch, g0);
    k_mlp<<<GG / 4, 256, 0, stream>>>(g0, p1_w, p1_b, p2_w, p2_b, cl1_w, cl1_b,
                                      clbn_g, clbn_b, clbn_m, clbn_v, cl2_w, cl2_b,
                                      (float*)d_out);
}

// Round 8
// 411.349 us; speedup vs baseline: 1.9514x; 1.0273x over previous
//
#include <hip/hip_runtime.h>
#include <hip/hip_bf16.h>
#include <math.h>

// Problem constants
constexpr int NN = 100000;   // nodes
constexpr int EE = 1600000;  // edges
constexpr int GG = 512;      // graphs
constexpr int MPAD = 100096; // 782 * 128 row-padded M
constexpr int NBUCK = 782;   // MPAD / 128 coarse buckets (128 nodes each)
constexpr int EPB = 8192;    // edges per partition block
constexpr int CAP = 4096;    // per-bucket fixed capacity (mean 2048, sigma~45)

typedef __attribute__((ext_vector_type(8))) short short8;
typedef __attribute__((ext_vector_type(4))) float floatx4;

__device__ __forceinline__ unsigned short f2bf_rne(float f) {
    unsigned int u = __float_as_uint(f);
    u += 0x7fff + ((u >> 16) & 1);
    return (unsigned short)(u >> 16);
}
__device__ __forceinline__ float bf_lo(unsigned int u) { return __uint_as_float(u << 16); }
__device__ __forceinline__ float bf_hi(unsigned int u) { return __uint_as_float(u & 0xffff0000u); }

// DPP-based add: single v_add_f32 with DPP ctrl on src.
template<int C>
__device__ __forceinline__ float dppadd(float x) {
    int t = __builtin_amdgcn_update_dpp(0, __float_as_int(x), C, 0xf, 0xf, true);
    return x + __int_as_float(t);
}
// Reduction over 4-lane group (one head = 16 features = 4 lanes x 4 feats).
__device__ __forceinline__ float qred4(float p) {
    p = dppadd<0xB1>(p);   // quad_perm [1,0,3,2]  (xor 1)
    p = dppadd<0x4E>(p);   // quad_perm [2,3,0,1]  (xor 2)
    return p;
}

__device__ __forceinline__ float dot4(uint2 kd, float q0, float q1, float q2, float q3) {
    return fmaf(bf_lo(kd.x), q0, fmaf(bf_hi(kd.x), q1,
           fmaf(bf_lo(kd.y), q2, bf_hi(kd.y) * q3)));
}

// ---------------------------------------------------------------------------
// CSR build: fixed-stride bucket partition (no histogram, no global scan)
// ---------------------------------------------------------------------------
__global__ __launch_bounds__(512) void k_part(const int* __restrict__ src,
                                              const int* __restrict__ dst,
                                              int* __restrict__ bcur,
                                              unsigned int* __restrict__ ppair) {
    __shared__ int cnt[NBUCK];
    __shared__ int base[NBUCK];
    int tid = threadIdx.x;
    int e0 = blockIdx.x * EPB;
    for (int j = tid; j < NBUCK; j += 512) cnt[j] = 0;
    __syncthreads();
    int myd[16], myr[16];
    #pragma unroll
    for (int t = 0; t < 16; t++) {
        int i = e0 + t * 512 + tid;
        if (i < EE) {
            int d = dst[i];
            myd[t] = d;
            myr[t] = atomicAdd(&cnt[d >> 7], 1);
        } else myd[t] = -1;
    }
    __syncthreads();
    for (int j = tid; j < NBUCK; j += 512) base[j] = atomicAdd(&bcur[j], cnt[j]);
    __syncthreads();
    #pragma unroll
    for (int t = 0; t < 16; t++) {
        int i = e0 + t * 512 + tid;
        if (myd[t] >= 0) {
            int b = myd[t] >> 7;
            int pos = base[b] + myr[t];
            if (pos < CAP)
                ppair[(size_t)b * CAP + pos] =
                    ((unsigned int)src[i] << 7) | (unsigned int)(myd[t] & 127);
        }
    }
}

// One block per bucket: counting sort by exact dst; emits rowbeg/rowend + csr.
__global__ __launch_bounds__(256) void k_bucket(const unsigned int* __restrict__ ppair,
                                                const int* __restrict__ bcur,
                                                int* __restrict__ rowbeg,
                                                int* __restrict__ rowend,
                                                int* __restrict__ csr) {
    __shared__ int cnt[128];
    __shared__ int sa[128], sb[128];
    __shared__ int cur[128];
    int t = threadIdx.x;
    int b = blockIdx.x;
    int n = bcur[b]; if (n > CAP) n = CAP;
    int start = b * CAP;
    if (t < 128) cnt[t] = 0;
    __syncthreads();
    for (int i = t; i < n; i += 256)
        atomicAdd(&cnt[ppair[start + i] & 127], 1);
    __syncthreads();
    if (t < 128) sa[t] = cnt[t];
    __syncthreads();
    int* p = sa; int* q = sb;
    for (int off = 1; off < 128; off <<= 1) {
        if (t < 128) q[t] = (t >= off) ? (p[t] + p[t - off]) : p[t];
        __syncthreads();
        int* tmp = p; p = q; q = tmp;
    }
    if (t < 128) {
        int excl = (t == 0) ? 0 : p[t - 1];
        rowbeg[b * 128 + t] = start + excl;
        rowend[b * 128 + t] = start + p[t];
        cur[t] = start + excl;
    }
    __syncthreads();
    for (int i = t; i < n; i += 256) {
        unsigned int e = ppair[start + i];
        int pos = atomicAdd(&cur[e & 127], 1);
        csr[pos] = (int)(e >> 7);
    }
}

// ---------------------------------------------------------------------------
// Pack weights for BOTH layers + zero g0, one dispatch.
// Bt[256][K] bf16; col order [k(64)|v(64)] then [q(64)|s(64)]. bias fp32.
// ---------------------------------------------------------------------------
__global__ __launch_bounds__(256) void k_cvt_all(
    const float* __restrict__ w1q, const float* __restrict__ b1q,
    const float* __restrict__ w1k, const float* __restrict__ b1k,
    const float* __restrict__ w1v, const float* __restrict__ b1v,
    const float* __restrict__ w1s, const float* __restrict__ b1s,
    const float* __restrict__ w2q, const float* __restrict__ b2q,
    const float* __restrict__ w2k, const float* __restrict__ b2k,
    const float* __restrict__ w2v, const float* __restrict__ b2v,
    const float* __restrict__ w2s, const float* __restrict__ b2s,
    unsigned short* __restrict__ Bt1, float* __restrict__ bias1,
    unsigned short* __restrict__ Bt2, float* __restrict__ bias2,
    float* __restrict__ g0) {
    int b = blockIdx.x, tid = threadIdx.x;
    if (b < 128) {
        g0[b * 256 + tid] = 0.f;   // 128*256 = 32768 = GG*64
        int idx = b * 256 + tid;   // [0, 256*128)
        int col = idx >> 7, k = idx & 127;
        float val;
        if (col < 64)        val = w1k[k * 64 + col];
        else if (col < 128)  val = w1v[k * 64 + (col - 64)];
        else if (col < 192)  val = w1q[k * 64 + (col - 128)];
        else                 val = w1s[k * 64 + (col - 192)];
        Bt1[col * 128 + k] = f2bf_rne(val);
        if (k == 0) {
            float bv;
            if (col < 64)        bv = b1k[col];
            else if (col < 128)  bv = b1v[col - 64];
            else if (col < 192)  bv = b1q[col - 128];
            else                 bv = b1s[col - 192];
            bias1[col] = bv;
        }
    } else {
        int idx = (b - 128) * 256 + tid;  // [0, 256*64)
        int col = idx >> 6, k = idx & 63;
        float val;
        if (col < 64)        val = w2k[k * 64 + col];
        else if (col < 128)  val = w2v[k * 64 + (col - 64)];
        else if (col < 192)  val = w2q[k * 64 + (col - 128)];
        else                 val = w2s[k * 64 + (col - 192)];
        Bt2[col * 64 + k] = f2bf_rne(val);
        if (k == 0) {
            float bv;
            if (col < 64)        bv = b2k[col];
            else if (col < 128)  bv = b2v[col - 64];
            else if (col < 192)  bv = b2q[col - 128];
            else                 bv = b2s[col - 192];
            bias2[col] = bv;
        }
    }
}

// ---------------------------------------------------------------------------
// MFMA GEMM: A[M][K] (fp32 or bf16) @ Bt[256][K] bf16 -> bf16 outputs:
//   col-tile 0 -> kv rows [k(64)|v(64)], col-tile 1 -> qsb rows [q(64)|s(64)].
// 128x128 tile, 4 waves (2x2). A staged in LDS; B fragments direct from
// global (Bt <= 64 KB, L2-hot across all blocks -> no Bs stage, no 2nd LDS).
// ---------------------------------------------------------------------------
template<int K, bool AF32>
__global__ __launch_bounds__(256) void gemm_mfma(
    const void* __restrict__ Araw,
    const unsigned short* __restrict__ Bt,
    const float* __restrict__ bias,
    unsigned short* __restrict__ out0,
    unsigned short* __restrict__ out1) {
    constexpr int SP = 72;                    // 64 + 8 pad (bf16 elts)
    __shared__ short As[128 * SP];            // 18432 B
    int tid = threadIdx.x;
    int wave = tid >> 6, lane = tid & 63;
    int wm = wave >> 1, wn = wave & 1;
    int quad = lane >> 4, l16 = lane & 15;
    int rowBase = blockIdx.x * 128;
    int ct = blockIdx.y;                      // 0: kv cols, 1: q|s cols

    const unsigned short* bRow[4];
    #pragma unroll
    for (int j = 0; j < 4; j++)
        bRow[j] = Bt + (size_t)(ct * 128 + wn * 64 + j * 16 + l16) * K + quad * 8;

    floatx4 acc[4][4];
    #pragma unroll
    for (int i = 0; i < 4; i++)
        #pragma unroll
        for (int j = 0; j < 4; j++) acc[i][j] = (floatx4)0.f;

    for (int kc = 0; kc < K; kc += 64) {
        #pragma unroll
        for (int it = 0; it < 4; it++) {
            int flat = it * 256 + tid;        // [0,1024)
            int r = flat >> 3, c8 = (flat & 7) * 8;
            int ar = rowBase + r; if (ar >= NN) ar = NN - 1;   // clamp: no OOB reads
            short8 va;
            if constexpr (AF32) {
                const float* ap = (const float*)Araw + (size_t)ar * K + kc + c8;
                float4 u0 = *reinterpret_cast<const float4*>(ap);
                float4 u1 = *reinterpret_cast<const float4*>(ap + 4);
                va[0] = (short)f2bf_rne(u0.x); va[1] = (short)f2bf_rne(u0.y);
                va[2] = (short)f2bf_rne(u0.z); va[3] = (short)f2bf_rne(u0.w);
                va[4] = (short)f2bf_rne(u1.x); va[5] = (short)f2bf_rne(u1.y);
                va[6] = (short)f2bf_rne(u1.z); va[7] = (short)f2bf_rne(u1.w);
            } else {
                va = *reinterpret_cast<const short8*>(
                        (const unsigned short*)Araw + (size_t)ar * K + kc + c8);
            }
            *reinterpret_cast<short8*>(&As[r * SP + c8]) = va;
        }
        __syncthreads();
        #pragma unroll
        for (int ks = 0; ks < 2; ks++) {
            short8 af[4], bf[4];
            #pragma unroll
            for (int i = 0; i < 4; i++)
                af[i] = *reinterpret_cast<const short8*>(&As[(wm * 64 + i * 16 + l16) * SP + ks * 32 + quad * 8]);
            #pragma unroll
            for (int j = 0; j < 4; j++)
                bf[j] = *reinterpret_cast<const short8*>(bRow[j] + kc + ks * 32);
            #pragma unroll
            for (int i = 0; i < 4; i++)
                #pragma unroll
                for (int j = 0; j < 4; j++)
                    acc[i][j] = __builtin_amdgcn_mfma_f32_16x16x32_bf16(af[i], bf[j], acc[i][j], 0, 0, 0);
        }
        __syncthreads();
    }

    // Epilogue: bias + bf16 store. C layout: col = lane&15, row = quad*4 + reg.
    unsigned short* outp = ct ? out1 : out0;
    float bj[4];
    #pragma unroll
    for (int j = 0; j < 4; j++) bj[j] = bias[ct * 128 + wn * 64 + j * 16 + l16];
    #pragma unroll
    for (int i = 0; i < 4; i++) {
        #pragma unroll
        for (int j = 0; j < 4; j++) {
            int col = wn * 64 + j * 16 + l16;
            #pragma unroll
            for (int r = 0; r < 4; r++) {
                int row = rowBase + wm * 64 + i * 16 + quad * 4 + r;
                if (row < NN)
                    outp[(size_t)row * 128 + col] = f2bf_rne(acc[i][j][r] + bj[j]);
            }
        }
    }
}

// ---------------------------------------------------------------------------
// Fused attention, quarter-wave edges. One wave per dst node, 8 edges/iter.
// lane = g*16 + ql; lane covers features [4ql, 4ql+4) of group g's edge.
// kv row: [k 128B bf16 | v 128B bf16]; qsb row: [q 128B bf16 | s 128B bf16].
// Head = 16 features = 4 lanes -> 2-DPP reduction. h out bf16.
// ---------------------------------------------------------------------------
__global__ __launch_bounds__(256) void attn_fused(
    const unsigned short* __restrict__ qsb,
    const uint2* __restrict__ kvp,          // 32 uint2 per node row
    const int* __restrict__ rowbeg,
    const int* __restrict__ rowend,
    const int* __restrict__ csr,
    const float* __restrict__ bng, const float* __restrict__ bnb,
    const float* __restrict__ bnm, const float* __restrict__ bnv,
    uint2* __restrict__ h_out) {
    int wid = (blockIdx.x * 256 + threadIdx.x) >> 6;
    int lane = threadIdx.x & 63;
    if (wid >= NN) return;
    int g = lane >> 4, ql = lane & 15;
    const uint2* qrow = reinterpret_cast<const uint2*>(qsb + (size_t)wid * 128);
    const float SC = 0.3606737602222409f;   // 0.25 * log2(e)
    uint2 qd = qrow[ql];
    float q0 = bf_lo(qd.x) * SC, q1 = bf_hi(qd.x) * SC;
    float q2 = bf_lo(qd.y) * SC, q3 = bf_hi(qd.y) * SC;
    int jb = rowbeg[wid], je = rowend[wid];
    float a0 = 0.f, a1 = 0.f, a2 = 0.f, a3 = 0.f, denom = 0.f;
    int j = jb;
    for (; j + 7 < je; j += 8) {            // 2 slots x 4 groups = 8 edges in flight
        int sA = csr[j + g];
        int sB = csr[j + 4 + g];
        const uint2* rA = kvp + (size_t)sA * 32;
        const uint2* rB = kvp + (size_t)sB * 32;
        uint2 kA = rA[ql], vA = rA[16 + ql];
        uint2 kB = rB[ql], vB = rB[16 + ql];
        float pA = qred4(dot4(kA, q0, q1, q2, q3));
        float pB = qred4(dot4(kB, q0, q1, q2, q3));
        float eA = exp2f(pA), eB = exp2f(pB);
        denom += eA + eB;
        a0 = fmaf(eA, bf_lo(vA.x), a0);
        a1 = fmaf(eA, bf_hi(vA.x), a1);
        a2 = fmaf(eA, bf_lo(vA.y), a2);
        a3 = fmaf(eA, bf_hi(vA.y), a3);
        a0 = fmaf(eB, bf_lo(vB.x), a0);
        a1 = fmaf(eB, bf_hi(vB.x), a1);
        a2 = fmaf(eB, bf_lo(vB.y), a2);
        a3 = fmaf(eB, bf_hi(vB.y), a3);
    }
    for (; j < je; j += 4) {                // masked tail, 4 at a time
        int jj = j + g;
        bool valid = jj < je;
        int s = csr[valid ? jj : je - 1];
        const uint2* r = kvp + (size_t)s * 32;
        uint2 kd = r[ql], vd = r[16 + ql];
        float p = qred4(dot4(kd, q0, q1, q2, q3));
        float e = valid ? exp2f(p) : 0.f;
        denom += e;
        a0 = fmaf(e, bf_lo(vd.x), a0);
        a1 = fmaf(e, bf_hi(vd.x), a1);
        a2 = fmaf(e, bf_lo(vd.y), a2);
        a3 = fmaf(e, bf_hi(vd.y), a3);
    }
    // combine 4 groups
    a0 += __shfl_xor(a0, 16);  a0 += __shfl_xor(a0, 32);
    a1 += __shfl_xor(a1, 16);  a1 += __shfl_xor(a1, 32);
    a2 += __shfl_xor(a2, 16);  a2 += __shfl_xor(a2, 32);
    a3 += __shfl_xor(a3, 16);  a3 += __shfl_xor(a3, 32);
    denom += __shfl_xor(denom, 16);  denom += __shfl_xor(denom, 32);
    float inv = 1.f / (denom + 1e-16f);
    uint2 sd = qrow[16 + ql];
    float4 m4 = reinterpret_cast<const float4*>(bnm)[ql];
    float4 v4 = reinterpret_cast<const float4*>(bnv)[ql];
    float4 g4 = reinterpret_cast<const float4*>(bng)[ql];
    float4 b4 = reinterpret_cast<const float4*>(bnb)[ql];
    float o0 = a0 * inv + bf_lo(sd.x), o1 = a1 * inv + bf_hi(sd.x);
    float o2 = a2 * inv + bf_lo(sd.y), o3 = a3 * inv + bf_hi(sd.y);
    o0 = fmaxf((o0 - m4.x) * rsqrtf(v4.x + 1e-5f) * g4.x + b4.x, 0.f);
    o1 = fmaxf((o1 - m4.y) * rsqrtf(v4.y + 1e-5f) * g4.y + b4.y, 0.f);
    o2 = fmaxf((o2 - m4.z) * rsqrtf(v4.z + 1e-5f) * g4.z + b4.z, 0.f);
    o3 = fmaxf((o3 - m4.w) * rsqrtf(v4.w + 1e-5f) * g4.w + b4.w, 0.f);
    if (g == 0) {
        uint2 hw;
        hw.x = (unsigned int)f2bf_rne(o0) | ((unsigned int)f2bf_rne(o1) << 16);
        hw.y = (unsigned int)f2bf_rne(o2) | ((unsigned int)f2bf_rne(o3) << 16);
        h_out[(size_t)wid * 16 + ql] = hw;
    }
}

// ---------------------------------------------------------------------------
// Global max pool over sorted batch ids (values are post-ReLU, >= 0). h bf16.
// ---------------------------------------------------------------------------
__global__ __launch_bounds__(256) void k_pool(const unsigned short* __restrict__ h,
                                              const int* __restrict__ batch,
                                              float* __restrict__ g0) {
    int f = threadIdx.x & 63;
    int sub = threadIdx.x >> 6;
    int n0 = blockIdx.x * 128;
    int nEnd = n0 + 128; if (nEnd > NN) nEnd = NN;
    int cur_g = -1; float cur_m = 0.f;
    for (int n = n0 + sub; n < nEnd; n += 4) {
        int bg = batch[n];
        float val = __uint_as_float((unsigned int)h[(size_t)n * 64 + f] << 16);
        if (bg != cur_g) {
            if (cur_g >= 0) atomicMax((int*)&g0[cur_g * 64 + f], __float_as_int(cur_m));
            cur_g = bg; cur_m = val;
        } else {
            cur_m = fmaxf(cur_m, val);
        }
    }
    if (cur_g >= 0) atomicMax((int*)&g0[cur_g * 64 + f], __float_as_int(cur_m));
}

// ---------------------------------------------------------------------------
// Fused MLP head: 4 layers + BN + log_softmax. One wave per graph row.
// ---------------------------------------------------------------------------
__global__ __launch_bounds__(256) void k_mlp(
    const float* __restrict__ g0,
    const float* __restrict__ p1w, const float* __restrict__ p1b,
    const float* __restrict__ p2w, const float* __restrict__ p2b,
    const float* __restrict__ cl1w, const float* __restrict__ cl1b,
    const float* __restrict__ bg, const float* __restrict__ bb,
    const float* __restrict__ bm, const float* __restrict__ bv,
    const float* __restrict__ cl2w, const float* __restrict__ cl2b,
    float* __restrict__ outp) {
    __shared__ float w1[64 * 64], w2[64 * 64], w3[64 * 64], w4[64 * 10];
    __shared__ float sb1[64], sb2[64], sb3[64], sbn[4 * 64], sb4[10];
    int tid = threadIdx.x;
    for (int i = tid; i < 64 * 64; i += 256) { w1[i] = p1w[i]; w2[i] = p2w[i]; w3[i] = cl1w[i]; }
    for (int i = tid; i < 64 * 10; i += 256) w4[i] = cl2w[i];
    if (tid < 64) {
        sb1[tid] = p1b[tid]; sb2[tid] = p2b[tid]; sb3[tid] = cl1b[tid];
        sbn[tid] = bg[tid]; sbn[64 + tid] = bb[tid];
        sbn[128 + tid] = bm[tid]; sbn[192 + tid] = bv[tid];
    }
    if (tid < 10) sb4[tid] = cl2b[tid];
    __syncthreads();
    int lane = tid & 63, w = tid >> 6;
    int row = blockIdx.x * 4 + w;
    float x = g0[row * 64 + lane];
    if (!isfinite(x)) x = 0.f;
    float a = sb1[lane];
    for (int k = 0; k < 64; k++) a += __shfl(x, k) * w1[k * 64 + lane];
    x = fmaxf(a, 0.f);
    a = sb2[lane];
    for (int k = 0; k < 64; k++) a += __shfl(x, k) * w2[k * 64 + lane];
    x = a;
    a = sb3[lane];
    for (int k = 0; k < 64; k++) a += __shfl(x, k) * w3[k * 64 + lane];
    a = (a - sbn[128 + lane]) * rsqrtf(sbn[192 + lane] + 1e-5f) * sbn[lane] + sbn[64 + lane];
    x = fmaxf(a, 0.f);
    float lg[10];
    #pragma unroll
    for (int c = 0; c < 10; c++) {
        float p = x * w4[lane * 10 + c];
        p += __shfl_xor(p, 1);  p += __shfl_xor(p, 2);  p += __shfl_xor(p, 4);
        p += __shfl_xor(p, 8);  p += __shfl_xor(p, 16); p += __shfl_xor(p, 32);
        lg[c] = p + sb4[c];
    }
    float mx = lg[0];
    #pragma unroll
    for (int c = 1; c < 10; c++) mx = fmaxf(mx, lg[c]);
    float s = 0.f;
    #pragma unroll
    for (int c = 0; c < 10; c++) s += __expf(lg[c] - mx);
    float lse = mx + logf(s);
    float o = 0.f;
    #pragma unroll
    for (int c = 0; c < 10; c++) if (lane == c) o = lg[c];
    if (lane < 10) outp[row * 10 + lane] = o - lse;
}

// ---------------------------------------------------------------------------
extern "C" void kernel_launch(void* const* d_in, const int* in_sizes, int n_in,
                              void* d_out, int out_size, void* d_ws, size_t ws_size,
                              hipStream_t stream) {
    const float* x     = (const float*)d_in[0];
    const int*   ei    = (const int*)d_in[1];
    const int*   batch = (const int*)d_in[2];
    const float *c1_wq = (const float*)d_in[3],  *c1_bq = (const float*)d_in[4];
    const float *c1_wk = (const float*)d_in[5],  *c1_bk = (const float*)d_in[6];
    const float *c1_wv = (const float*)d_in[7],  *c1_bv = (const float*)d_in[8];
    const float *c1_ws = (const float*)d_in[9],  *c1_bs = (const float*)d_in[10];
    const float *c2_wq = (const float*)d_in[11], *c2_bq = (const float*)d_in[12];
    const float *c2_wk = (const float*)d_in[13], *c2_bk = (const float*)d_in[14];
    const float *c2_wv = (const float*)d_in[15], *c2_bv = (const float*)d_in[16];
    const float *c2_ws = (const float*)d_in[17], *c2_bs = (const float*)d_in[18];
    const float *bn1_g = (const float*)d_in[19], *bn1_b = (const float*)d_in[20];
    const float *bn1_m = (const float*)d_in[21], *bn1_v = (const float*)d_in[22];
    const float *bn2_g = (const float*)d_in[23], *bn2_b = (const float*)d_in[24];
    const float *bn2_m = (const float*)d_in[25], *bn2_v = (const float*)d_in[26];
    const float *clbn_g = (const float*)d_in[27], *clbn_b = (const float*)d_in[28];
    const float *clbn_m = (const float*)d_in[29], *clbn_v = (const float*)d_in[30];
    const float *p1_w = (const float*)d_in[31], *p2_w = (const float*)d_in[32];
    const float *cl1_w = (const float*)d_in[33], *cl2_w = (const float*)d_in[34];
    const float *p1_b = (const float*)d_in[35], *p2_b = (const float*)d_in[36];
    const float *cl1_b = (const float*)d_in[37], *cl2_b = (const float*)d_in[38];

    char* ws = (char*)d_ws;
    unsigned short* kv     = (unsigned short*)(ws);               //  25,600,000
    unsigned short* qsb    = (unsigned short*)(ws + 25600000);    //  25,600,000
    unsigned short* hbuf   = (unsigned short*)(ws + 51200000);    //  12,812,288
    unsigned int*   ppair  = (unsigned int*)(ws + 64012288);      //  12,812,288
    int*            csr    = (int*)(ws + 76824576);               //  12,812,288
    int*            rowbeg = (int*)(ws + 89636864);               //     400,384
    int*            rowend = (int*)(ws + 90037248);               //     400,384
    int*            bcur   = (int*)(ws + 90437632);               //       3,136
    float*          g0     = (float*)(ws + 90440768);             //     131,072
    unsigned short* Bt1    = (unsigned short*)(ws + 90571840);    //      65,536
    float*          b1     = (float*)(ws + 90637376);             //       1,024
    unsigned short* Bt2    = (unsigned short*)(ws + 90638400);    //      32,768
    float*          b2     = (float*)(ws + 90671168);             //       1,024

    const int* srcIdx = ei;
    const int* dstIdx = ei + EE;

    hipMemsetAsync(bcur, 0, NBUCK * sizeof(int), stream);

    // Weight packing + g0 zero (one dispatch)
    k_cvt_all<<<192, 256, 0, stream>>>(c1_wq, c1_bq, c1_wk, c1_bk, c1_wv, c1_bv,
                                       c1_ws, c1_bs,
                                       c2_wq, c2_bq, c2_wk, c2_bk, c2_wv, c2_bv,
                                       c2_ws, c2_bs, Bt1, b1, Bt2, b2, g0);

    // CSR build: fixed-stride bucket partition + per-bucket counting sort
    constexpr int PBLK = (EE + EPB - 1) / EPB;   // 196
    k_part<<<PBLK, 512, 0, stream>>>(srcIdx, dstIdx, bcur, ppair);
    k_bucket<<<NBUCK, 256, 0, stream>>>(ppair, bcur, rowbeg, rowend, csr);

    // Conv1 (A = x fp32, converted in staging)
    {
        dim3 grid(MPAD / 128, 2);
        gemm_mfma<128, true><<<grid, 256, 0, stream>>>(x, Bt1, b1, kv, qsb);
    }
    attn_fused<<<NN / 4, 256, 0, stream>>>(qsb, (const uint2*)kv, rowbeg, rowend, csr,
                                           bn1_g, bn1_b, bn1_m, bn1_v, (uint2*)hbuf);

    // Conv2 (A = hbuf bf16)
    {
        dim3 grid(MPAD / 128, 2);
        gemm_mfma<64, false><<<grid, 256, 0, stream>>>(hbuf, Bt2, b2, kv, qsb);
    }
    attn_fused<<<NN / 4, 256, 0, stream>>>(qsb, (const uint2*)kv, rowbeg, rowend, csr,
                                           bn2_g, bn2_b, bn2_m, bn2_v, (uint2*)hbuf);

    // Pool + MLP head
    k_pool<<<(NN + 127) / 128, 256, 0, stream>>>(hbuf, batch, g0);
    k_mlp<<<GG / 4, 256, 0, stream>>>(g0, p1_w, p1_b, p2_w, p2_b, cl1_w, cl1_b,
                                      clbn_g, clbn_b, clbn_m, clbn_v, cl2_w, cl2_b,
                                      (float*)d_out);
}

// Round 9
// 402.374 us; speedup vs baseline: 1.9949x; 1.0223x over previous
//
#include <hip/hip_runtime.h>
#include <hip/hip_bf16.h>
#include <math.h>

// Problem constants
constexpr int NN = 100000;   // nodes
constexpr int EE = 1600000;  // edges
constexpr int GG = 512;      // graphs
constexpr int MPAD = 100096; // 782 * 128 row-padded M
constexpr int NBUCK = 782;   // MPAD / 128 coarse buckets (128 nodes each)
constexpr int EPB = 8192;    // edges per partition block
constexpr int CAP = 4096;    // per-bucket fixed capacity (mean 2048, sigma~45)

typedef __attribute__((ext_vector_type(8))) short short8;
typedef __attribute__((ext_vector_type(4))) float floatx4;

__device__ __forceinline__ unsigned short f2bf_rne(float f) {
    unsigned int u = __float_as_uint(f);
    u += 0x7fff + ((u >> 16) & 1);
    return (unsigned short)(u >> 16);
}
__device__ __forceinline__ float bf_lo(unsigned int u) { return __uint_as_float(u << 16); }
__device__ __forceinline__ float bf_hi(unsigned int u) { return __uint_as_float(u & 0xffff0000u); }

// DPP-based add: single v_add_f32 with DPP ctrl on src.
template<int C>
__device__ __forceinline__ float dppadd(float x) {
    int t = __builtin_amdgcn_update_dpp(0, __float_as_int(x), C, 0xf, 0xf, true);
    return x + __int_as_float(t);
}
// Reduction over 4-lane group (one head = 16 features = 4 lanes x 4 feats).
__device__ __forceinline__ float qred4(float p) {
    p = dppadd<0xB1>(p);   // quad_perm [1,0,3,2]  (xor 1)
    p = dppadd<0x4E>(p);   // quad_perm [2,3,0,1]  (xor 2)
    return p;
}

__device__ __forceinline__ float dot4(uint2 kd, float q0, float q1, float q2, float q3) {
    return fmaf(bf_lo(kd.x), q0, fmaf(bf_hi(kd.x), q1,
           fmaf(bf_lo(kd.y), q2, bf_hi(kd.y) * q3)));
}

// ---------------------------------------------------------------------------
// CSR build: fixed-stride bucket partition (no histogram, no global scan)
// ---------------------------------------------------------------------------
__global__ __launch_bounds__(512) void k_part(const int* __restrict__ src,
                                              const int* __restrict__ dst,
                                              int* __restrict__ bcur,
                                              unsigned int* __restrict__ ppair) {
    __shared__ int cnt[NBUCK];
    __shared__ int base[NBUCK];
    int tid = threadIdx.x;
    int e0 = blockIdx.x * EPB;
    for (int j = tid; j < NBUCK; j += 512) cnt[j] = 0;
    __syncthreads();
    int myd[16], myr[16];
    #pragma unroll
    for (int t = 0; t < 16; t++) {
        int i = e0 + t * 512 + tid;
        if (i < EE) {
            int d = dst[i];
            myd[t] = d;
            myr[t] = atomicAdd(&cnt[d >> 7], 1);
        } else myd[t] = -1;
    }
    __syncthreads();
    for (int j = tid; j < NBUCK; j += 512) base[j] = atomicAdd(&bcur[j], cnt[j]);
    __syncthreads();
    #pragma unroll
    for (int t = 0; t < 16; t++) {
        int i = e0 + t * 512 + tid;
        if (myd[t] >= 0) {
            int b = myd[t] >> 7;
            int pos = base[b] + myr[t];
            if (pos < CAP)
                ppair[(size_t)b * CAP + pos] =
                    ((unsigned int)src[i] << 7) | (unsigned int)(myd[t] & 127);
        }
    }
}

// One block per bucket: counting sort by exact dst; emits rowbeg/rowend + csr.
__global__ __launch_bounds__(256) void k_bucket(const unsigned int* __restrict__ ppair,
                                                const int* __restrict__ bcur,
                                                int* __restrict__ rowbeg,
                                                int* __restrict__ rowend,
                                                int* __restrict__ csr) {
    __shared__ int cnt[128];
    __shared__ int sa[128], sb[128];
    __shared__ int cur[128];
    int t = threadIdx.x;
    int b = blockIdx.x;
    int n = bcur[b]; if (n > CAP) n = CAP;
    int start = b * CAP;
    if (t < 128) cnt[t] = 0;
    __syncthreads();
    for (int i = t; i < n; i += 256)
        atomicAdd(&cnt[ppair[start + i] & 127], 1);
    __syncthreads();
    if (t < 128) sa[t] = cnt[t];
    __syncthreads();
    int* p = sa; int* q = sb;
    for (int off = 1; off < 128; off <<= 1) {
        if (t < 128) q[t] = (t >= off) ? (p[t] + p[t - off]) : p[t];
        __syncthreads();
        int* tmp = p; p = q; q = tmp;
    }
    if (t < 128) {
        int excl = (t == 0) ? 0 : p[t - 1];
        rowbeg[b * 128 + t] = start + excl;
        rowend[b * 128 + t] = start + p[t];
        cur[t] = start + excl;
    }
    __syncthreads();
    for (int i = t; i < n; i += 256) {
        unsigned int e = ppair[start + i];
        int pos = atomicAdd(&cur[e & 127], 1);
        csr[pos] = (int)(e >> 7);
    }
}

// ---------------------------------------------------------------------------
// Pack weights for BOTH layers + zero g0, one dispatch.
// Bt[256][K] bf16; col order [k(64)|v(64)|q(64)|s(64)]. bias fp32.
// ---------------------------------------------------------------------------
__global__ __launch_bounds__(256) void k_cvt_all(
    const float* __restrict__ w1q, const float* __restrict__ b1q,
    const float* __restrict__ w1k, const float* __restrict__ b1k,
    const float* __restrict__ w1v, const float* __restrict__ b1v,
    const float* __restrict__ w1s, const float* __restrict__ b1s,
    const float* __restrict__ w2q, const float* __restrict__ b2q,
    const float* __restrict__ w2k, const float* __restrict__ b2k,
    const float* __restrict__ w2v, const float* __restrict__ b2v,
    const float* __restrict__ w2s, const float* __restrict__ b2s,
    unsigned short* __restrict__ Bt1, float* __restrict__ bias1,
    unsigned short* __restrict__ Bt2, float* __restrict__ bias2,
    float* __restrict__ g0) {
    int b = blockIdx.x, tid = threadIdx.x;
    if (b < 128) {
        g0[b * 256 + tid] = 0.f;   // 128*256 = 32768 = GG*64
        int idx = b * 256 + tid;   // [0, 256*128)
        int col = idx >> 7, k = idx & 127;
        float val;
        if (col < 64)        val = w1k[k * 64 + col];
        else if (col < 128)  val = w1v[k * 64 + (col - 64)];
        else if (col < 192)  val = w1q[k * 64 + (col - 128)];
        else                 val = w1s[k * 64 + (col - 192)];
        Bt1[col * 128 + k] = f2bf_rne(val);
        if (k == 0) {
            float bv;
            if (col < 64)        bv = b1k[col];
            else if (col < 128)  bv = b1v[col - 64];
            else if (col < 192)  bv = b1q[col - 128];
            else                 bv = b1s[col - 192];
            bias1[col] = bv;
        }
    } else {
        int idx = (b - 128) * 256 + tid;  // [0, 256*64)
        int col = idx >> 6, k = idx & 63;
        float val;
        if (col < 64)        val = w2k[k * 64 + col];
        else if (col < 128)  val = w2v[k * 64 + (col - 64)];
        else if (col < 192)  val = w2q[k * 64 + (col - 128)];
        else                 val = w2s[k * 64 + (col - 192)];
        Bt2[col * 64 + k] = f2bf_rne(val);
        if (k == 0) {
            float bv;
            if (col < 64)        bv = b2k[col];
            else if (col < 128)  bv = b2v[col - 64];
            else if (col < 192)  bv = b2q[col - 128];
            else                 bv = b2s[col - 192];
            bias2[col] = bv;
        }
    }
}

// ---------------------------------------------------------------------------
// MFMA GEMM, one-pass: A[M][K] @ Bt[256][K] -> kv [k|v] bf16 + qsb [q|s] bf16.
// Block = 128 rows x 256 cols, 512 threads (8 waves, 2x4). A read ONCE.
// LDS: As 18.4 KB + Bs 36.9 KB = 55.3 KB -> 2 blocks/CU.
// ---------------------------------------------------------------------------
template<int K, bool AF32>
__global__ __launch_bounds__(512) void gemm_mfma(
    const void* __restrict__ Araw,
    const unsigned short* __restrict__ Bt,
    const float* __restrict__ bias,
    unsigned short* __restrict__ out0,      // kv
    unsigned short* __restrict__ out1) {    // qsb
    constexpr int SP = 72;                    // 64 + 8 pad (bf16 elts)
    __shared__ short As[128 * SP];            // 18432 B
    __shared__ short Bs[256 * SP];            // 36864 B
    int tid = threadIdx.x;
    int wave = tid >> 6, lane = tid & 63;
    int wm = wave >> 2, wn = wave & 3;        // 2 row-halves x 4 col-quarters
    int quad = lane >> 4, l16 = lane & 15;
    int rowBase = blockIdx.x * 128;

    floatx4 acc[4][4];
    #pragma unroll
    for (int i = 0; i < 4; i++)
        #pragma unroll
        for (int j = 0; j < 4; j++) acc[i][j] = (floatx4)0.f;

    for (int kc = 0; kc < K; kc += 64) {
        // Stage A: 128 rows x 64 k = 1024 flats over 512 threads
        #pragma unroll
        for (int it = 0; it < 2; it++) {
            int flat = it * 512 + tid;
            int r = flat >> 3, c8 = (flat & 7) * 8;
            int ar = rowBase + r; if (ar >= NN) ar = NN - 1;   // clamp: no OOB
            short8 va;
            if constexpr (AF32) {
                const float* ap = (const float*)Araw + (size_t)ar * K + kc + c8;
                float4 u0 = *reinterpret_cast<const float4*>(ap);
                float4 u1 = *reinterpret_cast<const float4*>(ap + 4);
                va[0] = (short)f2bf_rne(u0.x); va[1] = (short)f2bf_rne(u0.y);
                va[2] = (short)f2bf_rne(u0.z); va[3] = (short)f2bf_rne(u0.w);
                va[4] = (short)f2bf_rne(u1.x); va[5] = (short)f2bf_rne(u1.y);
                va[6] = (short)f2bf_rne(u1.z); va[7] = (short)f2bf_rne(u1.w);
            } else {
                va = *reinterpret_cast<const short8*>(
                        (const unsigned short*)Araw + (size_t)ar * K + kc + c8);
            }
            *reinterpret_cast<short8*>(&As[r * SP + c8]) = va;
        }
        // Stage B: 256 cols x 64 k = 2048 flats over 512 threads
        #pragma unroll
        for (int it = 0; it < 4; it++) {
            int flat = it * 512 + tid;
            int r = flat >> 3, c8 = (flat & 7) * 8;
            short8 vb = *reinterpret_cast<const short8*>(Bt + (size_t)r * K + kc + c8);
            *reinterpret_cast<short8*>(&Bs[r * SP + c8]) = vb;
        }
        __syncthreads();
        #pragma unroll
        for (int ks = 0; ks < 2; ks++) {
            short8 af[4], bf[4];
            #pragma unroll
            for (int i = 0; i < 4; i++)
                af[i] = *reinterpret_cast<const short8*>(&As[(wm * 64 + i * 16 + l16) * SP + ks * 32 + quad * 8]);
            #pragma unroll
            for (int j = 0; j < 4; j++)
                bf[j] = *reinterpret_cast<const short8*>(&Bs[(wn * 64 + j * 16 + l16) * SP + ks * 32 + quad * 8]);
            #pragma unroll
            for (int i = 0; i < 4; i++)
                #pragma unroll
                for (int j = 0; j < 4; j++)
                    acc[i][j] = __builtin_amdgcn_mfma_f32_16x16x32_bf16(af[i], bf[j], acc[i][j], 0, 0, 0);
        }
        __syncthreads();
    }

    // Epilogue: bias + bf16 store. C layout: col = lane&15, row = quad*4 + reg.
    unsigned short* outp = (wn < 2) ? out0 : out1;
    int colBase = (wn & 1) * 64;
    float bj[4];
    #pragma unroll
    for (int j = 0; j < 4; j++) bj[j] = bias[wn * 64 + j * 16 + l16];
    #pragma unroll
    for (int i = 0; i < 4; i++) {
        #pragma unroll
        for (int j = 0; j < 4; j++) {
            int col = colBase + j * 16 + l16;
            #pragma unroll
            for (int r = 0; r < 4; r++) {
                int row = rowBase + wm * 64 + i * 16 + quad * 4 + r;
                if (row < NN)
                    outp[(size_t)row * 128 + col] = f2bf_rne(acc[i][j][r] + bj[j]);
            }
        }
    }
}

// ---------------------------------------------------------------------------
// Fused attention, quarter-wave edges. One wave per dst node, 8 edges/iter.
// lane = g*16 + ql; lane covers features [4ql, 4ql+4) of group g's edge.
// kv row: [k 128B bf16 | v 128B bf16]; qsb row: [q 128B bf16 | s 128B bf16].
// 32-bit byte-offset addressing (saddr form): boff = (s<<8) + ql*8.
// ---------------------------------------------------------------------------
__global__ __launch_bounds__(256) void attn_fused(
    const unsigned short* __restrict__ qsb,
    const unsigned char* __restrict__ kvb,   // kv as bytes, 256 B per node
    const int* __restrict__ rowbeg,
    const int* __restrict__ rowend,
    const int* __restrict__ csr,
    const float* __restrict__ bng, const float* __restrict__ bnb,
    const float* __restrict__ bnm, const float* __restrict__ bnv,
    uint2* __restrict__ h_out) {
    int wid = (blockIdx.x * 256 + threadIdx.x) >> 6;
    int lane = threadIdx.x & 63;
    if (wid >= NN) return;
    int g = lane >> 4, ql = lane & 15;
    unsigned int qb8 = (unsigned int)(ql << 3);   // byte offset of lane's 8 B
    const uint2* qrow = reinterpret_cast<const uint2*>(qsb + (size_t)wid * 128);
    const float SC = 0.3606737602222409f;   // 0.25 * log2(e)
    uint2 qd = qrow[ql];
    float q0 = bf_lo(qd.x) * SC, q1 = bf_hi(qd.x) * SC;
    float q2 = bf_lo(qd.y) * SC, q3 = bf_hi(qd.y) * SC;
    int jb = rowbeg[wid], je = rowend[wid];
    float a0 = 0.f, a1 = 0.f, a2 = 0.f, a3 = 0.f, denom = 0.f;
    int j = jb;
    for (; j + 7 < je; j += 8) {            // 2 slots x 4 groups = 8 edges in flight
        unsigned int oA = ((unsigned int)csr[j + g] << 8) + qb8;
        unsigned int oB = ((unsigned int)csr[j + 4 + g] << 8) + qb8;
        uint2 kA = *reinterpret_cast<const uint2*>(kvb + oA);
        uint2 vA = *reinterpret_cast<const uint2*>(kvb + oA + 128);
        uint2 kB = *reinterpret_cast<const uint2*>(kvb + oB);
        uint2 vB = *reinterpret_cast<const uint2*>(kvb + oB + 128);
        float pA = qred4(dot4(kA, q0, q1, q2, q3));
        float pB = qred4(dot4(kB, q0, q1, q2, q3));
        float eA = exp2f(pA), eB = exp2f(pB);
        denom += eA + eB;
        a0 = fmaf(eA, bf_lo(vA.x), a0);
        a1 = fmaf(eA, bf_hi(vA.x), a1);
        a2 = fmaf(eA, bf_lo(vA.y), a2);
        a3 = fmaf(eA, bf_hi(vA.y), a3);
        a0 = fmaf(eB, bf_lo(vB.x), a0);
        a1 = fmaf(eB, bf_hi(vB.x), a1);
        a2 = fmaf(eB, bf_lo(vB.y), a2);
        a3 = fmaf(eB, bf_hi(vB.y), a3);
    }
    for (; j < je; j += 4) {                // masked tail, 4 at a time
        int jj = j + g;
        bool valid = jj < je;
        unsigned int o = ((unsigned int)csr[valid ? jj : je - 1] << 8) + qb8;
        uint2 kd = *reinterpret_cast<const uint2*>(kvb + o);
        uint2 vd = *reinterpret_cast<const uint2*>(kvb + o + 128);
        float p = qred4(dot4(kd, q0, q1, q2, q3));
        float e = valid ? exp2f(p) : 0.f;
        denom += e;
        a0 = fmaf(e, bf_lo(vd.x), a0);
        a1 = fmaf(e, bf_hi(vd.x), a1);
        a2 = fmaf(e, bf_lo(vd.y), a2);
        a3 = fmaf(e, bf_hi(vd.y), a3);
    }
    // combine 4 groups
    a0 += __shfl_xor(a0, 16);  a0 += __shfl_xor(a0, 32);
    a1 += __shfl_xor(a1, 16);  a1 += __shfl_xor(a1, 32);
    a2 += __shfl_xor(a2, 16);  a2 += __shfl_xor(a2, 32);
    a3 += __shfl_xor(a3, 16);  a3 += __shfl_xor(a3, 32);
    denom += __shfl_xor(denom, 16);  denom += __shfl_xor(denom, 32);
    float inv = 1.f / (denom + 1e-16f);
    uint2 sd = qrow[16 + ql];
    float4 m4 = reinterpret_cast<const float4*>(bnm)[ql];
    float4 v4 = reinterpret_cast<const float4*>(bnv)[ql];
    float4 g4 = reinterpret_cast<const float4*>(bng)[ql];
    float4 b4 = reinterpret_cast<const float4*>(bnb)[ql];
    float o0 = a0 * inv + bf_lo(sd.x), o1 = a1 * inv + bf_hi(sd.x);
    float o2 = a2 * inv + bf_lo(sd.y), o3 = a3 * inv + bf_hi(sd.y);
    o0 = fmaxf((o0 - m4.x) * rsqrtf(v4.x + 1e-5f) * g4.x + b4.x, 0.f);
    o1 = fmaxf((o1 - m4.y) * rsqrtf(v4.y + 1e-5f) * g4.y + b4.y, 0.f);
    o2 = fmaxf((o2 - m4.z) * rsqrtf(v4.z + 1e-5f) * g4.z + b4.z, 0.f);
    o3 = fmaxf((o3 - m4.w) * rsqrtf(v4.w + 1e-5f) * g4.w + b4.w, 0.f);
    if (g == 0) {
        uint2 hw;
        hw.x = (unsigned int)f2bf_rne(o0) | ((unsigned int)f2bf_rne(o1) << 16);
        hw.y = (unsigned int)f2bf_rne(o2) | ((unsigned int)f2bf_rne(o3) << 16);
        h_out[(size_t)wid * 16 + ql] = hw;
    }
}

// ---------------------------------------------------------------------------
// Global max pool over sorted batch ids (values are post-ReLU, >= 0). h bf16.
// ---------------------------------------------------------------------------
__global__ __launch_bounds__(256) void k_pool(const unsigned short* __restrict__ h,
                                              const int* __restrict__ batch,
                                              float* __restrict__ g0) {
    int f = threadIdx.x & 63;
    int sub = threadIdx.x >> 6;
    int n0 = blockIdx.x * 128;
    int nEnd = n0 + 128; if (nEnd > NN) nEnd = NN;
    int cur_g = -1; float cur_m = 0.f;
    for (int n = n0 + sub; n < nEnd; n += 4) {
        int bg = batch[n];
        float val = __uint_as_float((unsigned int)h[(size_t)n * 64 + f] << 16);
        if (bg != cur_g) {
            if (cur_g >= 0) atomicMax((int*)&g0[cur_g * 64 + f], __float_as_int(cur_m));
            cur_g = bg; cur_m = val;
        } else {
            cur_m = fmaxf(cur_m, val);
        }
    }
    if (cur_g >= 0) atomicMax((int*)&g0[cur_g * 64 + f], __float_as_int(cur_m));
}

// ---------------------------------------------------------------------------
// Fused MLP head: 4 layers + BN + log_softmax. One wave per graph row.
// ---------------------------------------------------------------------------
__global__ __launch_bounds__(256) void k_mlp(
    const float* __restrict__ g0,
    const float* __restrict__ p1w, const float* __restrict__ p1b,
    const float* __restrict__ p2w, const float* __restrict__ p2b,
    const float* __restrict__ cl1w, const float* __restrict__ cl1b,
    const float* __restrict__ bg, const float* __restrict__ bb,
    const float* __restrict__ bm, const float* __restrict__ bv,
    const float* __restrict__ cl2w, const float* __restrict__ cl2b,
    float* __restrict__ outp) {
    __shared__ float w1[64 * 64], w2[64 * 64], w3[64 * 64], w4[64 * 10];
    __shared__ float sb1[64], sb2[64], sb3[64], sbn[4 * 64], sb4[10];
    int tid = threadIdx.x;
    for (int i = tid; i < 64 * 64; i += 256) { w1[i] = p1w[i]; w2[i] = p2w[i]; w3[i] = cl1w[i]; }
    for (int i = tid; i < 64 * 10; i += 256) w4[i] = cl2w[i];
    if (tid < 64) {
        sb1[tid] = p1b[tid]; sb2[tid] = p2b[tid]; sb3[tid] = cl1b[tid];
        sbn[tid] = bg[tid]; sbn[64 + tid] = bb[tid];
        sbn[128 + tid] = bm[tid]; sbn[192 + tid] = bv[tid];
    }
    if (tid < 10) sb4[tid] = cl2b[tid];
    __syncthreads();
    int lane = tid & 63, w = tid >> 6;
    int row = blockIdx.x * 4 + w;
    float x = g0[row * 64 + lane];
    if (!isfinite(x)) x = 0.f;
    float a = sb1[lane];
    for (int k = 0; k < 64; k++) a += __shfl(x, k) * w1[k * 64 + lane];
    x = fmaxf(a, 0.f);
    a = sb2[lane];
    for (int k = 0; k < 64; k++) a += __shfl(x, k) * w2[k * 64 + lane];
    x = a;
    a = sb3[lane];
    for (int k = 0; k < 64; k++) a += __shfl(x, k) * w3[k * 64 + lane];
    a = (a - sbn[128 + lane]) * rsqrtf(sbn[192 + lane] + 1e-5f) * sbn[lane] + sbn[64 + lane];
    x = fmaxf(a, 0.f);
    float lg[10];
    #pragma unroll
    for (int c = 0; c < 10; c++) {
        float p = x * w4[lane * 10 + c];
        p += __shfl_xor(p, 1);  p += __shfl_xor(p, 2);  p += __shfl_xor(p, 4);
        p += __shfl_xor(p, 8);  p += __shfl_xor(p, 16); p += __shfl_xor(p, 32);
        lg[c] = p + sb4[c];
    }
    float mx = lg[0];
    #pragma unroll
    for (int c = 1; c < 10; c++) mx = fmaxf(mx, lg[c]);
    float s = 0.f;
    #pragma unroll
    for (int c = 0; c < 10; c++) s += __expf(lg[c] - mx);
    float lse = mx + logf(s);
    float o = 0.f;
    #pragma unroll
    for (int c = 0; c < 10; c++) if (lane == c) o = lg[c];
    if (lane < 10) outp[row * 10 + lane] = o - lse;
}

// ---------------------------------------------------------------------------
extern "C" void kernel_launch(void* const* d_in, const int* in_sizes, int n_in,
                              void* d_out, int out_size, void* d_ws, size_t ws_size,
                              hipStream_t stream) {
    const float* x     = (const float*)d_in[0];
    const int*   ei    = (const int*)d_in[1];
    const int*   batch = (const int*)d_in[2];
    const float *c1_wq = (const float*)d_in[3],  *c1_bq = (const float*)d_in[4];
    const float *c1_wk = (const float*)d_in[5],  *c1_bk = (const float*)d_in[6];
    const float *c1_wv = (const float*)d_in[7],  *c1_bv = (const float*)d_in[8];
    const float *c1_ws = (const float*)d_in[9],  *c1_bs = (const float*)d_in[10];
    const float *c2_wq = (const float*)d_in[11], *c2_bq = (const float*)d_in[12];
    const float *c2_wk = (const float*)d_in[13], *c2_bk = (const float*)d_in[14];
    const float *c2_wv = (const float*)d_in[15], *c2_bv = (const float*)d_in[16];
    const float *c2_ws = (const float*)d_in[17], *c2_bs = (const float*)d_in[18];
    const float *bn1_g = (const float*)d_in[19], *bn1_b = (const float*)d_in[20];
    const float *bn1_m = (const float*)d_in[21], *bn1_v = (const float*)d_in[22];
    const float *bn2_g = (const float*)d_in[23], *bn2_b = (const float*)d_in[24];
    const float *bn2_m = (const float*)d_in[25], *bn2_v = (const float*)d_in[26];
    const float *clbn_g = (const float*)d_in[27], *clbn_b = (const float*)d_in[28];
    const float *clbn_m = (const float*)d_in[29], *clbn_v = (const float*)d_in[30];
    const float *p1_w = (const float*)d_in[31], *p2_w = (const float*)d_in[32];
    const float *cl1_w = (const float*)d_in[33], *cl2_w = (const float*)d_in[34];
    const float *p1_b = (const float*)d_in[35], *p2_b = (const float*)d_in[36];
    const float *cl1_b = (const float*)d_in[37], *cl2_b = (const float*)d_in[38];

    char* ws = (char*)d_ws;
    unsigned short* kv     = (unsigned short*)(ws);               //  25,600,000
    unsigned short* qsb    = (unsigned short*)(ws + 25600000);    //  25,600,000
    unsigned short* hbuf   = (unsigned short*)(ws + 51200000);    //  12,812,288
    unsigned int*   ppair  = (unsigned int*)(ws + 64012288);      //  12,812,288
    int*            csr    = (int*)(ws + 76824576);               //  12,812,288
    int*            rowbeg = (int*)(ws + 89636864);               //     400,384
    int*            rowend = (int*)(ws + 90037248);               //     400,384
    int*            bcur   = (int*)(ws + 90437632);               //       3,136
    float*          g0     = (float*)(ws + 90440768);             //     131,072
    unsigned short* Bt1    = (unsigned short*)(ws + 90571840);    //      65,536
    float*          b1     = (float*)(ws + 90637376);             //       1,024
    unsigned short* Bt2    = (unsigned short*)(ws + 90638400);    //      32,768
    float*          b2     = (float*)(ws + 90671168);             //       1,024

    const int* srcIdx = ei;
    const int* dstIdx = ei + EE;

    hipMemsetAsync(bcur, 0, NBUCK * sizeof(int), stream);

    // Weight packing + g0 zero (one dispatch)
    k_cvt_all<<<192, 256, 0, stream>>>(c1_wq, c1_bq, c1_wk, c1_bk, c1_wv, c1_bv,
                                       c1_ws, c1_bs,
                                       c2_wq, c2_bq, c2_wk, c2_bk, c2_wv, c2_bv,
                                       c2_ws, c2_bs, Bt1, b1, Bt2, b2, g0);

    // CSR build: fixed-stride bucket partition + per-bucket counting sort
    constexpr int PBLK = (EE + EPB - 1) / EPB;   // 196
    k_part<<<PBLK, 512, 0, stream>>>(srcIdx, dstIdx, bcur, ppair);
    k_bucket<<<NBUCK, 256, 0, stream>>>(ppair, bcur, rowbeg, rowend, csr);

    // Conv1 (A = x fp32, converted in staging; single A pass)
    gemm_mfma<128, true><<<MPAD / 128, 512, 0, stream>>>(x, Bt1, b1, kv, qsb);
    attn_fused<<<NN / 4, 256, 0, stream>>>(qsb, (const unsigned char*)kv,
                                           rowbeg, rowend, csr,
                                           bn1_g, bn1_b, bn1_m, bn1_v, (uint2*)hbuf);

    // Conv2 (A = hbuf bf16)
    gemm_mfma<64, false><<<MPAD / 128, 512, 0, stream>>>(hbuf, Bt2, b2, kv, qsb);
    attn_fused<<<NN / 4, 256, 0, stream>>>(qsb, (const unsigned char*)kv,
                                           rowbeg, rowend, csr,
                                           bn2_g, bn2_b, bn2_m, bn2_v, (uint2*)hbuf);

    // Pool + MLP head
    k_pool<<<(NN + 127) / 128, 256, 0, stream>>>(hbuf, batch, g0);
    k_mlp<<<GG / 4, 256, 0, stream>>>(g0, p1_w, p1_b, p2_w, p2_b, cl1_w, cl1_b,
                                      clbn_g, clbn_b, clbn_m, clbn_v, cl2_w, cl2_b,
                                      (float*)d_out);
}

// Round 10
// 389.935 us; speedup vs baseline: 2.0585x; 1.0319x over previous
//
#include <hip/hip_runtime.h>
#include <hip/hip_bf16.h>
#include <math.h>

// Problem constants
constexpr int NN = 100000;   // nodes
constexpr int EE = 1600000;  // edges
constexpr int GG = 512;      // graphs
constexpr int MPAD = 100096; // 782 * 128 row-padded M
constexpr int NBUCK = 782;   // MPAD / 128 coarse buckets (128 nodes each)
constexpr int EPB = 8192;    // edges per partition block
constexpr int CAP = 4096;    // per-bucket fixed capacity (mean 2048, sigma~45)

typedef __attribute__((ext_vector_type(8))) short short8;
typedef __attribute__((ext_vector_type(4))) float floatx4;

__device__ __forceinline__ unsigned short f2bf_rne(float f) {
    unsigned int u = __float_as_uint(f);
    u += 0x7fff + ((u >> 16) & 1);
    return (unsigned short)(u >> 16);
}
__device__ __forceinline__ float bf_lo(unsigned int u) { return __uint_as_float(u << 16); }
__device__ __forceinline__ float bf_hi(unsigned int u) { return __uint_as_float(u & 0xffff0000u); }

// DPP-based add: single v_add_f32 with DPP ctrl on src.
template<int C>
__device__ __forceinline__ float dppadd(float x) {
    int t = __builtin_amdgcn_update_dpp(0, __float_as_int(x), C, 0xf, 0xf, true);
    return x + __int_as_float(t);
}

// 8-feature dot: lane's uint4 of bf16 pairs vs pre-scaled q[8].
__device__ __forceinline__ float dot8(uint4 kd, const float* q) {
    float p =      bf_lo(kd.x) * q[0];
    p = fmaf(bf_hi(kd.x), q[1], p);
    p = fmaf(bf_lo(kd.y), q[2], p);
    p = fmaf(bf_hi(kd.y), q[3], p);
    p = fmaf(bf_lo(kd.z), q[4], p);
    p = fmaf(bf_hi(kd.z), q[5], p);
    p = fmaf(bf_lo(kd.w), q[6], p);
    p = fmaf(bf_hi(kd.w), q[7], p);
    return p;
}
__device__ __forceinline__ void acc8(float* a, float e, uint4 vd) {
    a[0] = fmaf(e, bf_lo(vd.x), a[0]);
    a[1] = fmaf(e, bf_hi(vd.x), a[1]);
    a[2] = fmaf(e, bf_lo(vd.y), a[2]);
    a[3] = fmaf(e, bf_hi(vd.y), a[3]);
    a[4] = fmaf(e, bf_lo(vd.z), a[4]);
    a[5] = fmaf(e, bf_hi(vd.z), a[5]);
    a[6] = fmaf(e, bf_lo(vd.w), a[6]);
    a[7] = fmaf(e, bf_hi(vd.w), a[7]);
}

// ---------------------------------------------------------------------------
// CSR build: fixed-stride bucket partition (no histogram, no global scan)
// ---------------------------------------------------------------------------
__global__ __launch_bounds__(512) void k_part(const int* __restrict__ src,
                                              const int* __restrict__ dst,
                                              int* __restrict__ bcur,
                                              unsigned int* __restrict__ ppair) {
    __shared__ int cnt[NBUCK];
    __shared__ int base[NBUCK];
    int tid = threadIdx.x;
    int e0 = blockIdx.x * EPB;
    for (int j = tid; j < NBUCK; j += 512) cnt[j] = 0;
    __syncthreads();
    int myd[16], myr[16];
    #pragma unroll
    for (int t = 0; t < 16; t++) {
        int i = e0 + t * 512 + tid;
        if (i < EE) {
            int d = dst[i];
            myd[t] = d;
            myr[t] = atomicAdd(&cnt[d >> 7], 1);
        } else myd[t] = -1;
    }
    __syncthreads();
    for (int j = tid; j < NBUCK; j += 512) base[j] = atomicAdd(&bcur[j], cnt[j]);
    __syncthreads();
    #pragma unroll
    for (int t = 0; t < 16; t++) {
        int i = e0 + t * 512 + tid;
        if (myd[t] >= 0) {
            int b = myd[t] >> 7;
            int pos = base[b] + myr[t];
            if (pos < CAP)
                ppair[(size_t)b * CAP + pos] =
                    ((unsigned int)src[i] << 7) | (unsigned int)(myd[t] & 127);
        }
    }
}

// One block per bucket: counting sort by exact dst; emits rowbeg/rowend + csr.
__global__ __launch_bounds__(256) void k_bucket(const unsigned int* __restrict__ ppair,
                                                const int* __restrict__ bcur,
                                                int* __restrict__ rowbeg,
                                                int* __restrict__ rowend,
                                                int* __restrict__ csr) {
    __shared__ int cnt[128];
    __shared__ int sa[128], sb[128];
    __shared__ int cur[128];
    int t = threadIdx.x;
    int b = blockIdx.x;
    int n = bcur[b]; if (n > CAP) n = CAP;
    int start = b * CAP;
    if (t < 128) cnt[t] = 0;
    __syncthreads();
    for (int i = t; i < n; i += 256)
        atomicAdd(&cnt[ppair[start + i] & 127], 1);
    __syncthreads();
    if (t < 128) sa[t] = cnt[t];
    __syncthreads();
    int* p = sa; int* q = sb;
    for (int off = 1; off < 128; off <<= 1) {
        if (t < 128) q[t] = (t >= off) ? (p[t] + p[t - off]) : p[t];
        __syncthreads();
        int* tmp = p; p = q; q = tmp;
    }
    if (t < 128) {
        int excl = (t == 0) ? 0 : p[t - 1];
        rowbeg[b * 128 + t] = start + excl;
        rowend[b * 128 + t] = start + p[t];
        cur[t] = start + excl;
    }
    __syncthreads();
    for (int i = t; i < n; i += 256) {
        unsigned int e = ppair[start + i];
        int pos = atomicAdd(&cur[e & 127], 1);
        csr[pos] = (int)(e >> 7);
    }
}

// ---------------------------------------------------------------------------
// Pack weights for BOTH layers + zero g0 + precompute BN scale/shift.
// Bt[256][K] bf16; col order [k(64)|v(64)|q(64)|s(64)]. bias fp32.
// bnp layout: [layer*128 + 0..63] = scale, [layer*128 + 64..127] = shift.
// ---------------------------------------------------------------------------
__global__ __launch_bounds__(256) void k_cvt_all(
    const float* __restrict__ w1q, const float* __restrict__ b1q,
    const float* __restrict__ w1k, const float* __restrict__ b1k,
    const float* __restrict__ w1v, const float* __restrict__ b1v,
    const float* __restrict__ w1s, const float* __restrict__ b1s,
    const float* __restrict__ w2q, const float* __restrict__ b2q,
    const float* __restrict__ w2k, const float* __restrict__ b2k,
    const float* __restrict__ w2v, const float* __restrict__ b2v,
    const float* __restrict__ w2s, const float* __restrict__ b2s,
    const float* __restrict__ bn1g, const float* __restrict__ bn1b,
    const float* __restrict__ bn1m, const float* __restrict__ bn1v,
    const float* __restrict__ bn2g, const float* __restrict__ bn2b,
    const float* __restrict__ bn2m, const float* __restrict__ bn2v,
    unsigned short* __restrict__ Bt1, float* __restrict__ bias1,
    unsigned short* __restrict__ Bt2, float* __restrict__ bias2,
    float* __restrict__ bnp, float* __restrict__ g0) {
    int b = blockIdx.x, tid = threadIdx.x;
    if (b == 0 && tid < 128) {
        int layer = tid >> 6, f = tid & 63;
        float gg = layer ? bn2g[f] : bn1g[f];
        float bb = layer ? bn2b[f] : bn1b[f];
        float mm = layer ? bn2m[f] : bn1m[f];
        float vv = layer ? bn2v[f] : bn1v[f];
        float sc = gg * rsqrtf(vv + 1e-5f);
        bnp[layer * 128 + f] = sc;
        bnp[layer * 128 + 64 + f] = bb - mm * sc;
    }
    if (b < 128) {
        g0[b * 256 + tid] = 0.f;   // 128*256 = 32768 = GG*64
        int idx = b * 256 + tid;   // [0, 256*128)
        int col = idx >> 7, k = idx & 127;
        float val;
        if (col < 64)        val = w1k[k * 64 + col];
        else if (col < 128)  val = w1v[k * 64 + (col - 64)];
        else if (col < 192)  val = w1q[k * 64 + (col - 128)];
        else                 val = w1s[k * 64 + (col - 192)];
        Bt1[col * 128 + k] = f2bf_rne(val);
        if (k == 0) {
            float bv;
            if (col < 64)        bv = b1k[col];
            else if (col < 128)  bv = b1v[col - 64];
            else if (col < 192)  bv = b1q[col - 128];
            else                 bv = b1s[col - 192];
            bias1[col] = bv;
        }
    } else {
        int idx = (b - 128) * 256 + tid;  // [0, 256*64)
        int col = idx >> 6, k = idx & 63;
        float val;
        if (col < 64)        val = w2k[k * 64 + col];
        else if (col < 128)  val = w2v[k * 64 + (col - 64)];
        else if (col < 192)  val = w2q[k * 64 + (col - 128)];
        else                 val = w2s[k * 64 + (col - 192)];
        Bt2[col * 64 + k] = f2bf_rne(val);
        if (k == 0) {
            float bv;
            if (col < 64)        bv = b2k[col];
            else if (col < 128)  bv = b2v[col - 64];
            else if (col < 192)  bv = b2q[col - 128];
            else                 bv = b2s[col - 192];
            bias2[col] = bv;
        }
    }
}

// ---------------------------------------------------------------------------
// MFMA GEMM, one-pass: A[M][K] @ Bt[256][K] -> kv [k|v] bf16 + qsb [q|s] bf16.
// Block = 128 rows x 256 cols, 512 threads (8 waves, 2x4). A read ONCE.
// ---------------------------------------------------------------------------
template<int K, bool AF32>
__global__ __launch_bounds__(512) void gemm_mfma(
    const void* __restrict__ Araw,
    const unsigned short* __restrict__ Bt,
    const float* __restrict__ bias,
    unsigned short* __restrict__ out0,      // kv
    unsigned short* __restrict__ out1) {    // qsb
    constexpr int SP = 72;                    // 64 + 8 pad (bf16 elts)
    __shared__ short As[128 * SP];            // 18432 B
    __shared__ short Bs[256 * SP];            // 36864 B
    int tid = threadIdx.x;
    int wave = tid >> 6, lane = tid & 63;
    int wm = wave >> 2, wn = wave & 3;        // 2 row-halves x 4 col-quarters
    int quad = lane >> 4, l16 = lane & 15;
    int rowBase = blockIdx.x * 128;

    floatx4 acc[4][4];
    #pragma unroll
    for (int i = 0; i < 4; i++)
        #pragma unroll
        for (int j = 0; j < 4; j++) acc[i][j] = (floatx4)0.f;

    for (int kc = 0; kc < K; kc += 64) {
        // Stage A: 128 rows x 64 k = 1024 flats over 512 threads
        #pragma unroll
        for (int it = 0; it < 2; it++) {
            int flat = it * 512 + tid;
            int r = flat >> 3, c8 = (flat & 7) * 8;
            int ar = rowBase + r; if (ar >= NN) ar = NN - 1;   // clamp: no OOB
            short8 va;
            if constexpr (AF32) {
                const float* ap = (const float*)Araw + (size_t)ar * K + kc + c8;
                float4 u0 = *reinterpret_cast<const float4*>(ap);
                float4 u1 = *reinterpret_cast<const float4*>(ap + 4);
                va[0] = (short)f2bf_rne(u0.x); va[1] = (short)f2bf_rne(u0.y);
                va[2] = (short)f2bf_rne(u0.z); va[3] = (short)f2bf_rne(u0.w);
                va[4] = (short)f2bf_rne(u1.x); va[5] = (short)f2bf_rne(u1.y);
                va[6] = (short)f2bf_rne(u1.z); va[7] = (short)f2bf_rne(u1.w);
            } else {
                va = *reinterpret_cast<const short8*>(
                        (const unsigned short*)Araw + (size_t)ar * K + kc + c8);
            }
            *reinterpret_cast<short8*>(&As[r * SP + c8]) = va;
        }
        // Stage B: 256 cols x 64 k = 2048 flats over 512 threads
        #pragma unroll
        for (int it = 0; it < 4; it++) {
            int flat = it * 512 + tid;
            int r = flat >> 3, c8 = (flat & 7) * 8;
            short8 vb = *reinterpret_cast<const short8*>(Bt + (size_t)r * K + kc + c8);
            *reinterpret_cast<short8*>(&Bs[r * SP + c8]) = vb;
        }
        __syncthreads();
        #pragma unroll
        for (int ks = 0; ks < 2; ks++) {
            short8 af[4], bf[4];
            #pragma unroll
            for (int i = 0; i < 4; i++)
                af[i] = *reinterpret_cast<const short8*>(&As[(wm * 64 + i * 16 + l16) * SP + ks * 32 + quad * 8]);
            #pragma unroll
            for (int j = 0; j < 4; j++)
                bf[j] = *reinterpret_cast<const short8*>(&Bs[(wn * 64 + j * 16 + l16) * SP + ks * 32 + quad * 8]);
            #pragma unroll
            for (int i = 0; i < 4; i++)
                #pragma unroll
                for (int j = 0; j < 4; j++)
                    acc[i][j] = __builtin_amdgcn_mfma_f32_16x16x32_bf16(af[i], bf[j], acc[i][j], 0, 0, 0);
        }
        __syncthreads();
    }

    // Epilogue: bias + bf16 store. C layout: col = lane&15, row = quad*4 + reg.
    unsigned short* outp = (wn < 2) ? out0 : out1;
    int colBase = (wn & 1) * 64;
    float bj[4];
    #pragma unroll
    for (int j = 0; j < 4; j++) bj[j] = bias[wn * 64 + j * 16 + l16];
    #pragma unroll
    for (int i = 0; i < 4; i++) {
        #pragma unroll
        for (int j = 0; j < 4; j++) {
            int col = colBase + j * 16 + l16;
            #pragma unroll
            for (int r = 0; r < 4; r++) {
                int row = rowBase + wm * 64 + i * 16 + quad * 4 + r;
                if (row < NN)
                    outp[(size_t)row * 128 + col] = f2bf_rne(acc[i][j][r] + bj[j]);
            }
        }
    }
}

// ---------------------------------------------------------------------------
// Fused attention, eighth-wave edges. One wave per dst node, 16 edges/iter.
// lane = g*8 + l8 (8 groups x 8 lanes); lane covers features [8*l8, 8*l8+8).
// Head = 16 feats = 2 lanes -> ONE DPP add. kv row: [k 128B | v 128B] bf16.
// qsb row: [q 128B | s 128B] bf16. BN via precomputed scale/shift.
// ---------------------------------------------------------------------------
__global__ __launch_bounds__(256) void attn_fused(
    const unsigned short* __restrict__ qsb,
    const unsigned char* __restrict__ kvb,   // 256 B per node
    const int* __restrict__ rowbeg,
    const int* __restrict__ rowend,
    const int* __restrict__ csr,
    const float* __restrict__ bnscale, const float* __restrict__ bnshift,
    uint4* __restrict__ h_out) {
    int wid = (blockIdx.x * 256 + threadIdx.x) >> 6;
    int lane = threadIdx.x & 63;
    if (wid >= NN) return;
    int g = lane >> 3, l8 = lane & 7;
    unsigned int qb16 = (unsigned int)(l8 << 4);   // byte offset of lane's 16 B
    const uint4* qrow = reinterpret_cast<const uint4*>(qsb + (size_t)wid * 128);
    const float SC = 0.3606737602222409f;   // 0.25 * log2(e)
    uint4 qd = qrow[l8];
    float q[8];
    q[0] = bf_lo(qd.x) * SC; q[1] = bf_hi(qd.x) * SC;
    q[2] = bf_lo(qd.y) * SC; q[3] = bf_hi(qd.y) * SC;
    q[4] = bf_lo(qd.z) * SC; q[5] = bf_hi(qd.z) * SC;
    q[6] = bf_lo(qd.w) * SC; q[7] = bf_hi(qd.w) * SC;
    int jb = rowbeg[wid], je = rowend[wid];
    float a[8] = {0.f, 0.f, 0.f, 0.f, 0.f, 0.f, 0.f, 0.f};
    float denom = 0.f;
    int j = jb;
    for (; j + 15 < je; j += 16) {          // 2 slots x 8 groups = 16 edges
        unsigned int oA = ((unsigned int)csr[j + g] << 8) + qb16;
        unsigned int oB = ((unsigned int)csr[j + 8 + g] << 8) + qb16;
        uint4 kA = *reinterpret_cast<const uint4*>(kvb + oA);
        uint4 vA = *reinterpret_cast<const uint4*>(kvb + oA + 128);
        uint4 kB = *reinterpret_cast<const uint4*>(kvb + oB);
        uint4 vB = *reinterpret_cast<const uint4*>(kvb + oB + 128);
        float pA = dppadd<0xB1>(dot8(kA, q));   // head sum (2 lanes/head)
        float pB = dppadd<0xB1>(dot8(kB, q));
        float eA = exp2f(pA), eB = exp2f(pB);
        denom += eA + eB;
        acc8(a, eA, vA);
        acc8(a, eB, vB);
    }
    for (; j < je; j += 8) {                // masked tail, 8 at a time
        int jj = j + g;
        bool valid = jj < je;
        unsigned int o = ((unsigned int)csr[valid ? jj : je - 1] << 8) + qb16;
        uint4 kd = *reinterpret_cast<const uint4*>(kvb + o);
        uint4 vd = *reinterpret_cast<const uint4*>(kvb + o + 128);
        float p = dppadd<0xB1>(dot8(kd, q));
        float e = valid ? exp2f(p) : 0.f;
        denom += e;
        acc8(a, e, vd);
    }
    // combine 8 groups (same l8 across groups hold same features)
    #pragma unroll
    for (int i = 0; i < 8; i++) {
        a[i] += __shfl_xor(a[i], 8);
        a[i] += __shfl_xor(a[i], 16);
        a[i] += __shfl_xor(a[i], 32);
    }
    denom += __shfl_xor(denom, 8);
    denom += __shfl_xor(denom, 16);
    denom += __shfl_xor(denom, 32);
    float inv = 1.f / (denom + 1e-16f);
    uint4 sd = qrow[8 + l8];
    float s[8];
    s[0] = bf_lo(sd.x); s[1] = bf_hi(sd.x);
    s[2] = bf_lo(sd.y); s[3] = bf_hi(sd.y);
    s[4] = bf_lo(sd.z); s[5] = bf_hi(sd.z);
    s[6] = bf_lo(sd.w); s[7] = bf_hi(sd.w);
    const float4* scp = reinterpret_cast<const float4*>(bnscale);
    const float4* shp = reinterpret_cast<const float4*>(bnshift);
    float4 sc0 = scp[l8 * 2], sc1 = scp[l8 * 2 + 1];
    float4 sh0 = shp[l8 * 2], sh1 = shp[l8 * 2 + 1];
    float o0 = fmaxf(fmaf(a[0] * inv + s[0], sc0.x, sh0.x), 0.f);
    float o1 = fmaxf(fmaf(a[1] * inv + s[1], sc0.y, sh0.y), 0.f);
    float o2 = fmaxf(fmaf(a[2] * inv + s[2], sc0.z, sh0.z), 0.f);
    float o3 = fmaxf(fmaf(a[3] * inv + s[3], sc0.w, sh0.w), 0.f);
    float o4 = fmaxf(fmaf(a[4] * inv + s[4], sc1.x, sh1.x), 0.f);
    float o5 = fmaxf(fmaf(a[5] * inv + s[5], sc1.y, sh1.y), 0.f);
    float o6 = fmaxf(fmaf(a[6] * inv + s[6], sc1.z, sh1.z), 0.f);
    float o7 = fmaxf(fmaf(a[7] * inv + s[7], sc1.w, sh1.w), 0.f);
    if (g == 0) {
        uint4 hw;
        hw.x = (unsigned int)f2bf_rne(o0) | ((unsigned int)f2bf_rne(o1) << 16);
        hw.y = (unsigned int)f2bf_rne(o2) | ((unsigned int)f2bf_rne(o3) << 16);
        hw.z = (unsigned int)f2bf_rne(o4) | ((unsigned int)f2bf_rne(o5) << 16);
        hw.w = (unsigned int)f2bf_rne(o6) | ((unsigned int)f2bf_rne(o7) << 16);
        h_out[(size_t)wid * 8 + l8] = hw;
    }
}

// ---------------------------------------------------------------------------
// Global max pool over sorted batch ids (values are post-ReLU, >= 0). h bf16.
// ---------------------------------------------------------------------------
__global__ __launch_bounds__(256) void k_pool(const unsigned short* __restrict__ h,
                                              const int* __restrict__ batch,
                                              float* __restrict__ g0) {
    int f = threadIdx.x & 63;
    int sub = threadIdx.x >> 6;
    int n0 = blockIdx.x * 128;
    int nEnd = n0 + 128; if (nEnd > NN) nEnd = NN;
    int cur_g = -1; float cur_m = 0.f;
    for (int n = n0 + sub; n < nEnd; n += 4) {
        int bg = batch[n];
        float val = __uint_as_float((unsigned int)h[(size_t)n * 64 + f] << 16);
        if (bg != cur_g) {
            if (cur_g >= 0) atomicMax((int*)&g0[cur_g * 64 + f], __float_as_int(cur_m));
            cur_g = bg; cur_m = val;
        } else {
            cur_m = fmaxf(cur_m, val);
        }
    }
    if (cur_g >= 0) atomicMax((int*)&g0[cur_g * 64 + f], __float_as_int(cur_m));
}

// ---------------------------------------------------------------------------
// Fused MLP head: 4 layers + BN + log_softmax. One wave per graph row.
// ---------------------------------------------------------------------------
__global__ __launch_bounds__(256) void k_mlp(
    const float* __restrict__ g0,
    const float* __restrict__ p1w, const float* __restrict__ p1b,
    const float* __restrict__ p2w, const float* __restrict__ p2b,
    const float* __restrict__ cl1w, const float* __restrict__ cl1b,
    const float* __restrict__ bg, const float* __restrict__ bb,
    const float* __restrict__ bm, const float* __restrict__ bv,
    const float* __restrict__ cl2w, const float* __restrict__ cl2b,
    float* __restrict__ outp) {
    __shared__ float w1[64 * 64], w2[64 * 64], w3[64 * 64], w4[64 * 10];
    __shared__ float sb1[64], sb2[64], sb3[64], sbn[4 * 64], sb4[10];
    int tid = threadIdx.x;
    for (int i = tid; i < 64 * 64; i += 256) { w1[i] = p1w[i]; w2[i] = p2w[i]; w3[i] = cl1w[i]; }
    for (int i = tid; i < 64 * 10; i += 256) w4[i] = cl2w[i];
    if (tid < 64) {
        sb1[tid] = p1b[tid]; sb2[tid] = p2b[tid]; sb3[tid] = cl1b[tid];
        sbn[tid] = bg[tid]; sbn[64 + tid] = bb[tid];
        sbn[128 + tid] = bm[tid]; sbn[192 + tid] = bv[tid];
    }
    if (tid < 10) sb4[tid] = cl2b[tid];
    __syncthreads();
    int lane = tid & 63, w = tid >> 6;
    int row = blockIdx.x * 4 + w;
    float x = g0[row * 64 + lane];
    if (!isfinite(x)) x = 0.f;
    float a = sb1[lane];
    for (int k = 0; k < 64; k++) a += __shfl(x, k) * w1[k * 64 + lane];
    x = fmaxf(a, 0.f);
    a = sb2[lane];
    for (int k = 0; k < 64; k++) a += __shfl(x, k) * w2[k * 64 + lane];
    x = a;
    a = sb3[lane];
    for (int k = 0; k < 64; k++) a += __shfl(x, k) * w3[k * 64 + lane];
    a = (a - sbn[128 + lane]) * rsqrtf(sbn[192 + lane] + 1e-5f) * sbn[lane] + sbn[64 + lane];
    x = fmaxf(a, 0.f);
    float lg[10];
    #pragma unroll
    for (int c = 0; c < 10; c++) {
        float p = x * w4[lane * 10 + c];
        p += __shfl_xor(p, 1);  p += __shfl_xor(p, 2);  p += __shfl_xor(p, 4);
        p += __shfl_xor(p, 8);  p += __shfl_xor(p, 16); p += __shfl_xor(p, 32);
        lg[c] = p + sb4[c];
    }
    float mx = lg[0];
    #pragma unroll
    for (int c = 1; c < 10; c++) mx = fmaxf(mx, lg[c]);
    float s = 0.f;
    #pragma unroll
    for (int c = 0; c < 10; c++) s += __expf(lg[c] - mx);
    float lse = mx + logf(s);
    float o = 0.f;
    #pragma unroll
    for (int c = 0; c < 10; c++) if (lane == c) o = lg[c];
    if (lane < 10) outp[row * 10 + lane] = o - lse;
}

// ---------------------------------------------------------------------------
extern "C" void kernel_launch(void* const* d_in, const int* in_sizes, int n_in,
                              void* d_out, int out_size, void* d_ws, size_t ws_size,
                              hipStream_t stream) {
    const float* x     = (const float*)d_in[0];
    const int*   ei    = (const int*)d_in[1];
    const int*   batch = (const int*)d_in[2];
    const float *c1_wq = (const float*)d_in[3],  *c1_bq = (const float*)d_in[4];
    const float *c1_wk = (const float*)d_in[5],  *c1_bk = (const float*)d_in[6];
    const float *c1_wv = (const float*)d_in[7],  *c1_bv = (const float*)d_in[8];
    const float *c1_ws = (const float*)d_in[9],  *c1_bs = (const float*)d_in[10];
    const float *c2_wq = (const float*)d_in[11], *c2_bq = (const float*)d_in[12];
    const float *c2_wk = (const float*)d_in[13], *c2_bk = (const float*)d_in[14];
    const float *c2_wv = (const float*)d_in[15], *c2_bv = (const float*)d_in[16];
    const float *c2_ws = (const float*)d_in[17], *c2_bs = (const float*)d_in[18];
    const float *bn1_g = (const float*)d_in[19], *bn1_b = (const float*)d_in[20];
    const float *bn1_m = (const float*)d_in[21], *bn1_v = (const float*)d_in[22];
    const float *bn2_g = (const float*)d_in[23], *bn2_b = (const float*)d_in[24];
    const float *bn2_m = (const float*)d_in[25], *bn2_v = (const float*)d_in[26];
    const float *clbn_g = (const float*)d_in[27], *clbn_b = (const float*)d_in[28];
    const float *clbn_m = (const float*)d_in[29], *clbn_v = (const float*)d_in[30];
    const float *p1_w = (const float*)d_in[31], *p2_w = (const float*)d_in[32];
    const float *cl1_w = (const float*)d_in[33], *cl2_w = (const float*)d_in[34];
    const float *p1_b = (const float*)d_in[35], *p2_b = (const float*)d_in[36];
    const float *cl1_b = (const float*)d_in[37], *cl2_b = (const float*)d_in[38];

    char* ws = (char*)d_ws;
    unsigned short* kv     = (unsigned short*)(ws);               //  25,600,000
    unsigned short* qsb    = (unsigned short*)(ws + 25600000);    //  25,600,000
    unsigned short* hbuf   = (unsigned short*)(ws + 51200000);    //  12,812,288
    unsigned int*   ppair  = (unsigned int*)(ws + 64012288);      //  12,812,288
    int*            csr    = (int*)(ws + 76824576);               //  12,812,288
    int*            rowbeg = (int*)(ws + 89636864);               //     400,384
    int*            rowend = (int*)(ws + 90037248);               //     400,384
    int*            bcur   = (int*)(ws + 90437632);               //       3,136
    float*          g0     = (float*)(ws + 90440768);             //     131,072
    unsigned short* Bt1    = (unsigned short*)(ws + 90571840);    //      65,536
    float*          b1     = (float*)(ws + 90637376);             //       1,024
    unsigned short* Bt2    = (unsigned short*)(ws + 90638400);    //      32,768
    float*          b2     = (float*)(ws + 90671168);             //       1,024
    float*          bnp    = (float*)(ws + 90672192);             //       1,024

    const int* srcIdx = ei;
    const int* dstIdx = ei + EE;

    hipMemsetAsync(bcur, 0, NBUCK * sizeof(int), stream);

    // Weight packing + BN scale/shift + g0 zero (one dispatch)
    k_cvt_all<<<192, 256, 0, stream>>>(c1_wq, c1_bq, c1_wk, c1_bk, c1_wv, c1_bv,
                                       c1_ws, c1_bs,
                                       c2_wq, c2_bq, c2_wk, c2_bk, c2_wv, c2_bv,
                                       c2_ws, c2_bs,
                                       bn1_g, bn1_b, bn1_m, bn1_v,
                                       bn2_g, bn2_b, bn2_m, bn2_v,
                                       Bt1, b1, Bt2, b2, bnp, g0);

    // CSR build: fixed-stride bucket partition + per-bucket counting sort
    constexpr int PBLK = (EE + EPB - 1) / EPB;   // 196
    k_part<<<PBLK, 512, 0, stream>>>(srcIdx, dstIdx, bcur, ppair);
    k_bucket<<<NBUCK, 256, 0, stream>>>(ppair, bcur, rowbeg, rowend, csr);

    // Conv1 (A = x fp32, converted in staging; single A pass)
    gemm_mfma<128, true><<<MPAD / 128, 512, 0, stream>>>(x, Bt1, b1, kv, qsb);
    attn_fused<<<NN / 4, 256, 0, stream>>>(qsb, (const unsigned char*)kv,
                                           rowbeg, rowend, csr,
                                           bnp, bnp + 64, (uint4*)hbuf);

    // Conv2 (A = hbuf bf16)
    gemm_mfma<64, false><<<MPAD / 128, 512, 0, stream>>>(hbuf, Bt2, b2, kv, qsb);
    attn_fused<<<NN / 4, 256, 0, stream>>>(qsb, (const unsigned char*)kv,
                                           rowbeg, rowend, csr,
                                           bnp + 128, bnp + 192, (uint4*)hbuf);

    // Pool + MLP head
    k_pool<<<(NN + 127) / 128, 256, 0, stream>>>(hbuf, batch, g0);
    k_mlp<<<GG / 4, 256, 0, stream>>>(g0, p1_w, p1_b, p2_w, p2_b, cl1_w, cl1_b,
                                      clbn_g, clbn_b, clbn_m, clbn_v, cl2_w, cl2_b,
                                      (float*)d_out);
}